// Round 1
// baseline (1304.440 us; speedup 1.0000x reference)
//
#include <hip/hip_runtime.h>
#include <cstddef>

#define NTOK 2048
#define DMODEL 512
#define NHEAD 8
#define DHEAD 64
#define NWIN 254          // (2048-16)/8 + 1
#define CDIM 1024         // CB*DH
#define NEGV -1000000000.0f

// ---------------- workspace layout (float elements) ----------------
// total bytes needed: (16744448 + 81920)*4 = 67,305,472 (~64.2 MiB)
static const size_t OFF_H     = 0;                      // 2048*512      = 1048576
static const size_t OFF_QKV   = 1048576;                // 2048*1536     = 3145728 (reused below)
static const size_t OFF_KW    = OFF_QKV;                // 8*254*1024    = 2080768 (overwrites qkv after scatter)
static const size_t OFF_CK    = OFF_QKV + 2080768;      // 8*254*64      = 130048
static const size_t OFF_CV    = OFF_CK + 130048;        // 130048 (ends < OFF_Q)
static const size_t OFF_Q     = 4194304;                // 8*2048*64     = 1048576
static const size_t OFF_K     = 5242880;
static const size_t OFF_V     = 6291456;
static const size_t OFF_RQ    = 7340032;
static const size_t OFF_RK    = 8388608;
static const size_t OFF_VW    = 9437184;                // 2080768 (reused as COMB)
static const size_t OFF_COMB  = OFF_VW;
static const size_t OFF_HID   = 11517952;               // 2080768 (reused as STRAT)
static const size_t OFF_STRAT = OFF_HID;
static const size_t OFF_COUT  = 13598720;               // 1048576
static const size_t OFF_FOUT  = 14647296;
static const size_t OFF_SOUT  = 15695872;
static const size_t OFF_SEL   = 16744448;               // int region, 8*2048*5 = 81920 ints

// ---------------- RMSNorm ----------------
__global__ void k_rmsnorm(const float* __restrict__ x, const float* __restrict__ g,
                          float* __restrict__ h) {
  const int row = blockIdx.x;
  const int t = threadIdx.x;
  __shared__ float wsum[4];
  __shared__ float scale_s;
  const float* xr = x + (size_t)row * DMODEL;
  float s = 0.f;
  for (int c = t; c < DMODEL; c += 256) { float v = xr[c]; s += v * v; }
  for (int o = 32; o > 0; o >>= 1) s += __shfl_down(s, o);
  if ((t & 63) == 0) wsum[t >> 6] = s;
  __syncthreads();
  if (t == 0) {
    float tot = wsum[0] + wsum[1] + wsum[2] + wsum[3];
    scale_s = rsqrtf(tot * (1.f / DMODEL) + 1e-6f);
  }
  __syncthreads();
  float sc = scale_s;
  float* hr = h + (size_t)row * DMODEL;
  for (int c = t; c < DMODEL; c += 256) hr[c] = xr[c] * sc * g[c];
}

// ---------------- generic tiled GEMM: C = epi(A[M,K] @ W[K,N] + bias) ----------------
// EPI: 0=none 1=relu 2=sigmoid. K must be a multiple of 32.
template <int EPI>
__global__ void k_gemm(const float* __restrict__ A, const float* __restrict__ W,
                       const float* __restrict__ bias, float* __restrict__ C,
                       int M, int K, int Nc) {
  __shared__ float As[32][33];
  __shared__ float Ws[32][33];
  const int tx = threadIdx.x & 31;
  const int ty = threadIdx.x >> 5;   // 0..7
  const int row0 = blockIdx.y << 5;
  const int col0 = blockIdx.x << 5;
  const int col = col0 + tx;
  float acc[4] = {0.f, 0.f, 0.f, 0.f};
  for (int k0 = 0; k0 < K; k0 += 32) {
#pragma unroll
    for (int r = 0; r < 4; ++r) {
      int rr = ty + (r << 3);
      int grow = row0 + rr;
      As[rr][tx] = (grow < M) ? A[(size_t)grow * K + k0 + tx] : 0.f;
      Ws[rr][tx] = (col < Nc) ? W[(size_t)(k0 + rr) * Nc + col] : 0.f;
    }
    __syncthreads();
#pragma unroll
    for (int kk = 0; kk < 32; ++kk) {
      float w = Ws[kk][tx];
#pragma unroll
      for (int r = 0; r < 4; ++r) acc[r] = fmaf(As[ty + (r << 3)][kk], w, acc[r]);
    }
    __syncthreads();
  }
  if (col < Nc) {
#pragma unroll
    for (int r = 0; r < 4; ++r) {
      int grow = row0 + ty + (r << 3);
      if (grow < M) {
        float vv = acc[r] + (bias ? bias[col] : 0.f);
        if (EPI == 1) vv = fmaxf(vv, 0.f);
        if (EPI == 2) vv = 1.f / (1.f + expf(-vv));
        C[(size_t)grow * Nc + col] = vv;
      }
    }
  }
}

// ---------------- scatter qkv -> q,k,v in (H,N,DH) ----------------
__global__ void k_scatter(const float* __restrict__ qkv, float* __restrict__ q,
                          float* __restrict__ k, float* __restrict__ v) {
  int idx = blockIdx.x * 256 + threadIdx.x;      // 2048*1536 total (exact grid)
  int row = idx / 1536;
  int col = idx - row * 1536;
  int which = col >> 9;
  int rem = col & 511;
  int h = rem >> 6, d = rem & 63;
  float val = qkv[idx];
  float* dst = (which == 0) ? q : (which == 1) ? k : v;
  dst[((size_t)h * NTOK + row) * DHEAD + d] = val;
}

// ---------------- RoPE ----------------
__global__ void k_rope(const float* __restrict__ q, const float* __restrict__ k,
                       float* __restrict__ rq, float* __restrict__ rk) {
  int idx = blockIdx.x * 256 + threadIdx.x;      // 8*2048*32 total (exact grid)
  int i = idx & 31;
  int n = (idx >> 5) & (NTOK - 1);
  int h = idx >> 16;
  float ex = (float)(2 * i) * (1.f / 64.f);
  float inv = exp2f(-ex * 13.287712379549449f);  // 10000^-ex
  float ang = (float)n * inv;
  float sn, cs;
  sincosf(ang, &sn, &cs);
  size_t base = ((size_t)h * NTOK + n) * DHEAD + 2 * i;
  float q1 = q[base], q2 = q[base + 1];
  rq[base] = q1 * cs - q2 * sn;
  rq[base + 1] = q1 * sn + q2 * cs;
  float k1 = k[base], k2 = k[base + 1];
  rk[base] = k1 * cs - k2 * sn;
  rk[base + 1] = k1 * sn + k2 * cs;
}

// ---------------- build compression windows ----------------
__global__ void k_windows(const float* __restrict__ k, const float* __restrict__ v,
                          const float* __restrict__ kpos, const float* __restrict__ vpos,
                          float* __restrict__ kw, float* __restrict__ vw) {
  int idx = blockIdx.x * 256 + threadIdx.x;      // 8*254*1024 total (exact grid)
  int d = idx & 63;
  int c = (idx >> 6) & 15;
  int j = (idx >> 10) % NWIN;
  int h = idx / (NWIN << 10);
  int srcpos = (j << 3) + c;
  size_t src = ((size_t)h * NTOK + srcpos) * DHEAD + d;
  size_t pp = ((size_t)h * 16 + c) * DHEAD + d;
  kw[idx] = k[src] + kpos[pp];
  vw[idx] = v[src] + vpos[pp];
}

// ---------------- compression attention + block importance + top-k ----------------
__global__ void k_comp_attn(const float* __restrict__ q, const float* __restrict__ ck,
                            const float* __restrict__ cv, const float* __restrict__ memkv,
                            float* __restrict__ c_out, int* __restrict__ sel) {
  const int h = blockIdx.x >> 11;
  const int i = blockIdx.x & 2047;
  const int t = threadIdx.x;                     // 256
  __shared__ float qs[64];
  __shared__ float p[256];
  __shared__ float red[256];
  __shared__ float bimp[128];
  if (t < 64) qs[t] = q[((size_t)h * NTOK + i) * DHEAD + t];
  __syncthreads();
  float sim = NEGV;
  if (t < 255) {
    int wend = (t == 0) ? -1 : ((t - 1) << 3) + 15;
    if (wend < i) {
      const float* kr = (t == 0) ? (memkv + (size_t)h * DHEAD)
                                 : (ck + ((size_t)h * NWIN + (t - 1)) * DHEAD);
      float dsum = 0.f;
      for (int e = 0; e < 64; ++e) dsum = fmaf(qs[e], kr[e], dsum);
      sim = dsum * 0.125f;
    }
  }
  p[t] = sim;
  red[t] = sim;
  __syncthreads();
  for (int o = 128; o > 0; o >>= 1) { if (t < o) red[t] = fmaxf(red[t], red[t + o]); __syncthreads(); }
  float mx = red[0];
  __syncthreads();
  float e = __expf(sim - mx);                    // NEG entries underflow to 0
  red[t] = e;
  __syncthreads();
  for (int o = 128; o > 0; o >>= 1) { if (t < o) red[t] += red[t + o]; __syncthreads(); }
  float invs = 1.f / red[0];
  __syncthreads();
  p[t] = e * invs;
  __syncthreads();
  // block importance: bimp[f] = (attn[2f+1]+attn[2f+2])/2, masked to NEG if f >= i/16; f=127 always NEG
  if (t >= 64 && t < 192) {
    int f = t - 64;
    float v;
    if (f == 127) v = NEGV;
    else {
      v = (p[(f << 1) + 1] + p[(f << 1) + 2]) * 0.5f;
      if (f >= (i >> 4)) v = NEGV;
    }
    bimp[f] = v;
  }
  __syncthreads();
  if (t < 64) {
    float acc = p[0] * memkv[(size_t)(NHEAD + h) * DHEAD + t];
    for (int j = 1; j < 255; ++j)
      acc = fmaf(p[j], cv[((size_t)h * NWIN + (j - 1)) * DHEAD + t], acc);
    c_out[((size_t)h * NTOK + i) * DHEAD + t] = acc;
  } else if (t == 192) {
    // serial top-4 (first-index-wins on ties, matching lax.top_k)
    int base = ((h << 11) | i) * 5;
    for (int kk = 0; kk < 4; ++kk) {
      float bv = -3.0e38f; int bi_ = 0;
      for (int f = 0; f < 128; ++f) {
        float vv = bimp[f];
        if (vv > bv) { bv = vv; bi_ = f; }
      }
      bimp[bi_] = -3.0e38f;
      sel[base + kk] = (bv > -5.0e8f) ? bi_ : -1;  // -1 = invalid (gate 0)
    }
    sel[base + 4] = i >> 4;                        // own block, gate 1
  }
}

// ---------------- fine (selected-block) attention ----------------
__global__ void k_fine_attn(const float* __restrict__ rq, const float* __restrict__ rk,
                            const float* __restrict__ v, const int* __restrict__ sel,
                            float* __restrict__ f_out) {
  const int h = blockIdx.x >> 11;
  const int i = blockIdx.x & 2047;
  const int t = threadIdx.x;                     // 128
  __shared__ float qs[64];
  __shared__ int selb[5];
  __shared__ float p[128];
  __shared__ float red[128];
  if (t < 64) qs[t] = rq[((size_t)h * NTOK + i) * DHEAD + t];
  else if (t < 69) selb[t - 64] = sel[((h << 11) | i) * 5 + (t - 64)];
  __syncthreads();
  float sim = NEGV;
  if (t < 80) {
    int kb = selb[t >> 4];
    int pos = (kb << 4) + (t & 15);
    if (kb >= 0 && pos <= i) {
      const float* kr = rk + ((size_t)h * NTOK + pos) * DHEAD;
      float dsum = 0.f;
      for (int e = 0; e < 64; ++e) dsum = fmaf(qs[e], kr[e], dsum);
      sim = dsum * 0.125f;
    }
  }
  p[t] = sim;
  red[t] = sim;
  __syncthreads();
  for (int o = 64; o > 0; o >>= 1) { if (t < o) red[t] = fmaxf(red[t], red[t + o]); __syncthreads(); }
  float mx = red[0];
  __syncthreads();
  float e = (t < 80) ? __expf(sim - mx) : 0.f;
  red[t] = e;
  __syncthreads();
  for (int o = 64; o > 0; o >>= 1) { if (t < o) red[t] += red[t + o]; __syncthreads(); }
  float invs = 1.f / red[0];
  __syncthreads();
  p[t] = e * invs;
  __syncthreads();
  if (t < 64) {
    float acc = 0.f;
    for (int j = 0; j < 80; ++j) {
      int kb = selb[j >> 4];
      if (kb < 0) continue;                      // invalid block: p[j]==0 anyway
      int pos = (kb << 4) + (j & 15);
      acc = fmaf(p[j], v[((size_t)h * NTOK + pos) * DHEAD + t], acc);
    }
    f_out[((size_t)h * NTOK + i) * DHEAD + t] = acc;
  }
}

// ---------------- sliding-window attention (keys max(0,i-63)..i) ----------------
__global__ void k_slide_attn(const float* __restrict__ rq, const float* __restrict__ rk,
                             const float* __restrict__ v, float* __restrict__ s_out) {
  const int h = blockIdx.x >> 11;
  const int i = blockIdx.x & 2047;
  const int t = threadIdx.x;                     // 64
  __shared__ float qs[64];
  __shared__ float p[64];
  qs[t] = rq[((size_t)h * NTOK + i) * DHEAD + t];
  __syncthreads();
  int pos = i - 63 + t;
  float sim = NEGV;
  if (pos >= 0) {
    const float* kr = rk + ((size_t)h * NTOK + pos) * DHEAD;
    float dsum = 0.f;
    for (int e = 0; e < 64; ++e) dsum = fmaf(qs[e], kr[e], dsum);
    sim = dsum * 0.125f;
  }
  float mx = sim;
  for (int o = 32; o > 0; o >>= 1) mx = fmaxf(mx, __shfl_xor(mx, o));
  float e = (pos >= 0) ? __expf(sim - mx) : 0.f;
  float tot = e;
  for (int o = 32; o > 0; o >>= 1) tot += __shfl_xor(tot, o);
  p[t] = e / tot;
  __syncthreads();
  float acc = 0.f;
  for (int j = 0; j < 64; ++j) {
    int pj = i - 63 + j;
    if (pj < 0) continue;
    acc = fmaf(p[j], v[((size_t)h * NTOK + pj) * DHEAD + t], acc);
  }
  s_out[((size_t)h * NTOK + i) * DHEAD + t] = acc;
}

// ---------------- gate + combine branches ----------------
__global__ void k_combine(const float* __restrict__ strat, const float* __restrict__ c_out,
                          const float* __restrict__ f_out, const float* __restrict__ s_out,
                          float* __restrict__ comb) {
  int idx = blockIdx.x * 256 + threadIdx.x;      // 2048*512 total (exact grid)
  int i = idx >> 9;
  int c = idx & 511;
  int h = c >> 6, d = c & 63;
  size_t a = ((size_t)h * NTOK + i) * DHEAD + d;
  const float* st = strat + (size_t)i * 24 + h * 3;
  comb[idx] = st[0] * c_out[a] + st[1] * f_out[a] + st[2] * s_out[a];
}

extern "C" void kernel_launch(void* const* d_in, const int* in_sizes, int n_in,
                              void* d_out, int out_size, void* d_ws, size_t ws_size,
                              hipStream_t stream) {
  const float* x      = (const float*)d_in[0];
  const float* g_norm = (const float*)d_in[1];
  const float* w_qkv  = (const float*)d_in[2];
  const float* k_pos  = (const float*)d_in[3];
  const float* v_pos  = (const float*)d_in[4];
  const float* mem_kv = (const float*)d_in[5];
  const float* k_w1   = (const float*)d_in[6];
  const float* k_b1   = (const float*)d_in[7];
  const float* k_w2   = (const float*)d_in[8];
  const float* k_b2   = (const float*)d_in[9];
  const float* v_w1   = (const float*)d_in[10];
  const float* v_b1   = (const float*)d_in[11];
  const float* v_w2   = (const float*)d_in[12];
  const float* v_b2   = (const float*)d_in[13];
  const float* w_comb = (const float*)d_in[14];
  const float* b_comb = (const float*)d_in[15];
  const float* w_out  = (const float*)d_in[16];
  float* out = (float*)d_out;
  float* ws = (float*)d_ws;

  float* H_   = ws + OFF_H;
  float* QKV  = ws + OFF_QKV;
  float* KW   = ws + OFF_KW;
  float* CK   = ws + OFF_CK;
  float* CV   = ws + OFF_CV;
  float* Q    = ws + OFF_Q;
  float* K_   = ws + OFF_K;
  float* V    = ws + OFF_V;
  float* RQ   = ws + OFF_RQ;
  float* RK   = ws + OFF_RK;
  float* VW   = ws + OFF_VW;
  float* COMB = ws + OFF_COMB;
  float* HID  = ws + OFF_HID;
  float* STRAT= ws + OFF_STRAT;
  float* COUT = ws + OFF_COUT;
  float* FOUT = ws + OFF_FOUT;
  float* SOUT = ws + OFF_SOUT;
  int*   SEL  = (int*)(ws + OFF_SEL);

  // 1. RMSNorm
  k_rmsnorm<<<NTOK, 256, 0, stream>>>(x, g_norm, H_);
  // 2. qkv projection (2048x512 @ 512x1536)
  k_gemm<0><<<dim3(48, 64), 256, 0, stream>>>(H_, w_qkv, nullptr, QKV, NTOK, DMODEL, 1536);
  // 3. scatter to (H,N,DH)
  k_scatter<<<12288, 256, 0, stream>>>(QKV, Q, K_, V);
  // 4. RoPE (q,k -> rq,rk)
  k_rope<<<2048, 256, 0, stream>>>(Q, K_, RQ, RK);
  // 5. build compression windows (+pos emb); overwrites QKV region with KW
  k_windows<<<8128, 256, 0, stream>>>(K_, V, k_pos, v_pos, KW, VW);
  // 6-9. compression MLPs (k then v)
  k_gemm<1><<<dim3(32, 64), 256, 0, stream>>>(KW, k_w1, k_b1, HID, NHEAD * NWIN, CDIM, CDIM);
  k_gemm<0><<<dim3(2, 64), 256, 0, stream>>>(HID, k_w2, k_b2, CK, NHEAD * NWIN, CDIM, DHEAD);
  k_gemm<1><<<dim3(32, 64), 256, 0, stream>>>(VW, v_w1, v_b1, HID, NHEAD * NWIN, CDIM, CDIM);
  k_gemm<0><<<dim3(2, 64), 256, 0, stream>>>(HID, v_w2, v_b2, CV, NHEAD * NWIN, CDIM, DHEAD);
  // 10. compression attention + importance + top-k selection
  k_comp_attn<<<NHEAD * NTOK, 256, 0, stream>>>(Q, CK, CV, mem_kv, COUT, SEL);
  // 11. fine attention over selected blocks
  k_fine_attn<<<NHEAD * NTOK, 128, 0, stream>>>(RQ, RK, V, SEL, FOUT);
  // 12. sliding-window attention
  k_slide_attn<<<NHEAD * NTOK, 64, 0, stream>>>(RQ, RK, V, SOUT);
  // 13. strategy gates: sigmoid(h @ w_comb + b_comb) -> (2048,24)
  k_gemm<2><<<dim3(1, 64), 256, 0, stream>>>(H_, w_comb, b_comb, STRAT, NTOK, DMODEL, 24);
  // 14. gated combination -> (2048, 512)
  k_combine<<<4096, 256, 0, stream>>>(STRAT, COUT, FOUT, SOUT, COMB);
  // 15. output projection
  k_gemm<0><<<dim3(16, 64), 256, 0, stream>>>(COMB, w_out, nullptr, out, NTOK, DMODEL, DMODEL);
}

// Round 3
// 647.108 us; speedup vs baseline: 2.0158x; 2.0158x over previous
//
#include <hip/hip_runtime.h>
#include <hip/hip_bf16.h>
#include <cstddef>

#define NTOK 2048
#define DMODEL 512
#define NHEAD 8
#define DHEAD 64
#define NWIN 254          // (2048-16)/8 + 1
#define CDIM 1024         // CB*DH
#define NEGV -1000000000.0f

typedef __attribute__((ext_vector_type(8))) __bf16 bf16x8;
typedef __attribute__((ext_vector_type(4))) float f32x4;
typedef __hip_bfloat16 bf16;

// ---------------- workspace layout (byte offsets) ----------------
static const size_t B_WQKV_H = 0;          // 1536x512 bf16 = 1572864
static const size_t B_WQKV_L = 1572864;
static const size_t B_KW1_H  = 3145728;    // 1024x1024 bf16 = 2097152
static const size_t B_KW1_L  = 5242880;
static const size_t B_KW2_H  = 7340032;    // 64x1024 bf16 = 131072
static const size_t B_KW2_L  = 7471104;
static const size_t B_VW1_H  = 7602176;    // 2097152
static const size_t B_VW2_H  = 9699328;    // 131072
static const size_t B_WOUT_H = 9830400;    // 512x512 bf16 = 524288
static const size_t B_HB_H   = 10354688;   // 2048x512 bf16 = 2097152
static const size_t B_HB_L   = 12451840;
static const size_t B_Q      = 14548992;   // 8*2048*64 f32 = 4194304
static const size_t B_K      = 18743296;
static const size_t B_V      = 22937600;
static const size_t B_RQ     = 27131904;
static const size_t B_RK     = 31326208;
static const size_t B_CK     = 35520512;   // 8*254*64 f32 = 520192
static const size_t B_CV     = 36040704;
static const size_t B_COUT   = 36560896;   // 4194304 (HID_H overlays, dead before comp_attn)
static const size_t B_FOUT   = 40755200;   // 4194304 (HID_L overlays, dead before fine_attn)
static const size_t B_SOUT   = 44949504;   // 4194304
static const size_t B_STRAT  = 49143808;   // 2048*24 f32 = 196608
static const size_t B_SEL    = 49340416;   // 8*2048*5 int = 327680
static const size_t B_KW_H   = 49668096;   // 2032*1024 bf16 = 4161536 (COMBB overlays after dead)
static const size_t B_KW_L   = 53829632;
static const size_t B_VW_H   = 57991168;   // end 62152704 < 67.3MB known-good
static const size_t B_HID_H  = B_COUT;     // 4161536 <= 4194304
static const size_t B_HID_L  = B_FOUT;
static const size_t B_COMBB  = B_KW_H;     // 2097152 <= 4161536

// ---------------- RMSNorm -> hi/lo bf16 ----------------
__global__ void k_rmsnorm(const float* __restrict__ x, const float* __restrict__ g,
                          bf16* __restrict__ hbh, bf16* __restrict__ hbl) {
  const int row = blockIdx.x;
  const int t = threadIdx.x;
  __shared__ float wsum[4];
  __shared__ float scale_s;
  const float* xr = x + (size_t)row * DMODEL;
  float s = 0.f;
  for (int c = t; c < DMODEL; c += 256) { float v = xr[c]; s += v * v; }
  for (int o = 32; o > 0; o >>= 1) s += __shfl_down(s, o);
  if ((t & 63) == 0) wsum[t >> 6] = s;
  __syncthreads();
  if (t == 0) {
    float tot = wsum[0] + wsum[1] + wsum[2] + wsum[3];
    scale_s = rsqrtf(tot * (1.f / DMODEL) + 1e-6f);
  }
  __syncthreads();
  float sc = scale_s;
  for (int c = t; c < DMODEL; c += 256) {
    float v = xr[c] * sc * g[c];
    bf16 h1 = __float2bfloat16(v);
    hbh[(size_t)row * DMODEL + c] = h1;
    hbl[(size_t)row * DMODEL + c] = __float2bfloat16(v - __bfloat162float(h1));
  }
}

// ---------------- weight transpose+convert hi(/lo): WT[n][k] = split(W[k][n]) ----------------
__global__ void k_wt(const float* __restrict__ W, bf16* __restrict__ WTh,
                     bf16* __restrict__ WTl, int K, int N) {
  __shared__ float t[32][33];
  const int k0 = blockIdx.x << 5, n0 = blockIdx.y << 5;
  const int tx = threadIdx.x & 31, ty = threadIdx.x >> 5;
#pragma unroll
  for (int r = 0; r < 4; ++r)
    t[ty + (r << 3)][tx] = W[(size_t)(k0 + ty + (r << 3)) * N + n0 + tx];
  __syncthreads();
#pragma unroll
  for (int r = 0; r < 4; ++r) {
    float val = t[tx][ty + (r << 3)];
    size_t o = (size_t)(n0 + ty + (r << 3)) * K + k0 + tx;
    bf16 h1 = __float2bfloat16(val);
    WTh[o] = h1;
    if (WTl) WTl[o] = __float2bfloat16(val - __bfloat162float(h1));
  }
}

// ---------------- MFMA GEMM, optionally compensated (Markidis 3-term) ----------------
// A row-major [M][K] bf16 (hi + optional lo); WT = W^T [N][K] bf16 (hi + optional lo).
// EPI: 0=none 1=relu.
// OUT: 0 = fp32 C[M][N]; 1 = bf16 hi only; 2 = bf16 hi+lo; 3 = qkv scatter to q/k/v fp32.
// COMP: 1 = 3-term compensated (needs Al, Wl), 0 = plain.
// block 256 = 4 waves (2x2), tile 64x64, wave 32x32 (2x2 x 16x16 frags), K-step 32.
template <int EPI, int OUT, int COMP>
__global__ void k_cgemm(const bf16* __restrict__ Ah, const bf16* __restrict__ Al,
                        const bf16* __restrict__ Wh, const bf16* __restrict__ Wl,
                        const float* __restrict__ bias,
                        float* __restrict__ Cf, bf16* __restrict__ Cbh, bf16* __restrict__ Cbl,
                        float* __restrict__ q, float* __restrict__ k, float* __restrict__ v,
                        int M, int K, int N) {
  const int lane = threadIdx.x & 63;
  const int w = threadIdx.x >> 6;
  const int wr = w >> 1, wc = w & 1;
  const int row_base = (blockIdx.y << 6) + (wr << 5);
  const int col_base = (blockIdx.x << 6) + (wc << 5);
  const int lr = lane & 15;
  const int kg = (lane >> 4) << 3;   // k sub-offset 0,8,16,24

  int ar0 = row_base + lr;       if (ar0 > M - 1) ar0 = M - 1;
  int ar1 = row_base + 16 + lr;  if (ar1 > M - 1) ar1 = M - 1;
  const size_t a0o = (size_t)ar0 * K + kg;
  const size_t a1o = (size_t)ar1 * K + kg;
  const size_t b0o = (size_t)(col_base + lr) * K + kg;
  const size_t b1o = (size_t)(col_base + 16 + lr) * K + kg;

  f32x4 acc00 = {}, acc01 = {}, acc10 = {}, acc11 = {};
  for (int k0 = 0; k0 < K; k0 += 32) {
    bf16x8 ah0 = *reinterpret_cast<const bf16x8*>(Ah + a0o + k0);
    bf16x8 ah1 = *reinterpret_cast<const bf16x8*>(Ah + a1o + k0);
    bf16x8 bh0 = *reinterpret_cast<const bf16x8*>(Wh + b0o + k0);
    bf16x8 bh1 = *reinterpret_cast<const bf16x8*>(Wh + b1o + k0);
    acc00 = __builtin_amdgcn_mfma_f32_16x16x32_bf16(ah0, bh0, acc00, 0, 0, 0);
    acc01 = __builtin_amdgcn_mfma_f32_16x16x32_bf16(ah0, bh1, acc01, 0, 0, 0);
    acc10 = __builtin_amdgcn_mfma_f32_16x16x32_bf16(ah1, bh0, acc10, 0, 0, 0);
    acc11 = __builtin_amdgcn_mfma_f32_16x16x32_bf16(ah1, bh1, acc11, 0, 0, 0);
    if constexpr (COMP) {
      bf16x8 al0 = *reinterpret_cast<const bf16x8*>(Al + a0o + k0);
      bf16x8 al1 = *reinterpret_cast<const bf16x8*>(Al + a1o + k0);
      bf16x8 bl0 = *reinterpret_cast<const bf16x8*>(Wl + b0o + k0);
      bf16x8 bl1 = *reinterpret_cast<const bf16x8*>(Wl + b1o + k0);
      acc00 = __builtin_amdgcn_mfma_f32_16x16x32_bf16(ah0, bl0, acc00, 0, 0, 0);
      acc01 = __builtin_amdgcn_mfma_f32_16x16x32_bf16(ah0, bl1, acc01, 0, 0, 0);
      acc10 = __builtin_amdgcn_mfma_f32_16x16x32_bf16(ah1, bl0, acc10, 0, 0, 0);
      acc11 = __builtin_amdgcn_mfma_f32_16x16x32_bf16(ah1, bl1, acc11, 0, 0, 0);
      acc00 = __builtin_amdgcn_mfma_f32_16x16x32_bf16(al0, bh0, acc00, 0, 0, 0);
      acc01 = __builtin_amdgcn_mfma_f32_16x16x32_bf16(al0, bh1, acc01, 0, 0, 0);
      acc10 = __builtin_amdgcn_mfma_f32_16x16x32_bf16(al1, bh0, acc10, 0, 0, 0);
      acc11 = __builtin_amdgcn_mfma_f32_16x16x32_bf16(al1, bh1, acc11, 0, 0, 0);
    }
  }

  const int crow = (lane >> 4) << 2;  // 0,4,8,12
  f32x4 accs[2][2] = {acc00, acc01, acc10, acc11};
#pragma unroll
  for (int mi = 0; mi < 2; ++mi) {
#pragma unroll
    for (int ni = 0; ni < 2; ++ni) {
      int col = col_base + (ni << 4) + lr;
      float bv = bias ? bias[col] : 0.f;
#pragma unroll
      for (int r = 0; r < 4; ++r) {
        int row = row_base + (mi << 4) + crow + r;
        if (row < M) {
          float vv = accs[mi][ni][r] + bv;
          if (EPI == 1) vv = fmaxf(vv, 0.f);
          if constexpr (OUT == 0) {
            Cf[(size_t)row * N + col] = vv;
          } else if constexpr (OUT == 1) {
            Cbh[(size_t)row * N + col] = __float2bfloat16(vv);
          } else if constexpr (OUT == 2) {
            bf16 h1 = __float2bfloat16(vv);
            Cbh[(size_t)row * N + col] = h1;
            Cbl[(size_t)row * N + col] = __float2bfloat16(vv - __bfloat162float(h1));
          } else {  // OUT == 3: qkv scatter, N==1536
            int which = col >> 9, rem = col & 511;
            int hh = rem >> 6, dd = rem & 63;
            float* dst = (which == 0) ? q : (which == 1) ? k : v;
            dst[((size_t)hh * NTOK + row) * DHEAD + dd] = vv;
          }
        }
      }
    }
  }
}

// ---------------- strat GEMM: sigmoid((hi+lo) @ W + b), fp32 accum, N small ----------------
__global__ void k_gemm_hl(const bf16* __restrict__ Ah, const bf16* __restrict__ Al,
                          const float* __restrict__ W, const float* __restrict__ bias,
                          float* __restrict__ C, int M, int K, int Nc) {
  __shared__ float As[32][33];
  __shared__ float Ws[32][33];
  const int tx = threadIdx.x & 31;
  const int ty = threadIdx.x >> 5;
  const int row0 = blockIdx.y << 5;
  const int col0 = blockIdx.x << 5;
  const int col = col0 + tx;
  float acc[4] = {0.f, 0.f, 0.f, 0.f};
  for (int k0 = 0; k0 < K; k0 += 32) {
#pragma unroll
    for (int r = 0; r < 4; ++r) {
      int rr = ty + (r << 3);
      int grow = row0 + rr;
      size_t ao = (size_t)grow * K + k0 + tx;
      As[rr][tx] = (grow < M) ? (__bfloat162float(Ah[ao]) + __bfloat162float(Al[ao])) : 0.f;
      Ws[rr][tx] = (col < Nc) ? W[(size_t)(k0 + rr) * Nc + col] : 0.f;
    }
    __syncthreads();
#pragma unroll
    for (int kk = 0; kk < 32; ++kk) {
      float wv = Ws[kk][tx];
#pragma unroll
      for (int r = 0; r < 4; ++r) acc[r] = fmaf(As[ty + (r << 3)][kk], wv, acc[r]);
    }
    __syncthreads();
  }
  if (col < Nc) {
#pragma unroll
    for (int r = 0; r < 4; ++r) {
      int grow = row0 + ty + (r << 3);
      if (grow < M)
        C[(size_t)grow * Nc + col] = 1.f / (1.f + expf(-(acc[r] + bias[col])));
    }
  }
}

// ---------------- RoPE ----------------
__global__ void k_rope(const float* __restrict__ q, const float* __restrict__ k,
                       float* __restrict__ rq, float* __restrict__ rk) {
  int idx = blockIdx.x * 256 + threadIdx.x;
  int i = idx & 31;
  int n = (idx >> 5) & (NTOK - 1);
  int h = idx >> 16;
  float ex = (float)(2 * i) * (1.f / 64.f);
  float inv = exp2f(-ex * 13.287712379549449f);
  float ang = (float)n * inv;
  float sn, cs;
  sincosf(ang, &sn, &cs);
  size_t base = ((size_t)h * NTOK + n) * DHEAD + 2 * i;
  float q1 = q[base], q2 = q[base + 1];
  rq[base] = q1 * cs - q2 * sn;
  rq[base + 1] = q1 * sn + q2 * cs;
  float k1 = k[base], k2 = k[base + 1];
  rk[base] = k1 * cs - k2 * sn;
  rk[base + 1] = k1 * sn + k2 * cs;
}

// ---------------- build compression windows: KW hi/lo, VW hi ----------------
__global__ void k_windows(const float* __restrict__ k, const float* __restrict__ v,
                          const float* __restrict__ kpos, const float* __restrict__ vpos,
                          bf16* __restrict__ kwh, bf16* __restrict__ kwl,
                          bf16* __restrict__ vwh) {
  int idx = blockIdx.x * 256 + threadIdx.x;
  int d = idx & 63;
  int c = (idx >> 6) & 15;
  int j = (idx >> 10) % NWIN;
  int h = idx / (NWIN << 10);
  int srcpos = (j << 3) + c;
  size_t src = ((size_t)h * NTOK + srcpos) * DHEAD + d;
  size_t pp = ((size_t)h * 16 + c) * DHEAD + d;
  float kv = k[src] + kpos[pp];
  bf16 h1 = __float2bfloat16(kv);
  kwh[idx] = h1;
  kwl[idx] = __float2bfloat16(kv - __bfloat162float(h1));
  vwh[idx] = __float2bfloat16(v[src] + vpos[pp]);
}

// ---------------- compression attention + block importance + top-k ----------------
__global__ void k_comp_attn(const float* __restrict__ q, const float* __restrict__ ck,
                            const float* __restrict__ cv, const float* __restrict__ memkv,
                            float* __restrict__ c_out, int* __restrict__ sel) {
  const int h = blockIdx.x >> 11;
  const int i = blockIdx.x & 2047;
  const int t = threadIdx.x;
  __shared__ float qs[64];
  __shared__ float p[256];
  __shared__ float red[256];
  __shared__ float bimp[128];
  if (t < 64) qs[t] = q[((size_t)h * NTOK + i) * DHEAD + t];
  __syncthreads();
  float sim = NEGV;
  if (t < 255) {
    int wend = (t == 0) ? -1 : ((t - 1) << 3) + 15;
    if (wend < i) {
      const float* kr = (t == 0) ? (memkv + (size_t)h * DHEAD)
                                 : (ck + ((size_t)h * NWIN + (t - 1)) * DHEAD);
      float dsum = 0.f;
      for (int e = 0; e < 64; ++e) dsum = fmaf(qs[e], kr[e], dsum);
      sim = dsum * 0.125f;
    }
  }
  p[t] = sim;
  red[t] = sim;
  __syncthreads();
  for (int o = 128; o > 0; o >>= 1) { if (t < o) red[t] = fmaxf(red[t], red[t + o]); __syncthreads(); }
  float mx = red[0];
  __syncthreads();
  float e = __expf(sim - mx);
  red[t] = e;
  __syncthreads();
  for (int o = 128; o > 0; o >>= 1) { if (t < o) red[t] += red[t + o]; __syncthreads(); }
  float invs = 1.f / red[0];
  __syncthreads();
  p[t] = e * invs;
  __syncthreads();
  if (t >= 64 && t < 192) {
    int f = t - 64;
    float v;
    if (f == 127) v = NEGV;
    else {
      v = (p[(f << 1) + 1] + p[(f << 1) + 2]) * 0.5f;
      if (f >= (i >> 4)) v = NEGV;
    }
    bimp[f] = v;
  }
  __syncthreads();
  if (t < 64) {
    float acc = p[0] * memkv[(size_t)(NHEAD + h) * DHEAD + t];
    for (int j = 1; j < 255; ++j)
      acc = fmaf(p[j], cv[((size_t)h * NWIN + (j - 1)) * DHEAD + t], acc);
    c_out[((size_t)h * NTOK + i) * DHEAD + t] = acc;
  } else if (t == 192) {
    int base = ((h << 11) | i) * 5;
    for (int kk = 0; kk < 4; ++kk) {
      float bv = -3.0e38f; int bi_ = 0;
      for (int f = 0; f < 128; ++f) {
        float vv = bimp[f];
        if (vv > bv) { bv = vv; bi_ = f; }
      }
      bimp[bi_] = -3.0e38f;
      sel[base + kk] = (bv > -5.0e8f) ? bi_ : -1;
    }
    sel[base + 4] = i >> 4;
  }
}

// ---------------- fine (selected-block) attention ----------------
__global__ void k_fine_attn(const float* __restrict__ rq, const float* __restrict__ rk,
                            const float* __restrict__ v, const int* __restrict__ sel,
                            float* __restrict__ f_out) {
  const int h = blockIdx.x >> 11;
  const int i = blockIdx.x & 2047;
  const int t = threadIdx.x;
  __shared__ float qs[64];
  __shared__ int selb[5];
  __shared__ float p[128];
  __shared__ float red[128];
  if (t < 64) qs[t] = rq[((size_t)h * NTOK + i) * DHEAD + t];
  else if (t < 69) selb[t - 64] = sel[((h << 11) | i) * 5 + (t - 64)];
  __syncthreads();
  float sim = NEGV;
  if (t < 80) {
    int kb = selb[t >> 4];
    int pos = (kb << 4) + (t & 15);
    if (kb >= 0 && pos <= i) {
      const float* kr = rk + ((size_t)h * NTOK + pos) * DHEAD;
      float dsum = 0.f;
      for (int e = 0; e < 64; ++e) dsum = fmaf(qs[e], kr[e], dsum);
      sim = dsum * 0.125f;
    }
  }
  p[t] = sim;
  red[t] = sim;
  __syncthreads();
  for (int o = 64; o > 0; o >>= 1) { if (t < o) red[t] = fmaxf(red[t], red[t + o]); __syncthreads(); }
  float mx = red[0];
  __syncthreads();
  float e = (t < 80) ? __expf(sim - mx) : 0.f;
  red[t] = e;
  __syncthreads();
  for (int o = 64; o > 0; o >>= 1) { if (t < o) red[t] += red[t + o]; __syncthreads(); }
  float invs = 1.f / red[0];
  __syncthreads();
  p[t] = e * invs;
  __syncthreads();
  if (t < 64) {
    float acc = 0.f;
    for (int j = 0; j < 80; ++j) {
      int kb = selb[j >> 4];
      if (kb < 0) continue;
      int pos = (kb << 4) + (j & 15);
      acc = fmaf(p[j], v[((size_t)h * NTOK + pos) * DHEAD + t], acc);
    }
    f_out[((size_t)h * NTOK + i) * DHEAD + t] = acc;
  }
}

// ---------------- sliding-window attention ----------------
__global__ void k_slide_attn(const float* __restrict__ rq, const float* __restrict__ rk,
                             const float* __restrict__ v, float* __restrict__ s_out) {
  const int h = blockIdx.x >> 11;
  const int i = blockIdx.x & 2047;
  const int t = threadIdx.x;
  __shared__ float qs[64];
  __shared__ float p[64];
  qs[t] = rq[((size_t)h * NTOK + i) * DHEAD + t];
  __syncthreads();
  int pos = i - 63 + t;
  float sim = NEGV;
  if (pos >= 0) {
    const float* kr = rk + ((size_t)h * NTOK + pos) * DHEAD;
    float dsum = 0.f;
    for (int e = 0; e < 64; ++e) dsum = fmaf(qs[e], kr[e], dsum);
    sim = dsum * 0.125f;
  }
  float mx = sim;
  for (int o = 32; o > 0; o >>= 1) mx = fmaxf(mx, __shfl_xor(mx, o));
  float e = (pos >= 0) ? __expf(sim - mx) : 0.f;
  float tot = e;
  for (int o = 32; o > 0; o >>= 1) tot += __shfl_xor(tot, o);
  p[t] = e / tot;
  __syncthreads();
  float acc = 0.f;
  for (int j = 0; j < 64; ++j) {
    int pj = i - 63 + j;
    if (pj < 0) continue;
    acc = fmaf(p[j], v[((size_t)h * NTOK + pj) * DHEAD + t], acc);
  }
  s_out[((size_t)h * NTOK + i) * DHEAD + t] = acc;
}

// ---------------- gate + combine -> bf16 ----------------
__global__ void k_combine(const float* __restrict__ strat, const float* __restrict__ c_out,
                          const float* __restrict__ f_out, const float* __restrict__ s_out,
                          bf16* __restrict__ comb) {
  int idx = blockIdx.x * 256 + threadIdx.x;
  int i = idx >> 9;
  int c = idx & 511;
  int h = c >> 6, d = c & 63;
  size_t a = ((size_t)h * NTOK + i) * DHEAD + d;
  const float* st = strat + (size_t)i * 24 + h * 3;
  comb[idx] = __float2bfloat16(st[0] * c_out[a] + st[1] * f_out[a] + st[2] * s_out[a]);
}

extern "C" void kernel_launch(void* const* d_in, const int* in_sizes, int n_in,
                              void* d_out, int out_size, void* d_ws, size_t ws_size,
                              hipStream_t stream) {
  const float* x      = (const float*)d_in[0];
  const float* g_norm = (const float*)d_in[1];
  const float* w_qkv  = (const float*)d_in[2];
  const float* k_pos  = (const float*)d_in[3];
  const float* v_pos  = (const float*)d_in[4];
  const float* mem_kv = (const float*)d_in[5];
  const float* k_w1   = (const float*)d_in[6];
  const float* k_b1   = (const float*)d_in[7];
  const float* k_w2   = (const float*)d_in[8];
  const float* k_b2   = (const float*)d_in[9];
  const float* v_w1   = (const float*)d_in[10];
  const float* v_b1   = (const float*)d_in[11];
  const float* v_w2   = (const float*)d_in[12];
  const float* v_b2   = (const float*)d_in[13];
  const float* w_comb = (const float*)d_in[14];
  const float* b_comb = (const float*)d_in[15];
  const float* w_out  = (const float*)d_in[16];
  float* out = (float*)d_out;
  char* wsb = (char*)d_ws;

  bf16* WQKV_H = (bf16*)(wsb + B_WQKV_H);
  bf16* WQKV_L = (bf16*)(wsb + B_WQKV_L);
  bf16* KW1_H  = (bf16*)(wsb + B_KW1_H);
  bf16* KW1_L  = (bf16*)(wsb + B_KW1_L);
  bf16* KW2_H  = (bf16*)(wsb + B_KW2_H);
  bf16* KW2_L  = (bf16*)(wsb + B_KW2_L);
  bf16* VW1_H  = (bf16*)(wsb + B_VW1_H);
  bf16* VW2_H  = (bf16*)(wsb + B_VW2_H);
  bf16* WOUT_H = (bf16*)(wsb + B_WOUT_H);
  bf16* HB_H   = (bf16*)(wsb + B_HB_H);
  bf16* HB_L   = (bf16*)(wsb + B_HB_L);
  float* Q     = (float*)(wsb + B_Q);
  float* K_    = (float*)(wsb + B_K);
  float* V     = (float*)(wsb + B_V);
  float* RQ    = (float*)(wsb + B_RQ);
  float* RK    = (float*)(wsb + B_RK);
  float* CK    = (float*)(wsb + B_CK);
  float* CV    = (float*)(wsb + B_CV);
  float* COUT  = (float*)(wsb + B_COUT);
  float* FOUT  = (float*)(wsb + B_FOUT);
  float* SOUT  = (float*)(wsb + B_SOUT);
  float* STRAT = (float*)(wsb + B_STRAT);
  int*   SEL   = (int*)(wsb + B_SEL);
  bf16* KW_H   = (bf16*)(wsb + B_KW_H);
  bf16* KW_L   = (bf16*)(wsb + B_KW_L);
  bf16* VW_H   = (bf16*)(wsb + B_VW_H);
  bf16* HID_H  = (bf16*)(wsb + B_HID_H);
  bf16* HID_L  = (bf16*)(wsb + B_HID_L);
  bf16* COMBB  = (bf16*)(wsb + B_COMBB);

  // weight splits
  k_wt<<<dim3(16, 48), 256, 0, stream>>>(w_qkv, WQKV_H, WQKV_L, DMODEL, 1536);
  k_wt<<<dim3(32, 32), 256, 0, stream>>>(k_w1, KW1_H, KW1_L, CDIM, CDIM);
  k_wt<<<dim3(32, 2),  256, 0, stream>>>(k_w2, KW2_H, KW2_L, CDIM, DHEAD);
  k_wt<<<dim3(32, 32), 256, 0, stream>>>(v_w1, VW1_H, nullptr, CDIM, CDIM);
  k_wt<<<dim3(32, 2),  256, 0, stream>>>(v_w2, VW2_H, nullptr, CDIM, DHEAD);
  k_wt<<<dim3(16, 16), 256, 0, stream>>>(w_out, WOUT_H, nullptr, DMODEL, DMODEL);

  // 1. RMSNorm -> hi/lo
  k_rmsnorm<<<NTOK, 256, 0, stream>>>(x, g_norm, HB_H, HB_L);
  // 2. qkv projection (compensated) with fused scatter -> Q,K,V fp32
  k_cgemm<0, 3, 1><<<dim3(24, 32), 256, 0, stream>>>(
      HB_H, HB_L, WQKV_H, WQKV_L, nullptr, nullptr, nullptr, nullptr, Q, K_, V,
      NTOK, DMODEL, 1536);
  // 3. RoPE
  k_rope<<<2048, 256, 0, stream>>>(Q, K_, RQ, RK);
  // 4. windows: KW hi/lo, VW hi
  k_windows<<<8128, 256, 0, stream>>>(K_, V, k_pos, v_pos, KW_H, KW_L, VW_H);
  // 5. k-MLP (compensated; feeds selection)
  k_cgemm<1, 2, 1><<<dim3(16, 32), 256, 0, stream>>>(
      KW_H, KW_L, KW1_H, KW1_L, k_b1, nullptr, HID_H, HID_L, nullptr, nullptr, nullptr,
      NHEAD * NWIN, CDIM, CDIM);
  k_cgemm<0, 0, 1><<<dim3(1, 32), 256, 0, stream>>>(
      HID_H, HID_L, KW2_H, KW2_L, k_b2, CK, nullptr, nullptr, nullptr, nullptr, nullptr,
      NHEAD * NWIN, CDIM, DHEAD);
  // 6. v-MLP (plain bf16; values only)
  k_cgemm<1, 1, 0><<<dim3(16, 32), 256, 0, stream>>>(
      VW_H, nullptr, VW1_H, nullptr, v_b1, nullptr, HID_H, nullptr, nullptr, nullptr, nullptr,
      NHEAD * NWIN, CDIM, CDIM);
  k_cgemm<0, 0, 0><<<dim3(1, 32), 256, 0, stream>>>(
      HID_H, nullptr, VW2_H, nullptr, v_b2, CV, nullptr, nullptr, nullptr, nullptr, nullptr,
      NHEAD * NWIN, CDIM, DHEAD);
  // 7. compression attention + selection (fp32)
  k_comp_attn<<<NHEAD * NTOK, 256, 0, stream>>>(Q, CK, CV, mem_kv, COUT, SEL);
  // 8. fine attention
  k_fine_attn<<<NHEAD * NTOK, 128, 0, stream>>>(RQ, RK, V, SEL, FOUT);
  // 9. sliding-window attention
  k_slide_attn<<<NHEAD * NTOK, 64, 0, stream>>>(RQ, RK, V, SOUT);
  // 10. strategy gates (fp32 accum from hi+lo)
  k_gemm_hl<<<dim3(1, 64), 256, 0, stream>>>(HB_H, HB_L, w_comb, b_comb, STRAT,
                                             NTOK, DMODEL, 24);
  // 11. gated combination -> bf16
  k_combine<<<4096, 256, 0, stream>>>(STRAT, COUT, FOUT, SOUT, COMBB);
  // 12. output projection (plain bf16) -> fp32 out
  k_cgemm<0, 0, 0><<<dim3(8, 32), 256, 0, stream>>>(
      COMBB, nullptr, WOUT_H, nullptr, nullptr, out, nullptr, nullptr, nullptr, nullptr, nullptr,
      NTOK, DMODEL, DMODEL);
}

// Round 5
// 461.504 us; speedup vs baseline: 2.8265x; 1.4022x over previous
//
#include <hip/hip_runtime.h>
#include <hip/hip_bf16.h>
#include <cstddef>

#define NTOK 2048
#define DMODEL 512
#define NHEAD 8
#define DHEAD 64
#define NWIN 254          // (2048-16)/8 + 1
#define CDIM 1024         // CB*DH
#define NEGV -1000000000.0f

typedef __attribute__((ext_vector_type(8))) __bf16 bf16x8;
typedef __attribute__((ext_vector_type(4))) float f32x4;
typedef __hip_bfloat16 bf16;

// ---------------- workspace layout (byte offsets), total ~60.3 MB ----------------
static const size_t B_WQKV_H = 0;          // 1536*512*2
static const size_t B_WQKV_L = 1572864;
static const size_t B_KW1_H  = 3145728;    // 1024*1024*2
static const size_t B_KW1_L  = 5242880;
static const size_t B_KW2_H  = 7340032;    // 64*1024*2
static const size_t B_KW2_L  = 7471104;
static const size_t B_VW1_H  = 7602176;
static const size_t B_VW2_H  = 9699328;
static const size_t B_WOUT_H = 9830400;    // 512*512*2
static const size_t B_HB_H   = 10354688;   // 2048*512*2
static const size_t B_HB_L   = 12451840;
static const size_t B_QBH    = 14548992;   // 8*2048*64*2 (non-roped q, hi)
static const size_t B_QBL    = 16646144;   // (lo, 3rd term)
static const size_t B_KF     = 18743296;   // 8*2048*64*4 (k fp32, pre-rope)
static const size_t B_VBH    = 22937600;   // 8*2048*64*2
static const size_t B_RQH    = 25034752;   // roped q hi/lo
static const size_t B_RQL    = 27131904;
static const size_t B_RKH    = 29229056;   // 8*2112*64*2 (roped k, 64 zero-pad rows front)
static const size_t B_RKL    = 31391744;
static const size_t B_VTB    = 33554432;   // 8*64*2112*2 (v^T, 64 zero-pad cols front)
static const size_t B_CKT_H  = 35717120;   // 8*256*64*2 (compressed k rows, j=0 mem)
static const size_t B_CKT_L  = 35979264;
static const size_t B_CVT    = 36241408;   // 8*64*256*2 (compressed v transposed)
static const size_t B_STRAT  = 36503552;   // 2048*24*4
static const size_t B_SEL    = 36700160;   // 8*2048*5*4
static const size_t B_COUT   = 37027840;   // 4194304 (overlays KW_H)
static const size_t B_FOUT   = 41222144;   // 4194304 (overlays KW_L)
static const size_t B_SOUT   = 45416448;   // 4194304 (overlays VW_H)
static const size_t B_KW_H   = B_COUT;     // 2032*1024*2 = 4161536
static const size_t B_KW_L   = B_FOUT;
static const size_t B_VW_H   = B_SOUT;
static const size_t B_HID_H  = 49610752;   // 4161536
static const size_t B_HID_L  = 53772288;   // 4161536
static const size_t B_QBM    = 57933824;   // 8*2048*64*2 (q mid term)
static const size_t B_CKT_M  = 60030976;   // 8*256*64*2; end = 60293120
static const size_t B_COMBB  = B_HID_H;    // 2097152 (after MLPs dead)

// ---------------- RMSNorm -> hi/lo bf16 ----------------
__global__ void k_rmsnorm(const float* __restrict__ x, const float* __restrict__ g,
                          bf16* __restrict__ hbh, bf16* __restrict__ hbl) {
  const int row = blockIdx.x;
  const int t = threadIdx.x;
  __shared__ float wsum[4];
  __shared__ float scale_s;
  const float* xr = x + (size_t)row * DMODEL;
  float s = 0.f;
  for (int c = t; c < DMODEL; c += 256) { float v = xr[c]; s += v * v; }
  for (int o = 32; o > 0; o >>= 1) s += __shfl_down(s, o);
  if ((t & 63) == 0) wsum[t >> 6] = s;
  __syncthreads();
  if (t == 0) {
    float tot = wsum[0] + wsum[1] + wsum[2] + wsum[3];
    scale_s = rsqrtf(tot * (1.f / DMODEL) + 1e-6f);
  }
  __syncthreads();
  float sc = scale_s;
  for (int c = t; c < DMODEL; c += 256) {
    float v = xr[c] * sc * g[c];
    bf16 h1 = __float2bfloat16(v);
    hbh[(size_t)row * DMODEL + c] = h1;
    hbl[(size_t)row * DMODEL + c] = __float2bfloat16(v - __bfloat162float(h1));
  }
}

// ---------------- weight transpose+convert hi(/lo) ----------------
__global__ void k_wt(const float* __restrict__ W, bf16* __restrict__ WTh,
                     bf16* __restrict__ WTl, int K, int N) {
  __shared__ float t[32][33];
  const int k0 = blockIdx.x << 5, n0 = blockIdx.y << 5;
  const int tx = threadIdx.x & 31, ty = threadIdx.x >> 5;
#pragma unroll
  for (int r = 0; r < 4; ++r)
    t[ty + (r << 3)][tx] = W[(size_t)(k0 + ty + (r << 3)) * N + n0 + tx];
  __syncthreads();
#pragma unroll
  for (int r = 0; r < 4; ++r) {
    float val = t[tx][ty + (r << 3)];
    size_t o = (size_t)(n0 + ty + (r << 3)) * K + k0 + tx;
    bf16 h1 = __float2bfloat16(val);
    WTh[o] = h1;
    if (WTl) WTl[o] = __float2bfloat16(val - __bfloat162float(h1));
  }
}

// ---------------- MFMA GEMM (optionally Markidis-compensated) ----------------
// OUT: 0 fp32 C; 1 bf16 hi; 2 bf16 hi+lo; 3 qkv scatter (q hi/mid/lo, k fp32, v bf16);
//      5 ckT hi/mid/lo head-shifted; 6 cvT transposed head-shifted.
template <int EPI, int OUT, int COMP>
__global__ void k_cgemm(const bf16* __restrict__ Ah, const bf16* __restrict__ Al,
                        const bf16* __restrict__ Wh, const bf16* __restrict__ Wl,
                        const float* __restrict__ bias,
                        float* __restrict__ Cf, bf16* __restrict__ P0,
                        bf16* __restrict__ P1, bf16* __restrict__ P2,
                        bf16* __restrict__ P3,
                        int M, int K, int N) {
  const int lane = threadIdx.x & 63;
  const int w = threadIdx.x >> 6;
  const int wr = w >> 1, wc = w & 1;
  const int row_base = (blockIdx.y << 6) + (wr << 5);
  const int col_base = (blockIdx.x << 6) + (wc << 5);
  const int lr = lane & 15;
  const int kg = (lane >> 4) << 3;

  int ar0 = row_base + lr;       if (ar0 > M - 1) ar0 = M - 1;
  int ar1 = row_base + 16 + lr;  if (ar1 > M - 1) ar1 = M - 1;
  const size_t a0o = (size_t)ar0 * K + kg;
  const size_t a1o = (size_t)ar1 * K + kg;
  const size_t b0o = (size_t)(col_base + lr) * K + kg;
  const size_t b1o = (size_t)(col_base + 16 + lr) * K + kg;

  f32x4 acc00 = {}, acc01 = {}, acc10 = {}, acc11 = {};
  for (int k0 = 0; k0 < K; k0 += 32) {
    bf16x8 ah0 = *reinterpret_cast<const bf16x8*>(Ah + a0o + k0);
    bf16x8 ah1 = *reinterpret_cast<const bf16x8*>(Ah + a1o + k0);
    bf16x8 bh0 = *reinterpret_cast<const bf16x8*>(Wh + b0o + k0);
    bf16x8 bh1 = *reinterpret_cast<const bf16x8*>(Wh + b1o + k0);
    acc00 = __builtin_amdgcn_mfma_f32_16x16x32_bf16(ah0, bh0, acc00, 0, 0, 0);
    acc01 = __builtin_amdgcn_mfma_f32_16x16x32_bf16(ah0, bh1, acc01, 0, 0, 0);
    acc10 = __builtin_amdgcn_mfma_f32_16x16x32_bf16(ah1, bh0, acc10, 0, 0, 0);
    acc11 = __builtin_amdgcn_mfma_f32_16x16x32_bf16(ah1, bh1, acc11, 0, 0, 0);
    if constexpr (COMP) {
      bf16x8 al0 = *reinterpret_cast<const bf16x8*>(Al + a0o + k0);
      bf16x8 al1 = *reinterpret_cast<const bf16x8*>(Al + a1o + k0);
      bf16x8 bl0 = *reinterpret_cast<const bf16x8*>(Wl + b0o + k0);
      bf16x8 bl1 = *reinterpret_cast<const bf16x8*>(Wl + b1o + k0);
      acc00 = __builtin_amdgcn_mfma_f32_16x16x32_bf16(ah0, bl0, acc00, 0, 0, 0);
      acc01 = __builtin_amdgcn_mfma_f32_16x16x32_bf16(ah0, bl1, acc01, 0, 0, 0);
      acc10 = __builtin_amdgcn_mfma_f32_16x16x32_bf16(ah1, bl0, acc10, 0, 0, 0);
      acc11 = __builtin_amdgcn_mfma_f32_16x16x32_bf16(ah1, bl1, acc11, 0, 0, 0);
      acc00 = __builtin_amdgcn_mfma_f32_16x16x32_bf16(al0, bh0, acc00, 0, 0, 0);
      acc01 = __builtin_amdgcn_mfma_f32_16x16x32_bf16(al0, bh1, acc01, 0, 0, 0);
      acc10 = __builtin_amdgcn_mfma_f32_16x16x32_bf16(al1, bh0, acc10, 0, 0, 0);
      acc11 = __builtin_amdgcn_mfma_f32_16x16x32_bf16(al1, bh1, acc11, 0, 0, 0);
    }
  }

  const int crow = (lane >> 4) << 2;
  f32x4 accs[2][2] = {acc00, acc01, acc10, acc11};
#pragma unroll
  for (int mi = 0; mi < 2; ++mi) {
#pragma unroll
    for (int ni = 0; ni < 2; ++ni) {
      int col = col_base + (ni << 4) + lr;
      float bv = bias ? bias[col] : 0.f;
#pragma unroll
      for (int r = 0; r < 4; ++r) {
        int row = row_base + (mi << 4) + crow + r;
        if (row < M) {
          float vv = accs[mi][ni][r] + bv;
          if (EPI == 1) vv = fmaxf(vv, 0.f);
          if constexpr (OUT == 0) {
            Cf[(size_t)row * N + col] = vv;
          } else if constexpr (OUT == 1) {
            P0[(size_t)row * N + col] = __float2bfloat16(vv);
          } else if constexpr (OUT == 2) {
            bf16 h1 = __float2bfloat16(vv);
            P0[(size_t)row * N + col] = h1;
            P1[(size_t)row * N + col] = __float2bfloat16(vv - __bfloat162float(h1));
          } else if constexpr (OUT == 3) {
            int which = col >> 9, rem = col & 511;
            int hh = rem >> 6, dd = rem & 63;
            size_t o = ((size_t)hh * NTOK + row) * DHEAD + dd;
            if (which == 0) {
              bf16 h1 = __float2bfloat16(vv);
              float r1 = vv - __bfloat162float(h1);
              bf16 m1 = __float2bfloat16(r1);
              P0[o] = h1;
              P1[o] = m1;
              P3[o] = __float2bfloat16(r1 - __bfloat162float(m1));
            } else if (which == 1) {
              Cf[o] = vv;
            } else {
              P2[o] = __float2bfloat16(vv);
            }
          } else if constexpr (OUT == 5) {
            int hh = row / NWIN, jj = row - hh * NWIN;
            size_t o = ((size_t)hh * 256 + 1 + jj) * 64 + col;
            bf16 h1 = __float2bfloat16(vv);
            float r1 = vv - __bfloat162float(h1);
            bf16 m1 = __float2bfloat16(r1);
            P0[o] = h1;
            P1[o] = m1;
            P3[o] = __float2bfloat16(r1 - __bfloat162float(m1));
          } else if constexpr (OUT == 6) {
            int hh = row / NWIN, jj = row - hh * NWIN;
            P0[((size_t)hh * 64 + col) * 256 + 1 + jj] = __float2bfloat16(vv);
          }
        }
      }
    }
  }
}

// ---------------- strat GEMM (fp32 accum, sigmoid) ----------------
__global__ void k_gemm_hl(const bf16* __restrict__ Ah, const bf16* __restrict__ Al,
                          const float* __restrict__ W, const float* __restrict__ bias,
                          float* __restrict__ C, int M, int K, int Nc) {
  __shared__ float As[32][33];
  __shared__ float Ws[32][33];
  const int tx = threadIdx.x & 31;
  const int ty = threadIdx.x >> 5;
  const int row0 = blockIdx.y << 5;
  const int col0 = blockIdx.x << 5;
  const int col = col0 + tx;
  float acc[4] = {0.f, 0.f, 0.f, 0.f};
  for (int k0 = 0; k0 < K; k0 += 32) {
#pragma unroll
    for (int r = 0; r < 4; ++r) {
      int rr = ty + (r << 3);
      int grow = row0 + rr;
      size_t ao = (size_t)grow * K + k0 + tx;
      As[rr][tx] = (grow < M) ? (__bfloat162float(Ah[ao]) + __bfloat162float(Al[ao])) : 0.f;
      Ws[rr][tx] = (col < Nc) ? W[(size_t)(k0 + rr) * Nc + col] : 0.f;
    }
    __syncthreads();
#pragma unroll
    for (int kk = 0; kk < 32; ++kk) {
      float wv = Ws[kk][tx];
#pragma unroll
      for (int r = 0; r < 4; ++r) acc[r] = fmaf(As[ty + (r << 3)][kk], wv, acc[r]);
    }
    __syncthreads();
  }
  if (col < Nc) {
#pragma unroll
    for (int r = 0; r < 4; ++r) {
      int grow = row0 + ty + (r << 3);
      if (grow < M)
        C[(size_t)grow * Nc + col] = 1.f / (1.f + expf(-(acc[r] + bias[col])));
    }
  }
}

// ---------------- zero-pad fronts of rkh/rkl rows and vtb cols ----------------
__global__ void k_zpad(bf16* __restrict__ rkh, bf16* __restrict__ rkl,
                       bf16* __restrict__ vtb) {
  int idx = blockIdx.x * 256 + threadIdx.x;   // 8*64*64 = 32768 exact
  int h = idx >> 12;
  int r = (idx >> 6) & 63;
  int c = idx & 63;
  bf16 z = __float2bfloat16(0.f);
  rkh[((size_t)h * 2112 + r) * 64 + c] = z;
  rkl[((size_t)h * 2112 + r) * 64 + c] = z;
  vtb[((size_t)h * 64 + r) * 2112 + c] = z;
}

// ---------------- RoPE: q(hi/mid/lo bf16) + k(fp32) -> roped hi/lo bf16 ----------------
__global__ void k_rope(const bf16* __restrict__ qbh, const bf16* __restrict__ qbm,
                       const bf16* __restrict__ qbl, const float* __restrict__ kf,
                       bf16* __restrict__ rqh, bf16* __restrict__ rql,
                       bf16* __restrict__ rkh, bf16* __restrict__ rkl) {
  int idx = blockIdx.x * 256 + threadIdx.x;   // 8*2048*32 exact
  int i = idx & 31;
  int n = (idx >> 5) & (NTOK - 1);
  int h = idx >> 16;
  float ex = (float)(2 * i) * (1.f / 64.f);
  float inv = exp2f(-ex * 13.287712379549449f);
  float ang = (float)n * inv;
  float sn, cs;
  sincosf(ang, &sn, &cs);
  size_t base = ((size_t)h * NTOK + n) * DHEAD + 2 * i;
  float q1 = __bfloat162float(qbh[base]) + __bfloat162float(qbm[base]) + __bfloat162float(qbl[base]);
  float q2 = __bfloat162float(qbh[base + 1]) + __bfloat162float(qbm[base + 1]) + __bfloat162float(qbl[base + 1]);
  float r1 = q1 * cs - q2 * sn, r2 = q1 * sn + q2 * cs;
  bf16 h1 = __float2bfloat16(r1);
  rqh[base] = h1; rql[base] = __float2bfloat16(r1 - __bfloat162float(h1));
  h1 = __float2bfloat16(r2);
  rqh[base + 1] = h1; rql[base + 1] = __float2bfloat16(r2 - __bfloat162float(h1));
  float k1 = kf[base], k2 = kf[base + 1];
  float s1 = k1 * cs - k2 * sn, s2 = k1 * sn + k2 * cs;
  size_t kb = ((size_t)h * 2112 + 64 + n) * DHEAD + 2 * i;
  h1 = __float2bfloat16(s1);
  rkh[kb] = h1; rkl[kb] = __float2bfloat16(s1 - __bfloat162float(h1));
  h1 = __float2bfloat16(s2);
  rkh[kb + 1] = h1; rkl[kb + 1] = __float2bfloat16(s2 - __bfloat162float(h1));
}

// ---------------- transpose vbh -> vtb (+64 col pad) ----------------
__global__ void k_vt(const bf16* __restrict__ vbh, bf16* __restrict__ vtb) {
  __shared__ bf16 tile[64][65];
  int h = blockIdx.y, n0 = blockIdx.x << 6;
  int tx = threadIdx.x & 63, ty = threadIdx.x >> 6;
  for (int r = ty; r < 64; r += 4)
    tile[r][tx] = vbh[((size_t)h * NTOK + n0 + r) * DHEAD + tx];
  __syncthreads();
  for (int r = ty; r < 64; r += 4)
    vtb[((size_t)h * 64 + r) * 2112 + 64 + n0 + tx] = tile[tx][r];
}

// ---------------- compression windows: KW hi/lo (from k fp32), VW hi ----------------
__global__ void k_windows(const float* __restrict__ kf, const bf16* __restrict__ vbh,
                          const float* __restrict__ kpos, const float* __restrict__ vpos,
                          bf16* __restrict__ kwh, bf16* __restrict__ kwl,
                          bf16* __restrict__ vwh) {
  int idx = blockIdx.x * 256 + threadIdx.x;   // 8*254*1024 exact
  int d = idx & 63;
  int c = (idx >> 6) & 15;
  int j = (idx >> 10) % NWIN;
  int h = idx / (NWIN << 10);
  int srcpos = (j << 3) + c;
  size_t src = ((size_t)h * NTOK + srcpos) * DHEAD + d;
  size_t pp = ((size_t)h * 16 + c) * DHEAD + d;
  float kv = kf[src] + kpos[pp];
  bf16 h1 = __float2bfloat16(kv);
  kwh[idx] = h1;
  kwl[idx] = __float2bfloat16(kv - __bfloat162float(h1));
  vwh[idx] = __float2bfloat16(__bfloat162float(vbh[src]) + vpos[pp]);
}

// ---------------- fill mem slot (j=0) and zero pad slot (j=255) of ckT/cvT ----------------
__global__ void k_fillmem(const float* __restrict__ memkv, bf16* __restrict__ ckh,
                          bf16* __restrict__ ckm, bf16* __restrict__ ckl,
                          bf16* __restrict__ cvtb) {
  int t = threadIdx.x;            // 512
  int h = t >> 6, e = t & 63;
  float kv = memkv[(size_t)h * DHEAD + e];
  bf16 h1 = __float2bfloat16(kv);
  float r1 = kv - __bfloat162float(h1);
  bf16 m1 = __float2bfloat16(r1);
  ckh[((size_t)h * 256) * 64 + e] = h1;
  ckm[((size_t)h * 256) * 64 + e] = m1;
  ckl[((size_t)h * 256) * 64 + e] = __float2bfloat16(r1 - __bfloat162float(m1));
  bf16 z = __float2bfloat16(0.f);
  ckh[((size_t)h * 256 + 255) * 64 + e] = z;
  ckm[((size_t)h * 256 + 255) * 64 + e] = z;
  ckl[((size_t)h * 256 + 255) * 64 + e] = z;
  float vv = memkv[(size_t)(NHEAD + h) * DHEAD + e];
  cvtb[((size_t)h * 64 + e) * 256 + 0] = __float2bfloat16(vv);
  cvtb[((size_t)h * 64 + e) * 256 + 255] = z;
}

// ---------------- compression attention (MFMA, 32 queries/block) ----------------
// QK^T uses 3-way bf16 splits of q and ck: 6-term product -> ~2^-26 relative error
// (selection-critical; 2-way/3-term at 2^-17 flipped top-4 picks in round 4).
__global__ __launch_bounds__(256) void k_comp_attn(
    const bf16* __restrict__ qbh, const bf16* __restrict__ qbm, const bf16* __restrict__ qbl,
    const bf16* __restrict__ ckh, const bf16* __restrict__ ckm, const bf16* __restrict__ ckl,
    const bf16* __restrict__ cvtb,
    float* __restrict__ c_out, int* __restrict__ sel) {
  const int h = blockIdx.y;
  const int i0 = blockIdx.x << 5;
  const int t = threadIdx.x;
  const int w = t >> 6, lane = t & 63;
  const int lr = lane & 15, kg = (lane >> 4) << 3;
  const int crow = (lane >> 4) << 2;

  __shared__ float p[32][260];     // stride 260: rows 16B-aligned

  // ---- QK^T, 6-term (hh, hm, mh, hl, lh, mm)
  bf16x8 aH[2][2], aM[2][2], aL[2][2];
#pragma unroll
  for (int mi = 0; mi < 2; ++mi) {
    size_t qo = ((size_t)h * NTOK + i0 + mi * 16 + lr) * DHEAD + kg;
#pragma unroll
    for (int ks = 0; ks < 2; ++ks) {
      aH[mi][ks] = *reinterpret_cast<const bf16x8*>(qbh + qo + ks * 32);
      aM[mi][ks] = *reinterpret_cast<const bf16x8*>(qbm + qo + ks * 32);
      aL[mi][ks] = *reinterpret_cast<const bf16x8*>(qbl + qo + ks * 32);
    }
  }
  f32x4 acc[2][4];
#pragma unroll
  for (int a = 0; a < 2; ++a)
#pragma unroll
    for (int b = 0; b < 4; ++b) acc[a][b] = (f32x4){0.f, 0.f, 0.f, 0.f};
#pragma unroll
  for (int ni = 0; ni < 4; ++ni) {
    int col = (w << 6) + (ni << 4) + lr;
    size_t ko = ((size_t)h * 256 + col) * 64 + kg;
#pragma unroll
    for (int ks = 0; ks < 2; ++ks) {
      bf16x8 bH = *reinterpret_cast<const bf16x8*>(ckh + ko + ks * 32);
      bf16x8 bM = *reinterpret_cast<const bf16x8*>(ckm + ko + ks * 32);
      bf16x8 bL = *reinterpret_cast<const bf16x8*>(ckl + ko + ks * 32);
#pragma unroll
      for (int mi = 0; mi < 2; ++mi) {
        acc[mi][ni] = __builtin_amdgcn_mfma_f32_16x16x32_bf16(aH[mi][ks], bH, acc[mi][ni], 0, 0, 0);
        acc[mi][ni] = __builtin_amdgcn_mfma_f32_16x16x32_bf16(aH[mi][ks], bM, acc[mi][ni], 0, 0, 0);
        acc[mi][ni] = __builtin_amdgcn_mfma_f32_16x16x32_bf16(aM[mi][ks], bH, acc[mi][ni], 0, 0, 0);
        acc[mi][ni] = __builtin_amdgcn_mfma_f32_16x16x32_bf16(aH[mi][ks], bL, acc[mi][ni], 0, 0, 0);
        acc[mi][ni] = __builtin_amdgcn_mfma_f32_16x16x32_bf16(aL[mi][ks], bH, acc[mi][ni], 0, 0, 0);
        acc[mi][ni] = __builtin_amdgcn_mfma_f32_16x16x32_bf16(aM[mi][ks], bM, acc[mi][ni], 0, 0, 0);
      }
    }
  }
#pragma unroll
  for (int mi = 0; mi < 2; ++mi)
#pragma unroll
    for (int ni = 0; ni < 4; ++ni) {
      int col = (w << 6) + (ni << 4) + lr;
      int wend = (col == 0) ? -1 : ((col - 1) << 3) + 15;
#pragma unroll
      for (int r = 0; r < 4; ++r) {
        int qi = mi * 16 + crow + r;
        bool ok = (col < 255) && (wend < i0 + qi);
        p[qi][col] = ok ? acc[mi][ni][r] * 0.125f : NEGV;
      }
    }
  __syncthreads();

  // ---- softmax: 8 threads per row
  const int qi = t >> 3, s = t & 7;
  float ev[32];
  float mx = -3.0e38f;
#pragma unroll
  for (int u = 0; u < 32; ++u) { ev[u] = p[qi][s + (u << 3)]; mx = fmaxf(mx, ev[u]); }
  mx = fmaxf(mx, __shfl_xor(mx, 1));
  mx = fmaxf(mx, __shfl_xor(mx, 2));
  mx = fmaxf(mx, __shfl_xor(mx, 4));
  float sum = 0.f;
#pragma unroll
  for (int u = 0; u < 32; ++u) { float e = __expf(ev[u] - mx); ev[u] = e; sum += e; }
  sum += __shfl_xor(sum, 1); sum += __shfl_xor(sum, 2); sum += __shfl_xor(sum, 4);
  float invs = 1.f / sum;
#pragma unroll
  for (int u = 0; u < 32; ++u) p[qi][s + (u << 3)] = ev[u] * invs;
  // same 8 lanes (one wave) own row qi; lockstep LDS ordering suffices until PV barrier

  // ---- block importance in REGISTERS (lane s owns f in [s*16, s*16+16)) + top-4
  int qblk = (i0 + qi) >> 4;
  float vals[16];
#pragma unroll
  for (int u = 0; u < 16; ++u) {
    int f = (s << 4) + u;
    float v;
    if (f >= qblk || f == 127) v = NEGV;
    else v = (p[qi][2 * f + 1] + p[qi][2 * f + 2]) * 0.5f;
    vals[u] = v;
  }
  int base = ((h << 11) | (i0 + qi)) * 5;
  for (int kk = 0; kk < 4; ++kk) {
    float bv = -3.0e38f; int bi = 0;
#pragma unroll
    for (int u = 0; u < 16; ++u) {
      if (vals[u] > bv) { bv = vals[u]; bi = (s << 4) + u; }
    }
#pragma unroll
    for (int o = 1; o < 8; o <<= 1) {
      float ov = __shfl_xor(bv, o);
      int oi = __shfl_xor(bi, o);
      if (ov > bv || (ov == bv && oi < bi)) { bv = ov; bi = oi; }
    }
    if (s == 0) sel[base + kk] = (bv > -5.0e8f) ? bi : -1;
    if ((bi >> 4) == s) vals[bi & 15] = -3.0e38f;
  }
  if (s == 0) sel[base + 4] = (i0 + qi) >> 4;
  __syncthreads();

  // ---- PV: M=32 N=64 K=256, p split hi/lo (A), cvT bf16 (B)
  const int wm = w >> 1, wn = w & 1;
  const int arow = wm * 16 + lr;
  f32x4 pacc[2];
#pragma unroll
  for (int b = 0; b < 2; ++b) pacc[b] = (f32x4){0.f, 0.f, 0.f, 0.f};
#pragma unroll
  for (int ks = 0; ks < 8; ++ks) {
    int k0 = ks * 32 + kg;
    float4 x0 = *reinterpret_cast<const float4*>(&p[arow][k0]);
    float4 x1 = *reinterpret_cast<const float4*>(&p[arow][k0 + 4]);
    float xv[8] = {x0.x, x0.y, x0.z, x0.w, x1.x, x1.y, x1.z, x1.w};
    bf16x8 ph, pl;
#pragma unroll
    for (int e = 0; e < 8; ++e) {
      __bf16 hh = (__bf16)xv[e];
      ph[e] = hh;
      pl[e] = (__bf16)(xv[e] - (float)hh);
    }
#pragma unroll
    for (int ni = 0; ni < 2; ++ni) {
      int d = (wn << 5) + (ni << 4) + lr;
      bf16x8 bv = *reinterpret_cast<const bf16x8*>(cvtb + ((size_t)h * 64 + d) * 256 + k0);
      pacc[ni] = __builtin_amdgcn_mfma_f32_16x16x32_bf16(ph, bv, pacc[ni], 0, 0, 0);
      pacc[ni] = __builtin_amdgcn_mfma_f32_16x16x32_bf16(pl, bv, pacc[ni], 0, 0, 0);
    }
  }
#pragma unroll
  for (int ni = 0; ni < 2; ++ni) {
    int d = (wn << 5) + (ni << 4) + lr;
#pragma unroll
    for (int r = 0; r < 4; ++r) {
      int q2 = wm * 16 + crow + r;
      c_out[((size_t)h * NTOK + i0 + q2) * DHEAD + d] = pacc[ni][r];
    }
  }
}

// ---------------- fine attention (bf16 hi/lo inputs) ----------------
__global__ void k_fine_attn(const bf16* __restrict__ rqh, const bf16* __restrict__ rql,
                            const bf16* __restrict__ rkh, const bf16* __restrict__ rkl,
                            const bf16* __restrict__ vbh, const int* __restrict__ sel,
                            float* __restrict__ f_out) {
  const int h = blockIdx.x >> 11;
  const int i = blockIdx.x & 2047;
  const int t = threadIdx.x;
  __shared__ float qs[64];
  __shared__ int selb[5];
  __shared__ float p[128];
  __shared__ float red[128];
  if (t < 64) {
    size_t o = ((size_t)h * NTOK + i) * DHEAD + t;
    qs[t] = __bfloat162float(rqh[o]) + __bfloat162float(rql[o]);
  } else if (t < 69) selb[t - 64] = sel[((h << 11) | i) * 5 + (t - 64)];
  __syncthreads();
  float sim = NEGV;
  if (t < 80) {
    int kb = selb[t >> 4];
    int pos = (kb << 4) + (t & 15);
    if (kb >= 0 && pos <= i) {
      size_t kr = ((size_t)h * 2112 + 64 + pos) * DHEAD;
      float dsum = 0.f;
      for (int e = 0; e < 64; ++e)
        dsum = fmaf(qs[e], __bfloat162float(rkh[kr + e]) + __bfloat162float(rkl[kr + e]), dsum);
      sim = dsum * 0.125f;
    }
  }
  p[t] = sim;
  red[t] = sim;
  __syncthreads();
  for (int o = 64; o > 0; o >>= 1) { if (t < o) red[t] = fmaxf(red[t], red[t + o]); __syncthreads(); }
  float mx = red[0];
  __syncthreads();
  float e = (t < 80) ? __expf(sim - mx) : 0.f;
  red[t] = e;
  __syncthreads();
  for (int o = 64; o > 0; o >>= 1) { if (t < o) red[t] += red[t + o]; __syncthreads(); }
  float invs = 1.f / red[0];
  __syncthreads();
  p[t] = e * invs;
  __syncthreads();
  if (t < 64) {
    float acc = 0.f;
    for (int j = 0; j < 80; ++j) {
      int kb = selb[j >> 4];
      if (kb < 0) continue;
      int pos = (kb << 4) + (j & 15);
      acc = fmaf(p[j], __bfloat162float(vbh[((size_t)h * NTOK + pos) * DHEAD + t]), acc);
    }
    f_out[((size_t)h * NTOK + i) * DHEAD + t] = acc;
  }
}

// ---------------- sliding-window attention (MFMA, 64 queries/block) ----------------
__global__ __launch_bounds__(256) void k_slide_attn(
    const bf16* __restrict__ rqh, const bf16* __restrict__ rql,
    const bf16* __restrict__ rkh, const bf16* __restrict__ rkl,
    const bf16* __restrict__ vtb, float* __restrict__ s_out) {
  const int h = blockIdx.y, nb = blockIdx.x;
  const int t = threadIdx.x, w = t >> 6, lane = t & 63;
  const int lr = lane & 15, kg = (lane >> 4) << 3;
  const int crow = (lane >> 4) << 2;
  const int wm = w >> 1, wn = w & 1;
  __shared__ float p[64][132];

  // QK (compensated 3-term)
  bf16x8 aH[2][2], aL[2][2];
#pragma unroll
  for (int mi = 0; mi < 2; ++mi) {
    size_t qo = ((size_t)h * NTOK + nb * 64 + wm * 32 + mi * 16 + lr) * DHEAD + kg;
#pragma unroll
    for (int ks = 0; ks < 2; ++ks) {
      aH[mi][ks] = *reinterpret_cast<const bf16x8*>(rqh + qo + ks * 32);
      aL[mi][ks] = *reinterpret_cast<const bf16x8*>(rql + qo + ks * 32);
    }
  }
  f32x4 acc[2][4];
#pragma unroll
  for (int a = 0; a < 2; ++a)
#pragma unroll
    for (int b = 0; b < 4; ++b) acc[a][b] = (f32x4){0.f, 0.f, 0.f, 0.f};
#pragma unroll
  for (int ni = 0; ni < 4; ++ni) {
    int col = (wn << 6) + (ni << 4) + lr;
    size_t ko = ((size_t)h * 2112 + nb * 64 + col) * 64 + kg;
#pragma unroll
    for (int ks = 0; ks < 2; ++ks) {
      bf16x8 bH = *reinterpret_cast<const bf16x8*>(rkh + ko + ks * 32);
      bf16x8 bL = *reinterpret_cast<const bf16x8*>(rkl + ko + ks * 32);
#pragma unroll
      for (int mi = 0; mi < 2; ++mi) {
        acc[mi][ni] = __builtin_amdgcn_mfma_f32_16x16x32_bf16(aH[mi][ks], bH, acc[mi][ni], 0, 0, 0);
        acc[mi][ni] = __builtin_amdgcn_mfma_f32_16x16x32_bf16(aL[mi][ks], bH, acc[mi][ni], 0, 0, 0);
        acc[mi][ni] = __builtin_amdgcn_mfma_f32_16x16x32_bf16(aH[mi][ks], bL, acc[mi][ni], 0, 0, 0);
      }
    }
  }
#pragma unroll
  for (int mi = 0; mi < 2; ++mi)
#pragma unroll
    for (int ni = 0; ni < 4; ++ni) {
      int col = (wn << 6) + (ni << 4) + lr;
#pragma unroll
      for (int r = 0; r < 4; ++r) {
        int qi2 = wm * 32 + mi * 16 + crow + r;
        bool ok = (col >= qi2 + 1) && (col <= qi2 + 64) && (nb > 0 || col >= 64);
        p[qi2][col] = ok ? acc[mi][ni][r] * 0.125f : NEGV;
      }
    }
  __syncthreads();

  // softmax: 4 threads per row
  const int qi = t >> 2, s = t & 3;
  float ev[32];
  float mx = -3.0e38f;
#pragma unroll
  for (int u = 0; u < 32; ++u) { ev[u] = p[qi][s + (u << 2)]; mx = fmaxf(mx, ev[u]); }
  mx = fmaxf(mx, __shfl_xor(mx, 1));
  mx = fmaxf(mx, __shfl_xor(mx, 2));
  float sum = 0.f;
#pragma unroll
  for (int u = 0; u < 32; ++u) { float e = __expf(ev[u] - mx); ev[u] = e; sum += e; }
  sum += __shfl_xor(sum, 1); sum += __shfl_xor(sum, 2);
  float invs = 1.f / sum;
#pragma unroll
  for (int u = 0; u < 32; ++u) p[qi][s + (u << 2)] = ev[u] * invs;
  __syncthreads();

  // PV: M=64 N=64 K=128
  f32x4 pacc[2][2];
#pragma unroll
  for (int a = 0; a < 2; ++a)
#pragma unroll
    for (int b = 0; b < 2; ++b) pacc[a][b] = (f32x4){0.f, 0.f, 0.f, 0.f};
#pragma unroll
  for (int ks = 0; ks < 4; ++ks) {
    int k0 = ks * 32 + kg;
    bf16x8 ph[2], pl[2];
#pragma unroll
    for (int mi = 0; mi < 2; ++mi) {
      int arow = wm * 32 + mi * 16 + lr;
      float4 x0 = *reinterpret_cast<const float4*>(&p[arow][k0]);
      float4 x1 = *reinterpret_cast<const float4*>(&p[arow][k0 + 4]);
      float xv[8] = {x0.x, x0.y, x0.z, x0.w, x1.x, x1.y, x1.z, x1.w};
#pragma unroll
      for (int e = 0; e < 8; ++e) {
        __bf16 hh = (__bf16)xv[e];
        ph[mi][e] = hh;
        pl[mi][e] = (__bf16)(xv[e] - (float)hh);
      }
    }
#pragma unroll
    for (int ni = 0; ni < 2; ++ni) {
      int d = (wn << 5) + (ni << 4) + lr;
      bf16x8 bv = *reinterpret_cast<const bf16x8*>(vtb + ((size_t)h * 64 + d) * 2112 + nb * 64 + k0);
#pragma unroll
      for (int mi = 0; mi < 2; ++mi) {
        pacc[mi][ni] = __builtin_amdgcn_mfma_f32_16x16x32_bf16(ph[mi], bv, pacc[mi][ni], 0, 0, 0);
        pacc[mi][ni] = __builtin_amdgcn_mfma_f32_16x16x32_bf16(pl[mi], bv, pacc[mi][ni], 0, 0, 0);
      }
    }
  }
#pragma unroll
  for (int mi = 0; mi < 2; ++mi)
#pragma unroll
    for (int ni = 0; ni < 2; ++ni) {
      int d = (wn << 5) + (ni << 4) + lr;
#pragma unroll
      for (int r = 0; r < 4; ++r) {
        int qi2 = wm * 32 + mi * 16 + crow + r;
        s_out[((size_t)h * NTOK + nb * 64 + qi2) * DHEAD + d] = pacc[mi][ni][r];
      }
    }
}

// ---------------- gate + combine -> bf16 ----------------
__global__ void k_combine(const float* __restrict__ strat, const float* __restrict__ c_out,
                          const float* __restrict__ f_out, const float* __restrict__ s_out,
                          bf16* __restrict__ comb) {
  int idx = blockIdx.x * 256 + threadIdx.x;
  int i = idx >> 9;
  int c = idx & 511;
  int h = c >> 6, d = c & 63;
  size_t a = ((size_t)h * NTOK + i) * DHEAD + d;
  const float* st = strat + (size_t)i * 24 + h * 3;
  comb[idx] = __float2bfloat16(st[0] * c_out[a] + st[1] * f_out[a] + st[2] * s_out[a]);
}

extern "C" void kernel_launch(void* const* d_in, const int* in_sizes, int n_in,
                              void* d_out, int out_size, void* d_ws, size_t ws_size,
                              hipStream_t stream) {
  const float* x      = (const float*)d_in[0];
  const float* g_norm = (const float*)d_in[1];
  const float* w_qkv  = (const float*)d_in[2];
  const float* k_pos  = (const float*)d_in[3];
  const float* v_pos  = (const float*)d_in[4];
  const float* mem_kv = (const float*)d_in[5];
  const float* k_w1   = (const float*)d_in[6];
  const float* k_b1   = (const float*)d_in[7];
  const float* k_w2   = (const float*)d_in[8];
  const float* k_b2   = (const float*)d_in[9];
  const float* v_w1   = (const float*)d_in[10];
  const float* v_b1   = (const float*)d_in[11];
  const float* v_w2   = (const float*)d_in[12];
  const float* v_b2   = (const float*)d_in[13];
  const float* w_comb = (const float*)d_in[14];
  const float* b_comb = (const float*)d_in[15];
  const float* w_out  = (const float*)d_in[16];
  float* out = (float*)d_out;
  char* wsb = (char*)d_ws;

  bf16* WQKV_H = (bf16*)(wsb + B_WQKV_H);
  bf16* WQKV_L = (bf16*)(wsb + B_WQKV_L);
  bf16* KW1_H  = (bf16*)(wsb + B_KW1_H);
  bf16* KW1_L  = (bf16*)(wsb + B_KW1_L);
  bf16* KW2_H  = (bf16*)(wsb + B_KW2_H);
  bf16* KW2_L  = (bf16*)(wsb + B_KW2_L);
  bf16* VW1_H  = (bf16*)(wsb + B_VW1_H);
  bf16* VW2_H  = (bf16*)(wsb + B_VW2_H);
  bf16* WOUT_H = (bf16*)(wsb + B_WOUT_H);
  bf16* HB_H   = (bf16*)(wsb + B_HB_H);
  bf16* HB_L   = (bf16*)(wsb + B_HB_L);
  bf16* QBH    = (bf16*)(wsb + B_QBH);
  bf16* QBM    = (bf16*)(wsb + B_QBM);
  bf16* QBL    = (bf16*)(wsb + B_QBL);
  float* KF    = (float*)(wsb + B_KF);
  bf16* VBH    = (bf16*)(wsb + B_VBH);
  bf16* RQH    = (bf16*)(wsb + B_RQH);
  bf16* RQL    = (bf16*)(wsb + B_RQL);
  bf16* RKH    = (bf16*)(wsb + B_RKH);
  bf16* RKL    = (bf16*)(wsb + B_RKL);
  bf16* VTB    = (bf16*)(wsb + B_VTB);
  bf16* CKT_H  = (bf16*)(wsb + B_CKT_H);
  bf16* CKT_M  = (bf16*)(wsb + B_CKT_M);
  bf16* CKT_L  = (bf16*)(wsb + B_CKT_L);
  bf16* CVT    = (bf16*)(wsb + B_CVT);
  float* STRAT = (float*)(wsb + B_STRAT);
  int*   SEL   = (int*)(wsb + B_SEL);
  float* COUT  = (float*)(wsb + B_COUT);
  float* FOUT  = (float*)(wsb + B_FOUT);
  float* SOUT  = (float*)(wsb + B_SOUT);
  bf16* KW_H   = (bf16*)(wsb + B_KW_H);
  bf16* KW_L   = (bf16*)(wsb + B_KW_L);
  bf16* VW_H   = (bf16*)(wsb + B_VW_H);
  bf16* HID_H  = (bf16*)(wsb + B_HID_H);
  bf16* HID_L  = (bf16*)(wsb + B_HID_L);
  bf16* COMBB  = (bf16*)(wsb + B_COMBB);

  // weight splits
  k_wt<<<dim3(16, 48), 256, 0, stream>>>(w_qkv, WQKV_H, WQKV_L, DMODEL, 1536);
  k_wt<<<dim3(32, 32), 256, 0, stream>>>(k_w1, KW1_H, KW1_L, CDIM, CDIM);
  k_wt<<<dim3(32, 2),  256, 0, stream>>>(k_w2, KW2_H, KW2_L, CDIM, DHEAD);
  k_wt<<<dim3(32, 32), 256, 0, stream>>>(v_w1, VW1_H, nullptr, CDIM, CDIM);
  k_wt<<<dim3(32, 2),  256, 0, stream>>>(v_w2, VW2_H, nullptr, CDIM, DHEAD);
  k_wt<<<dim3(16, 16), 256, 0, stream>>>(w_out, WOUT_H, nullptr, DMODEL, DMODEL);

  k_rmsnorm<<<NTOK, 256, 0, stream>>>(x, g_norm, HB_H, HB_L);
  k_zpad<<<128, 256, 0, stream>>>(RKH, RKL, VTB);
  // qkv (compensated) with fused split/scatter: q->QBH/QBM/QBL, k->KF, v->VBH
  k_cgemm<0, 3, 1><<<dim3(24, 32), 256, 0, stream>>>(
      HB_H, HB_L, WQKV_H, WQKV_L, nullptr, KF, QBH, QBM, VBH, QBL, NTOK, DMODEL, 1536);
  k_rope<<<2048, 256, 0, stream>>>(QBH, QBM, QBL, KF, RQH, RQL, RKH, RKL);
  k_vt<<<dim3(32, 8), 256, 0, stream>>>(VBH, VTB);
  k_windows<<<8128, 256, 0, stream>>>(KF, VBH, k_pos, v_pos, KW_H, KW_L, VW_H);
  // k-MLP (compensated, feeds selection) -> ckT hi/mid/lo
  k_cgemm<1, 2, 1><<<dim3(16, 32), 256, 0, stream>>>(
      KW_H, KW_L, KW1_H, KW1_L, k_b1, nullptr, HID_H, HID_L, nullptr, nullptr,
      NHEAD * NWIN, CDIM, CDIM);
  k_cgemm<0, 5, 1><<<dim3(1, 32), 256, 0, stream>>>(
      HID_H, HID_L, KW2_H, KW2_L, k_b2, nullptr, CKT_H, CKT_M, nullptr, CKT_L,
      NHEAD * NWIN, CDIM, DHEAD);
  // v-MLP (plain) -> cvT
  k_cgemm<1, 1, 0><<<dim3(16, 32), 256, 0, stream>>>(
      VW_H, nullptr, VW1_H, nullptr, v_b1, nullptr, HID_H, nullptr, nullptr, nullptr,
      NHEAD * NWIN, CDIM, CDIM);
  k_cgemm<0, 6, 0><<<dim3(1, 32), 256, 0, stream>>>(
      HID_H, nullptr, VW2_H, nullptr, v_b2, nullptr, CVT, nullptr, nullptr, nullptr,
      NHEAD * NWIN, CDIM, DHEAD);
  k_fillmem<<<1, 512, 0, stream>>>(mem_kv, CKT_H, CKT_M, CKT_L, CVT);
  // attention branches
  k_comp_attn<<<dim3(64, 8), 256, 0, stream>>>(QBH, QBM, QBL, CKT_H, CKT_M, CKT_L, CVT, COUT, SEL);
  k_fine_attn<<<NHEAD * NTOK, 128, 0, stream>>>(RQH, RQL, RKH, RKL, VBH, SEL, FOUT);
  k_slide_attn<<<dim3(32, 8), 256, 0, stream>>>(RQH, RQL, RKH, RKL, VTB, SOUT);
  // gates + combine + output projection
  k_gemm_hl<<<dim3(1, 64), 256, 0, stream>>>(HB_H, HB_L, w_comb, b_comb, STRAT, NTOK, DMODEL, 24);
  k_combine<<<4096, 256, 0, stream>>>(STRAT, COUT, FOUT, SOUT, COMBB);
  k_cgemm<0, 0, 0><<<dim3(8, 32), 256, 0, stream>>>(
      COMBB, nullptr, WOUT_H, nullptr, nullptr, out, nullptr, nullptr, nullptr, nullptr,
      NTOK, DMODEL, DMODEL);
}

// Round 6
// 401.059 us; speedup vs baseline: 3.2525x; 1.1507x over previous
//
#include <hip/hip_runtime.h>
#include <hip/hip_bf16.h>
#include <cstddef>

#define NTOK 2048
#define DMODEL 512
#define NHEAD 8
#define DHEAD 64
#define NWIN 254          // (2048-16)/8 + 1
#define CDIM 1024         // CB*DH
#define NEGV -1000000000.0f

typedef __attribute__((ext_vector_type(8))) __bf16 bf16x8;
typedef __attribute__((ext_vector_type(4))) float f32x4;
typedef __hip_bfloat16 bf16;

// ---------------- workspace layout (byte offsets), total ~60.3 MB ----------------
static const size_t B_WQKV_H = 0;          // 1536*512*2
static const size_t B_WQKV_L = 1572864;
static const size_t B_KW1_H  = 3145728;    // 1024*1024*2
static const size_t B_KW1_L  = 5242880;
static const size_t B_KW2_H  = 7340032;    // 64*1024*2
static const size_t B_KW2_L  = 7471104;
static const size_t B_VW1_H  = 7602176;
static const size_t B_VW2_H  = 9699328;
static const size_t B_WOUT_H = 9830400;    // 512*512*2
static const size_t B_HB_H   = 10354688;   // 2048*512*2
static const size_t B_HB_L   = 12451840;
static const size_t B_QBH    = 14548992;   // 8*2048*64*2 (non-roped q, hi)
static const size_t B_QBL    = 16646144;   // (lo, 3rd term)
static const size_t B_KF     = 18743296;   // 8*2048*64*4 (k fp32, pre-rope)
static const size_t B_VBH    = 22937600;   // 8*2048*64*2
static const size_t B_RQH    = 25034752;   // roped q hi/lo
static const size_t B_RQL    = 27131904;
static const size_t B_RKH    = 29229056;   // 8*2112*64*2 (roped k, 64 zero-pad rows front)
static const size_t B_RKL    = 31391744;
static const size_t B_VTB    = 33554432;   // 8*64*2112*2 (v^T, 64 zero-pad cols front)
static const size_t B_CKT_H  = 35717120;   // 8*256*64*2 (compressed k rows, j=0 mem)
static const size_t B_CKT_L  = 35979264;
static const size_t B_CVT    = 36241408;   // 8*64*256*2 (compressed v transposed)
static const size_t B_STRAT  = 36503552;   // 2048*24*4
static const size_t B_SEL    = 36700160;   // 8*2048*5*4
static const size_t B_COUT   = 37027840;   // 4194304 (overlays KW_H)
static const size_t B_FOUT   = 41222144;   // 4194304 (overlays KW_L)
static const size_t B_SOUT   = 45416448;   // 4194304 (overlays VW_H)
static const size_t B_KW_H   = B_COUT;     // 2032*1024*2 = 4161536
static const size_t B_KW_L   = B_FOUT;
static const size_t B_VW_H   = B_SOUT;
static const size_t B_HID_H  = 49610752;   // 4161536
static const size_t B_HID_L  = 53772288;   // 4161536
static const size_t B_QBM    = 57933824;   // 8*2048*64*2 (q mid term)
static const size_t B_CKT_M  = 60030976;   // 8*256*64*2; end = 60293120
static const size_t B_COMBB  = B_HID_H;    // 2097152 (after MLPs dead)

// ---------------- RMSNorm -> hi/lo bf16 ----------------
__global__ void k_rmsnorm(const float* __restrict__ x, const float* __restrict__ g,
                          bf16* __restrict__ hbh, bf16* __restrict__ hbl) {
  const int row = blockIdx.x;
  const int t = threadIdx.x;
  __shared__ float wsum[4];
  __shared__ float scale_s;
  const float* xr = x + (size_t)row * DMODEL;
  float s = 0.f;
  for (int c = t; c < DMODEL; c += 256) { float v = xr[c]; s += v * v; }
  for (int o = 32; o > 0; o >>= 1) s += __shfl_down(s, o);
  if ((t & 63) == 0) wsum[t >> 6] = s;
  __syncthreads();
  if (t == 0) {
    float tot = wsum[0] + wsum[1] + wsum[2] + wsum[3];
    scale_s = rsqrtf(tot * (1.f / DMODEL) + 1e-6f);
  }
  __syncthreads();
  float sc = scale_s;
  for (int c = t; c < DMODEL; c += 256) {
    float v = xr[c] * sc * g[c];
    bf16 h1 = __float2bfloat16(v);
    hbh[(size_t)row * DMODEL + c] = h1;
    hbl[(size_t)row * DMODEL + c] = __float2bfloat16(v - __bfloat162float(h1));
  }
}

// ---------------- weight transpose+convert hi(/lo) ----------------
__global__ void k_wt(const float* __restrict__ W, bf16* __restrict__ WTh,
                     bf16* __restrict__ WTl, int K, int N) {
  __shared__ float t[32][33];
  const int k0 = blockIdx.x << 5, n0 = blockIdx.y << 5;
  const int tx = threadIdx.x & 31, ty = threadIdx.x >> 5;
#pragma unroll
  for (int r = 0; r < 4; ++r)
    t[ty + (r << 3)][tx] = W[(size_t)(k0 + ty + (r << 3)) * N + n0 + tx];
  __syncthreads();
#pragma unroll
  for (int r = 0; r < 4; ++r) {
    float val = t[tx][ty + (r << 3)];
    size_t o = (size_t)(n0 + ty + (r << 3)) * K + k0 + tx;
    bf16 h1 = __float2bfloat16(val);
    WTh[o] = h1;
    if (WTl) WTl[o] = __float2bfloat16(val - __bfloat162float(h1));
  }
}

// ---------------- MFMA GEMM (optionally Markidis-compensated) ----------------
// OUT: 0 fp32 C; 1 bf16 hi; 2 bf16 hi+lo; 3 qkv scatter (q hi/mid/lo, k fp32, v bf16);
//      5 ckT hi/mid/lo head-shifted; 6 cvT transposed head-shifted.
template <int EPI, int OUT, int COMP>
__global__ void k_cgemm(const bf16* __restrict__ Ah, const bf16* __restrict__ Al,
                        const bf16* __restrict__ Wh, const bf16* __restrict__ Wl,
                        const float* __restrict__ bias,
                        float* __restrict__ Cf, bf16* __restrict__ P0,
                        bf16* __restrict__ P1, bf16* __restrict__ P2,
                        bf16* __restrict__ P3,
                        int M, int K, int N) {
  const int lane = threadIdx.x & 63;
  const int w = threadIdx.x >> 6;
  const int wr = w >> 1, wc = w & 1;
  const int row_base = (blockIdx.y << 6) + (wr << 5);
  const int col_base = (blockIdx.x << 6) + (wc << 5);
  const int lr = lane & 15;
  const int kg = (lane >> 4) << 3;

  int ar0 = row_base + lr;       if (ar0 > M - 1) ar0 = M - 1;
  int ar1 = row_base + 16 + lr;  if (ar1 > M - 1) ar1 = M - 1;
  const size_t a0o = (size_t)ar0 * K + kg;
  const size_t a1o = (size_t)ar1 * K + kg;
  const size_t b0o = (size_t)(col_base + lr) * K + kg;
  const size_t b1o = (size_t)(col_base + 16 + lr) * K + kg;

  f32x4 acc00 = {}, acc01 = {}, acc10 = {}, acc11 = {};
  for (int k0 = 0; k0 < K; k0 += 32) {
    bf16x8 ah0 = *reinterpret_cast<const bf16x8*>(Ah + a0o + k0);
    bf16x8 ah1 = *reinterpret_cast<const bf16x8*>(Ah + a1o + k0);
    bf16x8 bh0 = *reinterpret_cast<const bf16x8*>(Wh + b0o + k0);
    bf16x8 bh1 = *reinterpret_cast<const bf16x8*>(Wh + b1o + k0);
    acc00 = __builtin_amdgcn_mfma_f32_16x16x32_bf16(ah0, bh0, acc00, 0, 0, 0);
    acc01 = __builtin_amdgcn_mfma_f32_16x16x32_bf16(ah0, bh1, acc01, 0, 0, 0);
    acc10 = __builtin_amdgcn_mfma_f32_16x16x32_bf16(ah1, bh0, acc10, 0, 0, 0);
    acc11 = __builtin_amdgcn_mfma_f32_16x16x32_bf16(ah1, bh1, acc11, 0, 0, 0);
    if constexpr (COMP) {
      bf16x8 al0 = *reinterpret_cast<const bf16x8*>(Al + a0o + k0);
      bf16x8 al1 = *reinterpret_cast<const bf16x8*>(Al + a1o + k0);
      bf16x8 bl0 = *reinterpret_cast<const bf16x8*>(Wl + b0o + k0);
      bf16x8 bl1 = *reinterpret_cast<const bf16x8*>(Wl + b1o + k0);
      acc00 = __builtin_amdgcn_mfma_f32_16x16x32_bf16(ah0, bl0, acc00, 0, 0, 0);
      acc01 = __builtin_amdgcn_mfma_f32_16x16x32_bf16(ah0, bl1, acc01, 0, 0, 0);
      acc10 = __builtin_amdgcn_mfma_f32_16x16x32_bf16(ah1, bl0, acc10, 0, 0, 0);
      acc11 = __builtin_amdgcn_mfma_f32_16x16x32_bf16(ah1, bl1, acc11, 0, 0, 0);
      acc00 = __builtin_amdgcn_mfma_f32_16x16x32_bf16(al0, bh0, acc00, 0, 0, 0);
      acc01 = __builtin_amdgcn_mfma_f32_16x16x32_bf16(al0, bh1, acc01, 0, 0, 0);
      acc10 = __builtin_amdgcn_mfma_f32_16x16x32_bf16(al1, bh0, acc10, 0, 0, 0);
      acc11 = __builtin_amdgcn_mfma_f32_16x16x32_bf16(al1, bh1, acc11, 0, 0, 0);
    }
  }

  const int crow = (lane >> 4) << 2;
  f32x4 accs[2][2] = {acc00, acc01, acc10, acc11};
#pragma unroll
  for (int mi = 0; mi < 2; ++mi) {
#pragma unroll
    for (int ni = 0; ni < 2; ++ni) {
      int col = col_base + (ni << 4) + lr;
      float bv = bias ? bias[col] : 0.f;
#pragma unroll
      for (int r = 0; r < 4; ++r) {
        int row = row_base + (mi << 4) + crow + r;
        if (row < M) {
          float vv = accs[mi][ni][r] + bv;
          if (EPI == 1) vv = fmaxf(vv, 0.f);
          if constexpr (OUT == 0) {
            Cf[(size_t)row * N + col] = vv;
          } else if constexpr (OUT == 1) {
            P0[(size_t)row * N + col] = __float2bfloat16(vv);
          } else if constexpr (OUT == 2) {
            bf16 h1 = __float2bfloat16(vv);
            P0[(size_t)row * N + col] = h1;
            P1[(size_t)row * N + col] = __float2bfloat16(vv - __bfloat162float(h1));
          } else if constexpr (OUT == 3) {
            int which = col >> 9, rem = col & 511;
            int hh = rem >> 6, dd = rem & 63;
            size_t o = ((size_t)hh * NTOK + row) * DHEAD + dd;
            if (which == 0) {
              bf16 h1 = __float2bfloat16(vv);
              float r1 = vv - __bfloat162float(h1);
              bf16 m1 = __float2bfloat16(r1);
              P0[o] = h1;
              P1[o] = m1;
              P3[o] = __float2bfloat16(r1 - __bfloat162float(m1));
            } else if (which == 1) {
              Cf[o] = vv;
            } else {
              P2[o] = __float2bfloat16(vv);
            }
          } else if constexpr (OUT == 5) {
            int hh = row / NWIN, jj = row - hh * NWIN;
            size_t o = ((size_t)hh * 256 + 1 + jj) * 64 + col;
            bf16 h1 = __float2bfloat16(vv);
            float r1 = vv - __bfloat162float(h1);
            bf16 m1 = __float2bfloat16(r1);
            P0[o] = h1;
            P1[o] = m1;
            P3[o] = __float2bfloat16(r1 - __bfloat162float(m1));
          } else if constexpr (OUT == 6) {
            int hh = row / NWIN, jj = row - hh * NWIN;
            P0[((size_t)hh * 64 + col) * 256 + 1 + jj] = __float2bfloat16(vv);
          }
        }
      }
    }
  }
}

// ---------------- strat GEMM (fp32 accum, sigmoid) ----------------
__global__ void k_gemm_hl(const bf16* __restrict__ Ah, const bf16* __restrict__ Al,
                          const float* __restrict__ W, const float* __restrict__ bias,
                          float* __restrict__ C, int M, int K, int Nc) {
  __shared__ float As[32][33];
  __shared__ float Ws[32][33];
  const int tx = threadIdx.x & 31;
  const int ty = threadIdx.x >> 5;
  const int row0 = blockIdx.y << 5;
  const int col0 = blockIdx.x << 5;
  const int col = col0 + tx;
  float acc[4] = {0.f, 0.f, 0.f, 0.f};
  for (int k0 = 0; k0 < K; k0 += 32) {
#pragma unroll
    for (int r = 0; r < 4; ++r) {
      int rr = ty + (r << 3);
      int grow = row0 + rr;
      size_t ao = (size_t)grow * K + k0 + tx;
      As[rr][tx] = (grow < M) ? (__bfloat162float(Ah[ao]) + __bfloat162float(Al[ao])) : 0.f;
      Ws[rr][tx] = (col < Nc) ? W[(size_t)(k0 + rr) * Nc + col] : 0.f;
    }
    __syncthreads();
#pragma unroll
    for (int kk = 0; kk < 32; ++kk) {
      float wv = Ws[kk][tx];
#pragma unroll
      for (int r = 0; r < 4; ++r) acc[r] = fmaf(As[ty + (r << 3)][kk], wv, acc[r]);
    }
    __syncthreads();
  }
  if (col < Nc) {
#pragma unroll
    for (int r = 0; r < 4; ++r) {
      int grow = row0 + ty + (r << 3);
      if (grow < M)
        C[(size_t)grow * Nc + col] = 1.f / (1.f + expf(-(acc[r] + bias[col])));
    }
  }
}

// ---------------- zero-pad fronts of rkh/rkl rows and vtb cols ----------------
__global__ void k_zpad(bf16* __restrict__ rkh, bf16* __restrict__ rkl,
                       bf16* __restrict__ vtb) {
  int idx = blockIdx.x * 256 + threadIdx.x;   // 8*64*64 = 32768 exact
  int h = idx >> 12;
  int r = (idx >> 6) & 63;
  int c = idx & 63;
  bf16 z = __float2bfloat16(0.f);
  rkh[((size_t)h * 2112 + r) * 64 + c] = z;
  rkl[((size_t)h * 2112 + r) * 64 + c] = z;
  vtb[((size_t)h * 64 + r) * 2112 + c] = z;
}

// ---------------- RoPE: q(hi/mid/lo bf16) + k(fp32) -> roped hi/lo bf16 ----------------
__global__ void k_rope(const bf16* __restrict__ qbh, const bf16* __restrict__ qbm,
                       const bf16* __restrict__ qbl, const float* __restrict__ kf,
                       bf16* __restrict__ rqh, bf16* __restrict__ rql,
                       bf16* __restrict__ rkh, bf16* __restrict__ rkl) {
  int idx = blockIdx.x * 256 + threadIdx.x;   // 8*2048*32 exact
  int i = idx & 31;
  int n = (idx >> 5) & (NTOK - 1);
  int h = idx >> 16;
  float ex = (float)(2 * i) * (1.f / 64.f);
  float inv = exp2f(-ex * 13.287712379549449f);
  float ang = (float)n * inv;
  float sn, cs;
  sincosf(ang, &sn, &cs);
  size_t base = ((size_t)h * NTOK + n) * DHEAD + 2 * i;
  float q1 = __bfloat162float(qbh[base]) + __bfloat162float(qbm[base]) + __bfloat162float(qbl[base]);
  float q2 = __bfloat162float(qbh[base + 1]) + __bfloat162float(qbm[base + 1]) + __bfloat162float(qbl[base + 1]);
  float r1 = q1 * cs - q2 * sn, r2 = q1 * sn + q2 * cs;
  bf16 h1 = __float2bfloat16(r1);
  rqh[base] = h1; rql[base] = __float2bfloat16(r1 - __bfloat162float(h1));
  h1 = __float2bfloat16(r2);
  rqh[base + 1] = h1; rql[base + 1] = __float2bfloat16(r2 - __bfloat162float(h1));
  float k1 = kf[base], k2 = kf[base + 1];
  float s1 = k1 * cs - k2 * sn, s2 = k1 * sn + k2 * cs;
  size_t kb = ((size_t)h * 2112 + 64 + n) * DHEAD + 2 * i;
  h1 = __float2bfloat16(s1);
  rkh[kb] = h1; rkl[kb] = __float2bfloat16(s1 - __bfloat162float(h1));
  h1 = __float2bfloat16(s2);
  rkh[kb + 1] = h1; rkl[kb + 1] = __float2bfloat16(s2 - __bfloat162float(h1));
}

// ---------------- transpose vbh -> vtb (+64 col pad) ----------------
__global__ void k_vt(const bf16* __restrict__ vbh, bf16* __restrict__ vtb) {
  __shared__ bf16 tile[64][65];
  int h = blockIdx.y, n0 = blockIdx.x << 6;
  int tx = threadIdx.x & 63, ty = threadIdx.x >> 6;
  for (int r = ty; r < 64; r += 4)
    tile[r][tx] = vbh[((size_t)h * NTOK + n0 + r) * DHEAD + tx];
  __syncthreads();
  for (int r = ty; r < 64; r += 4)
    vtb[((size_t)h * 64 + r) * 2112 + 64 + n0 + tx] = tile[tx][r];
}

// ---------------- compression windows: KW hi/lo (from k fp32), VW hi ----------------
__global__ void k_windows(const float* __restrict__ kf, const bf16* __restrict__ vbh,
                          const float* __restrict__ kpos, const float* __restrict__ vpos,
                          bf16* __restrict__ kwh, bf16* __restrict__ kwl,
                          bf16* __restrict__ vwh) {
  int idx = blockIdx.x * 256 + threadIdx.x;   // 8*254*1024 exact
  int d = idx & 63;
  int c = (idx >> 6) & 15;
  int j = (idx >> 10) % NWIN;
  int h = idx / (NWIN << 10);
  int srcpos = (j << 3) + c;
  size_t src = ((size_t)h * NTOK + srcpos) * DHEAD + d;
  size_t pp = ((size_t)h * 16 + c) * DHEAD + d;
  float kv = kf[src] + kpos[pp];
  bf16 h1 = __float2bfloat16(kv);
  kwh[idx] = h1;
  kwl[idx] = __float2bfloat16(kv - __bfloat162float(h1));
  vwh[idx] = __float2bfloat16(__bfloat162float(vbh[src]) + vpos[pp]);
}

// ---------------- fill mem slot (j=0) and zero pad slot (j=255) of ckT/cvT ----------------
__global__ void k_fillmem(const float* __restrict__ memkv, bf16* __restrict__ ckh,
                          bf16* __restrict__ ckm, bf16* __restrict__ ckl,
                          bf16* __restrict__ cvtb) {
  int t = threadIdx.x;            // 512
  int h = t >> 6, e = t & 63;
  float kv = memkv[(size_t)h * DHEAD + e];
  bf16 h1 = __float2bfloat16(kv);
  float r1 = kv - __bfloat162float(h1);
  bf16 m1 = __float2bfloat16(r1);
  ckh[((size_t)h * 256) * 64 + e] = h1;
  ckm[((size_t)h * 256) * 64 + e] = m1;
  ckl[((size_t)h * 256) * 64 + e] = __float2bfloat16(r1 - __bfloat162float(m1));
  bf16 z = __float2bfloat16(0.f);
  ckh[((size_t)h * 256 + 255) * 64 + e] = z;
  ckm[((size_t)h * 256 + 255) * 64 + e] = z;
  ckl[((size_t)h * 256 + 255) * 64 + e] = z;
  float vv = memkv[(size_t)(NHEAD + h) * DHEAD + e];
  cvtb[((size_t)h * 64 + e) * 256 + 0] = __float2bfloat16(vv);
  cvtb[((size_t)h * 64 + e) * 256 + 255] = z;
}

// ---------------- compression attention (MFMA, 32 queries/block) ----------------
__global__ __launch_bounds__(256) void k_comp_attn(
    const bf16* __restrict__ qbh, const bf16* __restrict__ qbm, const bf16* __restrict__ qbl,
    const bf16* __restrict__ ckh, const bf16* __restrict__ ckm, const bf16* __restrict__ ckl,
    const bf16* __restrict__ cvtb,
    float* __restrict__ c_out, int* __restrict__ sel) {
  const int h = blockIdx.y;
  const int i0 = blockIdx.x << 5;
  const int t = threadIdx.x;
  const int w = t >> 6, lane = t & 63;
  const int lr = lane & 15, kg = (lane >> 4) << 3;
  const int crow = (lane >> 4) << 2;

  __shared__ float p[32][260];     // stride 260: rows 16B-aligned

  // ---- QK^T, 6-term (hh, hm, mh, hl, lh, mm)
  bf16x8 aH[2][2], aM[2][2], aL[2][2];
#pragma unroll
  for (int mi = 0; mi < 2; ++mi) {
    size_t qo = ((size_t)h * NTOK + i0 + mi * 16 + lr) * DHEAD + kg;
#pragma unroll
    for (int ks = 0; ks < 2; ++ks) {
      aH[mi][ks] = *reinterpret_cast<const bf16x8*>(qbh + qo + ks * 32);
      aM[mi][ks] = *reinterpret_cast<const bf16x8*>(qbm + qo + ks * 32);
      aL[mi][ks] = *reinterpret_cast<const bf16x8*>(qbl + qo + ks * 32);
    }
  }
  f32x4 acc[2][4];
#pragma unroll
  for (int a = 0; a < 2; ++a)
#pragma unroll
    for (int b = 0; b < 4; ++b) acc[a][b] = (f32x4){0.f, 0.f, 0.f, 0.f};
#pragma unroll
  for (int ni = 0; ni < 4; ++ni) {
    int col = (w << 6) + (ni << 4) + lr;
    size_t ko = ((size_t)h * 256 + col) * 64 + kg;
#pragma unroll
    for (int ks = 0; ks < 2; ++ks) {
      bf16x8 bH = *reinterpret_cast<const bf16x8*>(ckh + ko + ks * 32);
      bf16x8 bM = *reinterpret_cast<const bf16x8*>(ckm + ko + ks * 32);
      bf16x8 bL = *reinterpret_cast<const bf16x8*>(ckl + ko + ks * 32);
#pragma unroll
      for (int mi = 0; mi < 2; ++mi) {
        acc[mi][ni] = __builtin_amdgcn_mfma_f32_16x16x32_bf16(aH[mi][ks], bH, acc[mi][ni], 0, 0, 0);
        acc[mi][ni] = __builtin_amdgcn_mfma_f32_16x16x32_bf16(aH[mi][ks], bM, acc[mi][ni], 0, 0, 0);
        acc[mi][ni] = __builtin_amdgcn_mfma_f32_16x16x32_bf16(aM[mi][ks], bH, acc[mi][ni], 0, 0, 0);
        acc[mi][ni] = __builtin_amdgcn_mfma_f32_16x16x32_bf16(aH[mi][ks], bL, acc[mi][ni], 0, 0, 0);
        acc[mi][ni] = __builtin_amdgcn_mfma_f32_16x16x32_bf16(aL[mi][ks], bH, acc[mi][ni], 0, 0, 0);
        acc[mi][ni] = __builtin_amdgcn_mfma_f32_16x16x32_bf16(aM[mi][ks], bM, acc[mi][ni], 0, 0, 0);
      }
    }
  }
#pragma unroll
  for (int mi = 0; mi < 2; ++mi)
#pragma unroll
    for (int ni = 0; ni < 4; ++ni) {
      int col = (w << 6) + (ni << 4) + lr;
      int wend = (col == 0) ? -1 : ((col - 1) << 3) + 15;
#pragma unroll
      for (int r = 0; r < 4; ++r) {
        int qi = mi * 16 + crow + r;
        bool ok = (col < 255) && (wend < i0 + qi);
        p[qi][col] = ok ? acc[mi][ni][r] * 0.125f : NEGV;
      }
    }
  __syncthreads();

  // ---- softmax: 8 threads per row
  const int qi = t >> 3, s = t & 7;
  float ev[32];
  float mx = -3.0e38f;
#pragma unroll
  for (int u = 0; u < 32; ++u) { ev[u] = p[qi][s + (u << 3)]; mx = fmaxf(mx, ev[u]); }
  mx = fmaxf(mx, __shfl_xor(mx, 1));
  mx = fmaxf(mx, __shfl_xor(mx, 2));
  mx = fmaxf(mx, __shfl_xor(mx, 4));
  float sum = 0.f;
#pragma unroll
  for (int u = 0; u < 32; ++u) { float e = __expf(ev[u] - mx); ev[u] = e; sum += e; }
  sum += __shfl_xor(sum, 1); sum += __shfl_xor(sum, 2); sum += __shfl_xor(sum, 4);
  float invs = 1.f / sum;
#pragma unroll
  for (int u = 0; u < 32; ++u) p[qi][s + (u << 3)] = ev[u] * invs;
  // same 8 lanes (one wave) own row qi; lockstep LDS ordering suffices until PV barrier

  // ---- block importance in REGISTERS (lane s owns f in [s*16, s*16+16)) + top-4
  int qblk = (i0 + qi) >> 4;
  float vals[16];
#pragma unroll
  for (int u = 0; u < 16; ++u) {
    int f = (s << 4) + u;
    float v;
    if (f >= qblk || f == 127) v = NEGV;
    else v = (p[qi][2 * f + 1] + p[qi][2 * f + 2]) * 0.5f;
    vals[u] = v;
  }
  int base = ((h << 11) | (i0 + qi)) * 5;
  for (int kk = 0; kk < 4; ++kk) {
    float bv = -3.0e38f; int bi = 0;
#pragma unroll
    for (int u = 0; u < 16; ++u) {
      if (vals[u] > bv) { bv = vals[u]; bi = (s << 4) + u; }
    }
#pragma unroll
    for (int o = 1; o < 8; o <<= 1) {
      float ov = __shfl_xor(bv, o);
      int oi = __shfl_xor(bi, o);
      if (ov > bv || (ov == bv && oi < bi)) { bv = ov; bi = oi; }
    }
    if (s == 0) sel[base + kk] = (bv > -5.0e8f) ? bi : -1;
    if ((bi >> 4) == s) vals[bi & 15] = -3.0e38f;
  }
  if (s == 0) sel[base + 4] = (i0 + qi) >> 4;
  __syncthreads();

  // ---- PV: M=32 N=64 K=256, p split hi/lo (A), cvT bf16 (B)
  const int wm = w >> 1, wn = w & 1;
  const int arow = wm * 16 + lr;
  f32x4 pacc[2];
#pragma unroll
  for (int b = 0; b < 2; ++b) pacc[b] = (f32x4){0.f, 0.f, 0.f, 0.f};
#pragma unroll
  for (int ks = 0; ks < 8; ++ks) {
    int k0 = ks * 32 + kg;
    float4 x0 = *reinterpret_cast<const float4*>(&p[arow][k0]);
    float4 x1 = *reinterpret_cast<const float4*>(&p[arow][k0 + 4]);
    float xv[8] = {x0.x, x0.y, x0.z, x0.w, x1.x, x1.y, x1.z, x1.w};
    bf16x8 ph, pl;
#pragma unroll
    for (int e = 0; e < 8; ++e) {
      __bf16 hh = (__bf16)xv[e];
      ph[e] = hh;
      pl[e] = (__bf16)(xv[e] - (float)hh);
    }
#pragma unroll
    for (int ni = 0; ni < 2; ++ni) {
      int d = (wn << 5) + (ni << 4) + lr;
      bf16x8 bv = *reinterpret_cast<const bf16x8*>(cvtb + ((size_t)h * 64 + d) * 256 + k0);
      pacc[ni] = __builtin_amdgcn_mfma_f32_16x16x32_bf16(ph, bv, pacc[ni], 0, 0, 0);
      pacc[ni] = __builtin_amdgcn_mfma_f32_16x16x32_bf16(pl, bv, pacc[ni], 0, 0, 0);
    }
  }
#pragma unroll
  for (int ni = 0; ni < 2; ++ni) {
    int d = (wn << 5) + (ni << 4) + lr;
#pragma unroll
    for (int r = 0; r < 4; ++r) {
      int q2 = wm * 16 + crow + r;
      c_out[((size_t)h * NTOK + i0 + q2) * DHEAD + d] = pacc[ni][r];
    }
  }
}

// ---------------- fine attention: 1 wave per query, vectorized ----------------
// grid (512, 8), block 256 = 4 waves; wave w handles query i = blockIdx.x*4 + w.
__global__ __launch_bounds__(256) void k_fine_attn(
    const bf16* __restrict__ rqh, const bf16* __restrict__ rql,
    const bf16* __restrict__ rkh, const bf16* __restrict__ rkl,
    const bf16* __restrict__ vbh, const int* __restrict__ sel,
    float* __restrict__ f_out) {
  const int h = blockIdx.y;
  const int wid = threadIdx.x >> 6;
  const int lane = threadIdx.x & 63;
  const int i = (blockIdx.x << 2) | wid;

  __shared__ float qs[4][64];
  __shared__ float pb[4][80];
  __shared__ int selb[4][5];

  size_t qoff = ((size_t)h * NTOK + i) * DHEAD + lane;
  qs[wid][lane] = __bfloat162float(rqh[qoff]) + __bfloat162float(rql[qoff]);
  if (lane < 5) selb[wid][lane] = sel[((h << 11) | i) * 5 + lane];
  __syncthreads();

  // ---- QK: lane -> key j=lane (all), j=64+lane (lane<16, own block)
  float sim0 = NEGV, sim1 = NEGV;
  {
    int kb = selb[wid][lane >> 4];
    int pos = (kb << 4) + (lane & 15);
    if (kb >= 0 && pos <= i) {
      const bf16* kh = rkh + ((size_t)h * 2112 + 64 + pos) * DHEAD;
      const bf16* kl = rkl + ((size_t)h * 2112 + 64 + pos) * DHEAD;
      float d = 0.f;
#pragma unroll
      for (int e8 = 0; e8 < 8; ++e8) {
        bf16x8 vh = *reinterpret_cast<const bf16x8*>(kh + e8 * 8);
        bf16x8 vl = *reinterpret_cast<const bf16x8*>(kl + e8 * 8);
#pragma unroll
        for (int e = 0; e < 8; ++e)
          d = fmaf(qs[wid][e8 * 8 + e], (float)vh[e] + (float)vl[e], d);
      }
      sim0 = d * 0.125f;
    }
  }
  if (lane < 16) {
    int kb = selb[wid][4];               // own block, always valid
    int pos = (kb << 4) + lane;
    if (pos <= i) {
      const bf16* kh = rkh + ((size_t)h * 2112 + 64 + pos) * DHEAD;
      const bf16* kl = rkl + ((size_t)h * 2112 + 64 + pos) * DHEAD;
      float d = 0.f;
#pragma unroll
      for (int e8 = 0; e8 < 8; ++e8) {
        bf16x8 vh = *reinterpret_cast<const bf16x8*>(kh + e8 * 8);
        bf16x8 vl = *reinterpret_cast<const bf16x8*>(kl + e8 * 8);
#pragma unroll
        for (int e = 0; e < 8; ++e)
          d = fmaf(qs[wid][e8 * 8 + e], (float)vh[e] + (float)vl[e], d);
      }
      sim1 = d * 0.125f;
    }
  }

  // ---- softmax over 80 (wave shuffles, no barriers)
  float mx = fmaxf(sim0, sim1);
#pragma unroll
  for (int o = 32; o > 0; o >>= 1) mx = fmaxf(mx, __shfl_xor(mx, o));
  float e0 = __expf(sim0 - mx);
  float e1 = __expf(sim1 - mx);        // lanes>=16: sim1=NEGV -> 0
  float sum = e0 + e1;
#pragma unroll
  for (int o = 32; o > 0; o >>= 1) sum += __shfl_xor(sum, o);
  float invs = 1.f / sum;
  pb[wid][lane] = e0 * invs;
  if (lane < 16) pb[wid][64 + lane] = e1 * invs;
  // same wave writes & reads pb[wid]: DS ops are wave-ordered, no barrier needed

  // ---- PV: lane = dim d; p broadcast from LDS, coalesced v loads
  float acc = 0.f;
#pragma unroll
  for (int b = 0; b < 5; ++b) {
    int kb = selb[wid][b];
    if (kb < 0) continue;
    const bf16* vr = vbh + ((size_t)h * NTOK + ((size_t)kb << 4)) * DHEAD + lane;
#pragma unroll
    for (int u = 0; u < 16; ++u)
      acc = fmaf(pb[wid][b * 16 + u], __bfloat162float(vr[(size_t)u * DHEAD]), acc);
  }
  f_out[((size_t)h * NTOK + i) * DHEAD + lane] = acc;
}

// ---------------- sliding-window attention (MFMA, 64 queries/block) ----------------
__global__ __launch_bounds__(256) void k_slide_attn(
    const bf16* __restrict__ rqh, const bf16* __restrict__ rql,
    const bf16* __restrict__ rkh, const bf16* __restrict__ rkl,
    const bf16* __restrict__ vtb, float* __restrict__ s_out) {
  const int h = blockIdx.y, nb = blockIdx.x;
  const int t = threadIdx.x, w = t >> 6, lane = t & 63;
  const int lr = lane & 15, kg = (lane >> 4) << 3;
  const int crow = (lane >> 4) << 2;
  const int wm = w >> 1, wn = w & 1;
  __shared__ float p[64][132];

  // QK (compensated 3-term)
  bf16x8 aH[2][2], aL[2][2];
#pragma unroll
  for (int mi = 0; mi < 2; ++mi) {
    size_t qo = ((size_t)h * NTOK + nb * 64 + wm * 32 + mi * 16 + lr) * DHEAD + kg;
#pragma unroll
    for (int ks = 0; ks < 2; ++ks) {
      aH[mi][ks] = *reinterpret_cast<const bf16x8*>(rqh + qo + ks * 32);
      aL[mi][ks] = *reinterpret_cast<const bf16x8*>(rql + qo + ks * 32);
    }
  }
  f32x4 acc[2][4];
#pragma unroll
  for (int a = 0; a < 2; ++a)
#pragma unroll
    for (int b = 0; b < 4; ++b) acc[a][b] = (f32x4){0.f, 0.f, 0.f, 0.f};
#pragma unroll
  for (int ni = 0; ni < 4; ++ni) {
    int col = (wn << 6) + (ni << 4) + lr;
    size_t ko = ((size_t)h * 2112 + nb * 64 + col) * 64 + kg;
#pragma unroll
    for (int ks = 0; ks < 2; ++ks) {
      bf16x8 bH = *reinterpret_cast<const bf16x8*>(rkh + ko + ks * 32);
      bf16x8 bL = *reinterpret_cast<const bf16x8*>(rkl + ko + ks * 32);
#pragma unroll
      for (int mi = 0; mi < 2; ++mi) {
        acc[mi][ni] = __builtin_amdgcn_mfma_f32_16x16x32_bf16(aH[mi][ks], bH, acc[mi][ni], 0, 0, 0);
        acc[mi][ni] = __builtin_amdgcn_mfma_f32_16x16x32_bf16(aL[mi][ks], bH, acc[mi][ni], 0, 0, 0);
        acc[mi][ni] = __builtin_amdgcn_mfma_f32_16x16x32_bf16(aH[mi][ks], bL, acc[mi][ni], 0, 0, 0);
      }
    }
  }
#pragma unroll
  for (int mi = 0; mi < 2; ++mi)
#pragma unroll
    for (int ni = 0; ni < 4; ++ni) {
      int col = (wn << 6) + (ni << 4) + lr;
#pragma unroll
      for (int r = 0; r < 4; ++r) {
        int qi2 = wm * 32 + mi * 16 + crow + r;
        bool ok = (col >= qi2 + 1) && (col <= qi2 + 64) && (nb > 0 || col >= 64);
        p[qi2][col] = ok ? acc[mi][ni][r] * 0.125f : NEGV;
      }
    }
  __syncthreads();

  // softmax: 4 threads per row
  const int qi = t >> 2, s = t & 3;
  float ev[32];
  float mx = -3.0e38f;
#pragma unroll
  for (int u = 0; u < 32; ++u) { ev[u] = p[qi][s + (u << 2)]; mx = fmaxf(mx, ev[u]); }
  mx = fmaxf(mx, __shfl_xor(mx, 1));
  mx = fmaxf(mx, __shfl_xor(mx, 2));
  float sum = 0.f;
#pragma unroll
  for (int u = 0; u < 32; ++u) { float e = __expf(ev[u] - mx); ev[u] = e; sum += e; }
  sum += __shfl_xor(sum, 1); sum += __shfl_xor(sum, 2);
  float invs = 1.f / sum;
#pragma unroll
  for (int u = 0; u < 32; ++u) p[qi][s + (u << 2)] = ev[u] * invs;
  __syncthreads();

  // PV: M=64 N=64 K=128
  f32x4 pacc[2][2];
#pragma unroll
  for (int a = 0; a < 2; ++a)
#pragma unroll
    for (int b = 0; b < 2; ++b) pacc[a][b] = (f32x4){0.f, 0.f, 0.f, 0.f};
#pragma unroll
  for (int ks = 0; ks < 4; ++ks) {
    int k0 = ks * 32 + kg;
    bf16x8 ph[2], pl[2];
#pragma unroll
    for (int mi = 0; mi < 2; ++mi) {
      int arow = wm * 32 + mi * 16 + lr;
      float4 x0 = *reinterpret_cast<const float4*>(&p[arow][k0]);
      float4 x1 = *reinterpret_cast<const float4*>(&p[arow][k0 + 4]);
      float xv[8] = {x0.x, x0.y, x0.z, x0.w, x1.x, x1.y, x1.z, x1.w};
#pragma unroll
      for (int e = 0; e < 8; ++e) {
        __bf16 hh = (__bf16)xv[e];
        ph[mi][e] = hh;
        pl[mi][e] = (__bf16)(xv[e] - (float)hh);
      }
    }
#pragma unroll
    for (int ni = 0; ni < 2; ++ni) {
      int d = (wn << 5) + (ni << 4) + lr;
      bf16x8 bv = *reinterpret_cast<const bf16x8*>(vtb + ((size_t)h * 64 + d) * 2112 + nb * 64 + k0);
#pragma unroll
      for (int mi = 0; mi < 2; ++mi) {
        pacc[mi][ni] = __builtin_amdgcn_mfma_f32_16x16x32_bf16(ph[mi], bv, pacc[mi][ni], 0, 0, 0);
        pacc[mi][ni] = __builtin_amdgcn_mfma_f32_16x16x32_bf16(pl[mi], bv, pacc[mi][ni], 0, 0, 0);
      }
    }
  }
#pragma unroll
  for (int mi = 0; mi < 2; ++mi)
#pragma unroll
    for (int ni = 0; ni < 2; ++ni) {
      int d = (wn << 5) + (ni << 4) + lr;
#pragma unroll
      for (int r = 0; r < 4; ++r) {
        int qi2 = wm * 32 + mi * 16 + crow + r;
        s_out[((size_t)h * NTOK + nb * 64 + qi2) * DHEAD + d] = pacc[mi][ni][r];
      }
    }
}

// ---------------- gate + combine -> bf16 ----------------
__global__ void k_combine(const float* __restrict__ strat, const float* __restrict__ c_out,
                          const float* __restrict__ f_out, const float* __restrict__ s_out,
                          bf16* __restrict__ comb) {
  int idx = blockIdx.x * 256 + threadIdx.x;
  int i = idx >> 9;
  int c = idx & 511;
  int h = c >> 6, d = c & 63;
  size_t a = ((size_t)h * NTOK + i) * DHEAD + d;
  const float* st = strat + (size_t)i * 24 + h * 3;
  comb[idx] = __float2bfloat16(st[0] * c_out[a] + st[1] * f_out[a] + st[2] * s_out[a]);
}

extern "C" void kernel_launch(void* const* d_in, const int* in_sizes, int n_in,
                              void* d_out, int out_size, void* d_ws, size_t ws_size,
                              hipStream_t stream) {
  const float* x      = (const float*)d_in[0];
  const float* g_norm = (const float*)d_in[1];
  const float* w_qkv  = (const float*)d_in[2];
  const float* k_pos  = (const float*)d_in[3];
  const float* v_pos  = (const float*)d_in[4];
  const float* mem_kv = (const float*)d_in[5];
  const float* k_w1   = (const float*)d_in[6];
  const float* k_b1   = (const float*)d_in[7];
  const float* k_w2   = (const float*)d_in[8];
  const float* k_b2   = (const float*)d_in[9];
  const float* v_w1   = (const float*)d_in[10];
  const float* v_b1   = (const float*)d_in[11];
  const float* v_w2   = (const float*)d_in[12];
  const float* v_b2   = (const float*)d_in[13];
  const float* w_comb = (const float*)d_in[14];
  const float* b_comb = (const float*)d_in[15];
  const float* w_out  = (const float*)d_in[16];
  float* out = (float*)d_out;
  char* wsb = (char*)d_ws;

  bf16* WQKV_H = (bf16*)(wsb + B_WQKV_H);
  bf16* WQKV_L = (bf16*)(wsb + B_WQKV_L);
  bf16* KW1_H  = (bf16*)(wsb + B_KW1_H);
  bf16* KW1_L  = (bf16*)(wsb + B_KW1_L);
  bf16* KW2_H  = (bf16*)(wsb + B_KW2_H);
  bf16* KW2_L  = (bf16*)(wsb + B_KW2_L);
  bf16* VW1_H  = (bf16*)(wsb + B_VW1_H);
  bf16* VW2_H  = (bf16*)(wsb + B_VW2_H);
  bf16* WOUT_H = (bf16*)(wsb + B_WOUT_H);
  bf16* HB_H   = (bf16*)(wsb + B_HB_H);
  bf16* HB_L   = (bf16*)(wsb + B_HB_L);
  bf16* QBH    = (bf16*)(wsb + B_QBH);
  bf16* QBM    = (bf16*)(wsb + B_QBM);
  bf16* QBL    = (bf16*)(wsb + B_QBL);
  float* KF    = (float*)(wsb + B_KF);
  bf16* VBH    = (bf16*)(wsb + B_VBH);
  bf16* RQH    = (bf16*)(wsb + B_RQH);
  bf16* RQL    = (bf16*)(wsb + B_RQL);
  bf16* RKH    = (bf16*)(wsb + B_RKH);
  bf16* RKL    = (bf16*)(wsb + B_RKL);
  bf16* VTB    = (bf16*)(wsb + B_VTB);
  bf16* CKT_H  = (bf16*)(wsb + B_CKT_H);
  bf16* CKT_M  = (bf16*)(wsb + B_CKT_M);
  bf16* CKT_L  = (bf16*)(wsb + B_CKT_L);
  bf16* CVT    = (bf16*)(wsb + B_CVT);
  float* STRAT = (float*)(wsb + B_STRAT);
  int*   SEL   = (int*)(wsb + B_SEL);
  float* COUT  = (float*)(wsb + B_COUT);
  float* FOUT  = (float*)(wsb + B_FOUT);
  float* SOUT  = (float*)(wsb + B_SOUT);
  bf16* KW_H   = (bf16*)(wsb + B_KW_H);
  bf16* KW_L   = (bf16*)(wsb + B_KW_L);
  bf16* VW_H   = (bf16*)(wsb + B_VW_H);
  bf16* HID_H  = (bf16*)(wsb + B_HID_H);
  bf16* HID_L  = (bf16*)(wsb + B_HID_L);
  bf16* COMBB  = (bf16*)(wsb + B_COMBB);

  // weight splits
  k_wt<<<dim3(16, 48), 256, 0, stream>>>(w_qkv, WQKV_H, WQKV_L, DMODEL, 1536);
  k_wt<<<dim3(32, 32), 256, 0, stream>>>(k_w1, KW1_H, KW1_L, CDIM, CDIM);
  k_wt<<<dim3(32, 2),  256, 0, stream>>>(k_w2, KW2_H, KW2_L, CDIM, DHEAD);
  k_wt<<<dim3(32, 32), 256, 0, stream>>>(v_w1, VW1_H, nullptr, CDIM, CDIM);
  k_wt<<<dim3(32, 2),  256, 0, stream>>>(v_w2, VW2_H, nullptr, CDIM, DHEAD);
  k_wt<<<dim3(16, 16), 256, 0, stream>>>(w_out, WOUT_H, nullptr, DMODEL, DMODEL);

  k_rmsnorm<<<NTOK, 256, 0, stream>>>(x, g_norm, HB_H, HB_L);
  k_zpad<<<128, 256, 0, stream>>>(RKH, RKL, VTB);
  // qkv (compensated) with fused split/scatter: q->QBH/QBM/QBL, k->KF, v->VBH
  k_cgemm<0, 3, 1><<<dim3(24, 32), 256, 0, stream>>>(
      HB_H, HB_L, WQKV_H, WQKV_L, nullptr, KF, QBH, QBM, VBH, QBL, NTOK, DMODEL, 1536);
  k_rope<<<2048, 256, 0, stream>>>(QBH, QBM, QBL, KF, RQH, RQL, RKH, RKL);
  k_vt<<<dim3(32, 8), 256, 0, stream>>>(VBH, VTB);
  k_windows<<<8128, 256, 0, stream>>>(KF, VBH, k_pos, v_pos, KW_H, KW_L, VW_H);
  // k-MLP (compensated, feeds selection) -> ckT hi/mid/lo
  k_cgemm<1, 2, 1><<<dim3(16, 32), 256, 0, stream>>>(
      KW_H, KW_L, KW1_H, KW1_L, k_b1, nullptr, HID_H, HID_L, nullptr, nullptr,
      NHEAD * NWIN, CDIM, CDIM);
  k_cgemm<0, 5, 1><<<dim3(1, 32), 256, 0, stream>>>(
      HID_H, HID_L, KW2_H, KW2_L, k_b2, nullptr, CKT_H, CKT_M, nullptr, CKT_L,
      NHEAD * NWIN, CDIM, DHEAD);
  // v-MLP (plain) -> cvT
  k_cgemm<1, 1, 0><<<dim3(16, 32), 256, 0, stream>>>(
      VW_H, nullptr, VW1_H, nullptr, v_b1, nullptr, HID_H, nullptr, nullptr, nullptr,
      NHEAD * NWIN, CDIM, CDIM);
  k_cgemm<0, 6, 0><<<dim3(1, 32), 256, 0, stream>>>(
      HID_H, nullptr, VW2_H, nullptr, v_b2, nullptr, CVT, nullptr, nullptr, nullptr,
      NHEAD * NWIN, CDIM, DHEAD);
  k_fillmem<<<1, 512, 0, stream>>>(mem_kv, CKT_H, CKT_M, CKT_L, CVT);
  // attention branches
  k_comp_attn<<<dim3(64, 8), 256, 0, stream>>>(QBH, QBM, QBL, CKT_H, CKT_M, CKT_L, CVT, COUT, SEL);
  k_fine_attn<<<dim3(512, 8), 256, 0, stream>>>(RQH, RQL, RKH, RKL, VBH, SEL, FOUT);
  k_slide_attn<<<dim3(32, 8), 256, 0, stream>>>(RQH, RQL, RKH, RKL, VTB, SOUT);
  // gates + combine + output projection
  k_gemm_hl<<<dim3(1, 64), 256, 0, stream>>>(HB_H, HB_L, w_comb, b_comb, STRAT, NTOK, DMODEL, 24);
  k_combine<<<4096, 256, 0, stream>>>(STRAT, COUT, FOUT, SOUT, COMBB);
  k_cgemm<0, 0, 0><<<dim3(8, 32), 256, 0, stream>>>(
      COMBB, nullptr, WOUT_H, nullptr, nullptr, out, nullptr, nullptr, nullptr, nullptr,
      NTOK, DMODEL, DMODEL);
}

// Round 7
// 369.650 us; speedup vs baseline: 3.5289x; 1.0850x over previous
//
#include <hip/hip_runtime.h>
#include <hip/hip_bf16.h>
#include <cstddef>

#define NTOK 2048
#define DMODEL 512
#define NHEAD 8
#define DHEAD 64
#define NWIN 254          // (2048-16)/8 + 1
#define CDIM 1024         // CB*DH
#define NEGV -1000000000.0f

typedef __attribute__((ext_vector_type(8))) __bf16 bf16x8;
typedef __attribute__((ext_vector_type(4))) float f32x4;
typedef __hip_bfloat16 bf16;

// ---------------- workspace layout (byte offsets), total ~61.5 MB ----------------
static const size_t B_WQKV_H = 0;          // 1536*512*2
static const size_t B_WQKV_L = 1572864;
static const size_t B_KW1_H  = 3145728;    // 1024*1024*2
static const size_t B_KW1_L  = 5242880;
static const size_t B_KW2_H  = 7340032;    // 64*1024*2
static const size_t B_KW2_L  = 7471104;
static const size_t B_VW1_H  = 7602176;
static const size_t B_VW2_H  = 9699328;
static const size_t B_WOUT_H = 9830400;    // 512*512*2
static const size_t B_HB_H   = 10354688;   // 2048*512*2
static const size_t B_HB_L   = 12451840;
static const size_t B_QBH    = 14548992;   // 8*2048*64*2 (non-roped q, hi)
static const size_t B_QBL    = 16646144;   // (lo, 3rd term)
static const size_t B_KF     = 18743296;   // 8*2048*64*4 (k fp32, pre-rope)
static const size_t B_VBH    = 22937600;   // 8*2048*64*2
static const size_t B_RQH    = 25034752;   // roped q hi/lo
static const size_t B_RQL    = 27131904;
static const size_t B_RKH    = 29229056;   // 8*2112*64*2 (roped k, 64 zero-pad rows front)
static const size_t B_RKL    = 31391744;
static const size_t B_VTB    = 33554432;   // 8*64*2112*2 (v^T, 64 zero-pad cols front)
static const size_t B_CKT_H  = 35717120;   // 8*256*64*2 (compressed k rows, j=0 mem)
static const size_t B_CKT_L  = 35979264;
static const size_t B_CVT    = 36241408;   // 8*64*256*2 (compressed v transposed)
static const size_t B_STRAT  = 36503552;   // 2048*24*4
static const size_t B_SEL    = 36700160;   // 8*2048*5*4
static const size_t B_COUT   = 37027840;   // 4194304 (overlays KW_H)
static const size_t B_FOUT   = 41222144;   // 4194304 (overlays KW_L)
static const size_t B_SOUT   = 45416448;   // 4194304 (overlays VW_H)
static const size_t B_KW_H   = B_COUT;     // 2032*1024*2 = 4161536
static const size_t B_KW_L   = B_FOUT;
static const size_t B_VW_H   = B_SOUT;
static const size_t B_HID_H  = 49610752;   // 4161536
static const size_t B_HID_L  = 53772288;   // 4161536
static const size_t B_QBM    = 57933824;   // 8*2048*64*2 (q mid term)
static const size_t B_CKT_M  = 60030976;   // 8*256*64*2
static const size_t B_RKF    = 60293120;   // 8*2048*64*4 (roped k fp32, for fine attn); end 64487424
static const size_t B_COMBB  = B_HID_H;    // 2097152 (after MLPs dead)

// ---------------- RMSNorm -> hi/lo bf16 ----------------
__global__ void k_rmsnorm(const float* __restrict__ x, const float* __restrict__ g,
                          bf16* __restrict__ hbh, bf16* __restrict__ hbl) {
  const int row = blockIdx.x;
  const int t = threadIdx.x;
  __shared__ float wsum[4];
  __shared__ float scale_s;
  const float* xr = x + (size_t)row * DMODEL;
  float s = 0.f;
  for (int c = t; c < DMODEL; c += 256) { float v = xr[c]; s += v * v; }
  for (int o = 32; o > 0; o >>= 1) s += __shfl_down(s, o);
  if ((t & 63) == 0) wsum[t >> 6] = s;
  __syncthreads();
  if (t == 0) {
    float tot = wsum[0] + wsum[1] + wsum[2] + wsum[3];
    scale_s = rsqrtf(tot * (1.f / DMODEL) + 1e-6f);
  }
  __syncthreads();
  float sc = scale_s;
  for (int c = t; c < DMODEL; c += 256) {
    float v = xr[c] * sc * g[c];
    bf16 h1 = __float2bfloat16(v);
    hbh[(size_t)row * DMODEL + c] = h1;
    hbl[(size_t)row * DMODEL + c] = __float2bfloat16(v - __bfloat162float(h1));
  }
}

// ---------------- weight transpose+convert hi(/lo) ----------------
__global__ void k_wt(const float* __restrict__ W, bf16* __restrict__ WTh,
                     bf16* __restrict__ WTl, int K, int N) {
  __shared__ float t[32][33];
  const int k0 = blockIdx.x << 5, n0 = blockIdx.y << 5;
  const int tx = threadIdx.x & 31, ty = threadIdx.x >> 5;
#pragma unroll
  for (int r = 0; r < 4; ++r)
    t[ty + (r << 3)][tx] = W[(size_t)(k0 + ty + (r << 3)) * N + n0 + tx];
  __syncthreads();
#pragma unroll
  for (int r = 0; r < 4; ++r) {
    float val = t[tx][ty + (r << 3)];
    size_t o = (size_t)(n0 + ty + (r << 3)) * K + k0 + tx;
    bf16 h1 = __float2bfloat16(val);
    WTh[o] = h1;
    if (WTl) WTl[o] = __float2bfloat16(val - __bfloat162float(h1));
  }
}

// ---------------- MFMA GEMM (optionally Markidis-compensated) ----------------
// OUT: 0 fp32 C; 1 bf16 hi; 2 bf16 hi+lo; 3 qkv scatter (q hi/mid/lo, k fp32, v bf16);
//      5 ckT hi/mid/lo head-shifted; 6 cvT transposed head-shifted.
template <int EPI, int OUT, int COMP>
__global__ void k_cgemm(const bf16* __restrict__ Ah, const bf16* __restrict__ Al,
                        const bf16* __restrict__ Wh, const bf16* __restrict__ Wl,
                        const float* __restrict__ bias,
                        float* __restrict__ Cf, bf16* __restrict__ P0,
                        bf16* __restrict__ P1, bf16* __restrict__ P2,
                        bf16* __restrict__ P3,
                        int M, int K, int N) {
  const int lane = threadIdx.x & 63;
  const int w = threadIdx.x >> 6;
  const int wr = w >> 1, wc = w & 1;
  const int row_base = (blockIdx.y << 6) + (wr << 5);
  const int col_base = (blockIdx.x << 6) + (wc << 5);
  const int lr = lane & 15;
  const int kg = (lane >> 4) << 3;

  int ar0 = row_base + lr;       if (ar0 > M - 1) ar0 = M - 1;
  int ar1 = row_base + 16 + lr;  if (ar1 > M - 1) ar1 = M - 1;
  const size_t a0o = (size_t)ar0 * K + kg;
  const size_t a1o = (size_t)ar1 * K + kg;
  const size_t b0o = (size_t)(col_base + lr) * K + kg;
  const size_t b1o = (size_t)(col_base + 16 + lr) * K + kg;

  f32x4 acc00 = {}, acc01 = {}, acc10 = {}, acc11 = {};
  for (int k0 = 0; k0 < K; k0 += 32) {
    bf16x8 ah0 = *reinterpret_cast<const bf16x8*>(Ah + a0o + k0);
    bf16x8 ah1 = *reinterpret_cast<const bf16x8*>(Ah + a1o + k0);
    bf16x8 bh0 = *reinterpret_cast<const bf16x8*>(Wh + b0o + k0);
    bf16x8 bh1 = *reinterpret_cast<const bf16x8*>(Wh + b1o + k0);
    acc00 = __builtin_amdgcn_mfma_f32_16x16x32_bf16(ah0, bh0, acc00, 0, 0, 0);
    acc01 = __builtin_amdgcn_mfma_f32_16x16x32_bf16(ah0, bh1, acc01, 0, 0, 0);
    acc10 = __builtin_amdgcn_mfma_f32_16x16x32_bf16(ah1, bh0, acc10, 0, 0, 0);
    acc11 = __builtin_amdgcn_mfma_f32_16x16x32_bf16(ah1, bh1, acc11, 0, 0, 0);
    if constexpr (COMP) {
      bf16x8 al0 = *reinterpret_cast<const bf16x8*>(Al + a0o + k0);
      bf16x8 al1 = *reinterpret_cast<const bf16x8*>(Al + a1o + k0);
      bf16x8 bl0 = *reinterpret_cast<const bf16x8*>(Wl + b0o + k0);
      bf16x8 bl1 = *reinterpret_cast<const bf16x8*>(Wl + b1o + k0);
      acc00 = __builtin_amdgcn_mfma_f32_16x16x32_bf16(ah0, bl0, acc00, 0, 0, 0);
      acc01 = __builtin_amdgcn_mfma_f32_16x16x32_bf16(ah0, bl1, acc01, 0, 0, 0);
      acc10 = __builtin_amdgcn_mfma_f32_16x16x32_bf16(ah1, bl0, acc10, 0, 0, 0);
      acc11 = __builtin_amdgcn_mfma_f32_16x16x32_bf16(ah1, bl1, acc11, 0, 0, 0);
      acc00 = __builtin_amdgcn_mfma_f32_16x16x32_bf16(al0, bh0, acc00, 0, 0, 0);
      acc01 = __builtin_amdgcn_mfma_f32_16x16x32_bf16(al0, bh1, acc01, 0, 0, 0);
      acc10 = __builtin_amdgcn_mfma_f32_16x16x32_bf16(al1, bh0, acc10, 0, 0, 0);
      acc11 = __builtin_amdgcn_mfma_f32_16x16x32_bf16(al1, bh1, acc11, 0, 0, 0);
    }
  }

  const int crow = (lane >> 4) << 2;
  f32x4 accs[2][2] = {acc00, acc01, acc10, acc11};
#pragma unroll
  for (int mi = 0; mi < 2; ++mi) {
#pragma unroll
    for (int ni = 0; ni < 2; ++ni) {
      int col = col_base + (ni << 4) + lr;
      float bv = bias ? bias[col] : 0.f;
#pragma unroll
      for (int r = 0; r < 4; ++r) {
        int row = row_base + (mi << 4) + crow + r;
        if (row < M) {
          float vv = accs[mi][ni][r] + bv;
          if (EPI == 1) vv = fmaxf(vv, 0.f);
          if constexpr (OUT == 0) {
            Cf[(size_t)row * N + col] = vv;
          } else if constexpr (OUT == 1) {
            P0[(size_t)row * N + col] = __float2bfloat16(vv);
          } else if constexpr (OUT == 2) {
            bf16 h1 = __float2bfloat16(vv);
            P0[(size_t)row * N + col] = h1;
            P1[(size_t)row * N + col] = __float2bfloat16(vv - __bfloat162float(h1));
          } else if constexpr (OUT == 3) {
            int which = col >> 9, rem = col & 511;
            int hh = rem >> 6, dd = rem & 63;
            size_t o = ((size_t)hh * NTOK + row) * DHEAD + dd;
            if (which == 0) {
              bf16 h1 = __float2bfloat16(vv);
              float r1 = vv - __bfloat162float(h1);
              bf16 m1 = __float2bfloat16(r1);
              P0[o] = h1;
              P1[o] = m1;
              P3[o] = __float2bfloat16(r1 - __bfloat162float(m1));
            } else if (which == 1) {
              Cf[o] = vv;
            } else {
              P2[o] = __float2bfloat16(vv);
            }
          } else if constexpr (OUT == 5) {
            int hh = row / NWIN, jj = row - hh * NWIN;
            size_t o = ((size_t)hh * 256 + 1 + jj) * 64 + col;
            bf16 h1 = __float2bfloat16(vv);
            float r1 = vv - __bfloat162float(h1);
            bf16 m1 = __float2bfloat16(r1);
            P0[o] = h1;
            P1[o] = m1;
            P3[o] = __float2bfloat16(r1 - __bfloat162float(m1));
          } else if constexpr (OUT == 6) {
            int hh = row / NWIN, jj = row - hh * NWIN;
            P0[((size_t)hh * 64 + col) * 256 + 1 + jj] = __float2bfloat16(vv);
          }
        }
      }
    }
  }
}

// ---------------- strat: sigmoid(h @ w_comb + b_comb), one block per row ----------------
// block 256: stage h row (hi+lo) in LDS; 8 lanes per output col, shuffle-reduce.
__global__ __launch_bounds__(256) void k_strat(
    const bf16* __restrict__ Ah, const bf16* __restrict__ Al,
    const float* __restrict__ W, const float* __restrict__ bias,
    float* __restrict__ C) {
  const int row = blockIdx.x;
  const int t = threadIdx.x;
  __shared__ float hs[DMODEL];
  size_t ro = (size_t)row * DMODEL;
#pragma unroll
  for (int u = 0; u < 2; ++u) {
    int c = t + u * 256;
    hs[c] = __bfloat162float(Ah[ro + c]) + __bfloat162float(Al[ro + c]);
  }
  __syncthreads();
  if (t < 192) {
    int c = t >> 3, s = t & 7;
    float acc = 0.f;
    for (int u = 0; u < 64; ++u) {
      int e = s * 64 + u;
      acc = fmaf(hs[e], W[(size_t)e * 24 + c], acc);
    }
    acc += __shfl_xor(acc, 1);
    acc += __shfl_xor(acc, 2);
    acc += __shfl_xor(acc, 4);
    if (s == 0)
      C[(size_t)row * 24 + c] = 1.f / (1.f + expf(-(acc + bias[c])));
  }
}

// ---------------- zero-pad fronts of rkh/rkl rows and vtb cols ----------------
__global__ void k_zpad(bf16* __restrict__ rkh, bf16* __restrict__ rkl,
                       bf16* __restrict__ vtb) {
  int idx = blockIdx.x * 256 + threadIdx.x;   // 8*64*64 = 32768 exact
  int h = idx >> 12;
  int r = (idx >> 6) & 63;
  int c = idx & 63;
  bf16 z = __float2bfloat16(0.f);
  rkh[((size_t)h * 2112 + r) * 64 + c] = z;
  rkl[((size_t)h * 2112 + r) * 64 + c] = z;
  vtb[((size_t)h * 64 + r) * 2112 + c] = z;
}

// ---------------- RoPE: q(hi/mid/lo) + k(fp32) -> roped q hi/lo, k hi/lo + k fp32 ----------------
__global__ void k_rope(const bf16* __restrict__ qbh, const bf16* __restrict__ qbm,
                       const bf16* __restrict__ qbl, const float* __restrict__ kf,
                       bf16* __restrict__ rqh, bf16* __restrict__ rql,
                       bf16* __restrict__ rkh, bf16* __restrict__ rkl,
                       float* __restrict__ rkf) {
  int idx = blockIdx.x * 256 + threadIdx.x;   // 8*2048*32 exact
  int i = idx & 31;
  int n = (idx >> 5) & (NTOK - 1);
  int h = idx >> 16;
  float ex = (float)(2 * i) * (1.f / 64.f);
  float inv = exp2f(-ex * 13.287712379549449f);
  float ang = (float)n * inv;
  float sn, cs;
  sincosf(ang, &sn, &cs);
  size_t base = ((size_t)h * NTOK + n) * DHEAD + 2 * i;
  float q1 = __bfloat162float(qbh[base]) + __bfloat162float(qbm[base]) + __bfloat162float(qbl[base]);
  float q2 = __bfloat162float(qbh[base + 1]) + __bfloat162float(qbm[base + 1]) + __bfloat162float(qbl[base + 1]);
  float r1 = q1 * cs - q2 * sn, r2 = q1 * sn + q2 * cs;
  bf16 h1 = __float2bfloat16(r1);
  rqh[base] = h1; rql[base] = __float2bfloat16(r1 - __bfloat162float(h1));
  h1 = __float2bfloat16(r2);
  rqh[base + 1] = h1; rql[base + 1] = __float2bfloat16(r2 - __bfloat162float(h1));
  float k1 = kf[base], k2 = kf[base + 1];
  float s1 = k1 * cs - k2 * sn, s2 = k1 * sn + k2 * cs;
  rkf[base] = s1;
  rkf[base + 1] = s2;
  size_t kb = ((size_t)h * 2112 + 64 + n) * DHEAD + 2 * i;
  h1 = __float2bfloat16(s1);
  rkh[kb] = h1; rkl[kb] = __float2bfloat16(s1 - __bfloat162float(h1));
  h1 = __float2bfloat16(s2);
  rkh[kb + 1] = h1; rkl[kb + 1] = __float2bfloat16(s2 - __bfloat162float(h1));
}

// ---------------- transpose vbh -> vtb (+64 col pad) ----------------
__global__ void k_vt(const bf16* __restrict__ vbh, bf16* __restrict__ vtb) {
  __shared__ bf16 tile[64][65];
  int h = blockIdx.y, n0 = blockIdx.x << 6;
  int tx = threadIdx.x & 63, ty = threadIdx.x >> 6;
  for (int r = ty; r < 64; r += 4)
    tile[r][tx] = vbh[((size_t)h * NTOK + n0 + r) * DHEAD + tx];
  __syncthreads();
  for (int r = ty; r < 64; r += 4)
    vtb[((size_t)h * 64 + r) * 2112 + 64 + n0 + tx] = tile[tx][r];
}

// ---------------- compression windows: KW hi/lo (from k fp32), VW hi ----------------
__global__ void k_windows(const float* __restrict__ kf, const bf16* __restrict__ vbh,
                          const float* __restrict__ kpos, const float* __restrict__ vpos,
                          bf16* __restrict__ kwh, bf16* __restrict__ kwl,
                          bf16* __restrict__ vwh) {
  int idx = blockIdx.x * 256 + threadIdx.x;   // 8*254*1024 exact
  int d = idx & 63;
  int c = (idx >> 6) & 15;
  int j = (idx >> 10) % NWIN;
  int h = idx / (NWIN << 10);
  int srcpos = (j << 3) + c;
  size_t src = ((size_t)h * NTOK + srcpos) * DHEAD + d;
  size_t pp = ((size_t)h * 16 + c) * DHEAD + d;
  float kv = kf[src] + kpos[pp];
  bf16 h1 = __float2bfloat16(kv);
  kwh[idx] = h1;
  kwl[idx] = __float2bfloat16(kv - __bfloat162float(h1));
  vwh[idx] = __float2bfloat16(__bfloat162float(vbh[src]) + vpos[pp]);
}

// ---------------- fill mem slot (j=0) and zero pad slot (j=255) of ckT/cvT ----------------
__global__ void k_fillmem(const float* __restrict__ memkv, bf16* __restrict__ ckh,
                          bf16* __restrict__ ckm, bf16* __restrict__ ckl,
                          bf16* __restrict__ cvtb) {
  int t = threadIdx.x;            // 512
  int h = t >> 6, e = t & 63;
  float kv = memkv[(size_t)h * DHEAD + e];
  bf16 h1 = __float2bfloat16(kv);
  float r1 = kv - __bfloat162float(h1);
  bf16 m1 = __float2bfloat16(r1);
  ckh[((size_t)h * 256) * 64 + e] = h1;
  ckm[((size_t)h * 256) * 64 + e] = m1;
  ckl[((size_t)h * 256) * 64 + e] = __float2bfloat16(r1 - __bfloat162float(m1));
  bf16 z = __float2bfloat16(0.f);
  ckh[((size_t)h * 256 + 255) * 64 + e] = z;
  ckm[((size_t)h * 256 + 255) * 64 + e] = z;
  ckl[((size_t)h * 256 + 255) * 64 + e] = z;
  float vv = memkv[(size_t)(NHEAD + h) * DHEAD + e];
  cvtb[((size_t)h * 64 + e) * 256 + 0] = __float2bfloat16(vv);
  cvtb[((size_t)h * 64 + e) * 256 + 255] = z;
}

// ---------------- compression attention (MFMA, 32 queries/block) ----------------
__global__ __launch_bounds__(256) void k_comp_attn(
    const bf16* __restrict__ qbh, const bf16* __restrict__ qbm, const bf16* __restrict__ qbl,
    const bf16* __restrict__ ckh, const bf16* __restrict__ ckm, const bf16* __restrict__ ckl,
    const bf16* __restrict__ cvtb,
    float* __restrict__ c_out, int* __restrict__ sel) {
  const int h = blockIdx.y;
  const int i0 = blockIdx.x << 5;
  const int t = threadIdx.x;
  const int w = t >> 6, lane = t & 63;
  const int lr = lane & 15, kg = (lane >> 4) << 3;
  const int crow = (lane >> 4) << 2;

  __shared__ float p[32][260];     // stride 260: rows 16B-aligned

  // ---- QK^T, 6-term (hh, hm, mh, hl, lh, mm)
  bf16x8 aH[2][2], aM[2][2], aL[2][2];
#pragma unroll
  for (int mi = 0; mi < 2; ++mi) {
    size_t qo = ((size_t)h * NTOK + i0 + mi * 16 + lr) * DHEAD + kg;
#pragma unroll
    for (int ks = 0; ks < 2; ++ks) {
      aH[mi][ks] = *reinterpret_cast<const bf16x8*>(qbh + qo + ks * 32);
      aM[mi][ks] = *reinterpret_cast<const bf16x8*>(qbm + qo + ks * 32);
      aL[mi][ks] = *reinterpret_cast<const bf16x8*>(qbl + qo + ks * 32);
    }
  }
  f32x4 acc[2][4];
#pragma unroll
  for (int a = 0; a < 2; ++a)
#pragma unroll
    for (int b = 0; b < 4; ++b) acc[a][b] = (f32x4){0.f, 0.f, 0.f, 0.f};
#pragma unroll
  for (int ni = 0; ni < 4; ++ni) {
    int col = (w << 6) + (ni << 4) + lr;
    size_t ko = ((size_t)h * 256 + col) * 64 + kg;
#pragma unroll
    for (int ks = 0; ks < 2; ++ks) {
      bf16x8 bH = *reinterpret_cast<const bf16x8*>(ckh + ko + ks * 32);
      bf16x8 bM = *reinterpret_cast<const bf16x8*>(ckm + ko + ks * 32);
      bf16x8 bL = *reinterpret_cast<const bf16x8*>(ckl + ko + ks * 32);
#pragma unroll
      for (int mi = 0; mi < 2; ++mi) {
        acc[mi][ni] = __builtin_amdgcn_mfma_f32_16x16x32_bf16(aH[mi][ks], bH, acc[mi][ni], 0, 0, 0);
        acc[mi][ni] = __builtin_amdgcn_mfma_f32_16x16x32_bf16(aH[mi][ks], bM, acc[mi][ni], 0, 0, 0);
        acc[mi][ni] = __builtin_amdgcn_mfma_f32_16x16x32_bf16(aM[mi][ks], bH, acc[mi][ni], 0, 0, 0);
        acc[mi][ni] = __builtin_amdgcn_mfma_f32_16x16x32_bf16(aH[mi][ks], bL, acc[mi][ni], 0, 0, 0);
        acc[mi][ni] = __builtin_amdgcn_mfma_f32_16x16x32_bf16(aL[mi][ks], bH, acc[mi][ni], 0, 0, 0);
        acc[mi][ni] = __builtin_amdgcn_mfma_f32_16x16x32_bf16(aM[mi][ks], bM, acc[mi][ni], 0, 0, 0);
      }
    }
  }
#pragma unroll
  for (int mi = 0; mi < 2; ++mi)
#pragma unroll
    for (int ni = 0; ni < 4; ++ni) {
      int col = (w << 6) + (ni << 4) + lr;
      int wend = (col == 0) ? -1 : ((col - 1) << 3) + 15;
#pragma unroll
      for (int r = 0; r < 4; ++r) {
        int qi = mi * 16 + crow + r;
        bool ok = (col < 255) && (wend < i0 + qi);
        p[qi][col] = ok ? acc[mi][ni][r] * 0.125f : NEGV;
      }
    }
  __syncthreads();

  // ---- softmax: 8 threads per row
  const int qi = t >> 3, s = t & 7;
  float ev[32];
  float mx = -3.0e38f;
#pragma unroll
  for (int u = 0; u < 32; ++u) { ev[u] = p[qi][s + (u << 3)]; mx = fmaxf(mx, ev[u]); }
  mx = fmaxf(mx, __shfl_xor(mx, 1));
  mx = fmaxf(mx, __shfl_xor(mx, 2));
  mx = fmaxf(mx, __shfl_xor(mx, 4));
  float sum = 0.f;
#pragma unroll
  for (int u = 0; u < 32; ++u) { float e = __expf(ev[u] - mx); ev[u] = e; sum += e; }
  sum += __shfl_xor(sum, 1); sum += __shfl_xor(sum, 2); sum += __shfl_xor(sum, 4);
  float invs = 1.f / sum;
#pragma unroll
  for (int u = 0; u < 32; ++u) p[qi][s + (u << 3)] = ev[u] * invs;
  // same 8 lanes (one wave) own row qi; lockstep LDS ordering suffices until PV barrier

  // ---- block importance in REGISTERS (lane s owns f in [s*16, s*16+16)) + top-4
  int qblk = (i0 + qi) >> 4;
  float vals[16];
#pragma unroll
  for (int u = 0; u < 16; ++u) {
    int f = (s << 4) + u;
    float v;
    if (f >= qblk || f == 127) v = NEGV;
    else v = (p[qi][2 * f + 1] + p[qi][2 * f + 2]) * 0.5f;
    vals[u] = v;
  }
  int base = ((h << 11) | (i0 + qi)) * 5;
  for (int kk = 0; kk < 4; ++kk) {
    float bv = -3.0e38f; int bi = 0;
#pragma unroll
    for (int u = 0; u < 16; ++u) {
      if (vals[u] > bv) { bv = vals[u]; bi = (s << 4) + u; }
    }
#pragma unroll
    for (int o = 1; o < 8; o <<= 1) {
      float ov = __shfl_xor(bv, o);
      int oi = __shfl_xor(bi, o);
      if (ov > bv || (ov == bv && oi < bi)) { bv = ov; bi = oi; }
    }
    if (s == 0) sel[base + kk] = (bv > -5.0e8f) ? bi : -1;
    if ((bi >> 4) == s) vals[bi & 15] = -3.0e38f;
  }
  if (s == 0) sel[base + 4] = (i0 + qi) >> 4;
  __syncthreads();

  // ---- PV: M=32 N=64 K=256, p split hi/lo (A), cvT bf16 (B)
  const int wm = w >> 1, wn = w & 1;
  const int arow = wm * 16 + lr;
  f32x4 pacc[2];
#pragma unroll
  for (int b = 0; b < 2; ++b) pacc[b] = (f32x4){0.f, 0.f, 0.f, 0.f};
#pragma unroll
  for (int ks = 0; ks < 8; ++ks) {
    int k0 = ks * 32 + kg;
    float4 x0 = *reinterpret_cast<const float4*>(&p[arow][k0]);
    float4 x1 = *reinterpret_cast<const float4*>(&p[arow][k0 + 4]);
    float xv[8] = {x0.x, x0.y, x0.z, x0.w, x1.x, x1.y, x1.z, x1.w};
    bf16x8 ph, pl;
#pragma unroll
    for (int e = 0; e < 8; ++e) {
      __bf16 hh = (__bf16)xv[e];
      ph[e] = hh;
      pl[e] = (__bf16)(xv[e] - (float)hh);
    }
#pragma unroll
    for (int ni = 0; ni < 2; ++ni) {
      int d = (wn << 5) + (ni << 4) + lr;
      bf16x8 bv = *reinterpret_cast<const bf16x8*>(cvtb + ((size_t)h * 64 + d) * 256 + k0);
      pacc[ni] = __builtin_amdgcn_mfma_f32_16x16x32_bf16(ph, bv, pacc[ni], 0, 0, 0);
      pacc[ni] = __builtin_amdgcn_mfma_f32_16x16x32_bf16(pl, bv, pacc[ni], 0, 0, 0);
    }
  }
#pragma unroll
  for (int ni = 0; ni < 2; ++ni) {
    int d = (wn << 5) + (ni << 4) + lr;
#pragma unroll
    for (int r = 0; r < 4; ++r) {
      int q2 = wm * 16 + crow + r;
      c_out[((size_t)h * NTOK + i0 + q2) * DHEAD + d] = pacc[ni][r];
    }
  }
}

// ---------------- fine attention: 1 wave per query, fp32 K via float4 ----------------
// grid (512, 8), block 256 = 4 waves; wave w handles query i = blockIdx.x*4 + w.
__global__ __launch_bounds__(256) void k_fine_attn(
    const bf16* __restrict__ rqh, const bf16* __restrict__ rql,
    const float* __restrict__ rkf, const bf16* __restrict__ vbh,
    const int* __restrict__ sel, float* __restrict__ f_out) {
  const int h = blockIdx.y;
  const int wid = threadIdx.x >> 6;
  const int lane = threadIdx.x & 63;
  const int i = (blockIdx.x << 2) | wid;

  __shared__ float qs[4][64];
  __shared__ float pb[4][80];
  __shared__ int selb[4][5];

  size_t qoff = ((size_t)h * NTOK + i) * DHEAD + lane;
  qs[wid][lane] = __bfloat162float(rqh[qoff]) + __bfloat162float(rql[qoff]);
  if (lane < 5) selb[wid][lane] = sel[((h << 11) | i) * 5 + lane];
  __syncthreads();

  // ---- QK: lane -> key j=lane (blocks 0-3), j=64+lane (lane<16, own block)
  float sim0 = NEGV, sim1 = NEGV;
  {
    int kb = selb[wid][lane >> 4];
    int pos = (kb << 4) + (lane & 15);
    if (kb >= 0 && pos <= i) {
      const float* kp = rkf + ((size_t)h * NTOK + pos) * DHEAD;
      float d = 0.f;
#pragma unroll
      for (int e4 = 0; e4 < 16; ++e4) {
        float4 kv = *reinterpret_cast<const float4*>(kp + e4 * 4);
        d = fmaf(qs[wid][e4 * 4 + 0], kv.x, d);
        d = fmaf(qs[wid][e4 * 4 + 1], kv.y, d);
        d = fmaf(qs[wid][e4 * 4 + 2], kv.z, d);
        d = fmaf(qs[wid][e4 * 4 + 3], kv.w, d);
      }
      sim0 = d * 0.125f;
    }
  }
  if (lane < 16) {
    int kb = selb[wid][4];               // own block, always valid
    int pos = (kb << 4) + lane;
    if (pos <= i) {
      const float* kp = rkf + ((size_t)h * NTOK + pos) * DHEAD;
      float d = 0.f;
#pragma unroll
      for (int e4 = 0; e4 < 16; ++e4) {
        float4 kv = *reinterpret_cast<const float4*>(kp + e4 * 4);
        d = fmaf(qs[wid][e4 * 4 + 0], kv.x, d);
        d = fmaf(qs[wid][e4 * 4 + 1], kv.y, d);
        d = fmaf(qs[wid][e4 * 4 + 2], kv.z, d);
        d = fmaf(qs[wid][e4 * 4 + 3], kv.w, d);
      }
      sim1 = d * 0.125f;
    }
  }

  // ---- softmax over 80 (wave shuffles, no barriers)
  float mx = fmaxf(sim0, sim1);
#pragma unroll
  for (int o = 32; o > 0; o >>= 1) mx = fmaxf(mx, __shfl_xor(mx, o));
  float e0 = __expf(sim0 - mx);
  float e1 = __expf(sim1 - mx);        // lanes>=16: sim1=NEGV -> 0
  float sum = e0 + e1;
#pragma unroll
  for (int o = 32; o > 0; o >>= 1) sum += __shfl_xor(sum, o);
  float invs = 1.f / sum;
  pb[wid][lane] = e0 * invs;
  if (lane < 16) pb[wid][64 + lane] = e1 * invs;
  // same wave writes & reads pb[wid]: DS ops are wave-ordered, no barrier needed

  // ---- PV: lane = dim d; p broadcast from LDS, coalesced v loads
  float acc = 0.f;
#pragma unroll
  for (int b = 0; b < 5; ++b) {
    int kb = selb[wid][b];
    if (kb < 0) continue;
    const bf16* vr = vbh + ((size_t)h * NTOK + ((size_t)kb << 4)) * DHEAD + lane;
#pragma unroll
    for (int u = 0; u < 16; ++u)
      acc = fmaf(pb[wid][b * 16 + u], __bfloat162float(vr[(size_t)u * DHEAD]), acc);
  }
  f_out[((size_t)h * NTOK + i) * DHEAD + lane] = acc;
}

// ---------------- sliding-window attention (MFMA, 64 queries/block) ----------------
__global__ __launch_bounds__(256) void k_slide_attn(
    const bf16* __restrict__ rqh, const bf16* __restrict__ rql,
    const bf16* __restrict__ rkh, const bf16* __restrict__ rkl,
    const bf16* __restrict__ vtb, float* __restrict__ s_out) {
  const int h = blockIdx.y, nb = blockIdx.x;
  const int t = threadIdx.x, w = t >> 6, lane = t & 63;
  const int lr = lane & 15, kg = (lane >> 4) << 3;
  const int crow = (lane >> 4) << 2;
  const int wm = w >> 1, wn = w & 1;
  __shared__ float p[64][132];

  // QK (compensated 3-term)
  bf16x8 aH[2][2], aL[2][2];
#pragma unroll
  for (int mi = 0; mi < 2; ++mi) {
    size_t qo = ((size_t)h * NTOK + nb * 64 + wm * 32 + mi * 16 + lr) * DHEAD + kg;
#pragma unroll
    for (int ks = 0; ks < 2; ++ks) {
      aH[mi][ks] = *reinterpret_cast<const bf16x8*>(rqh + qo + ks * 32);
      aL[mi][ks] = *reinterpret_cast<const bf16x8*>(rql + qo + ks * 32);
    }
  }
  f32x4 acc[2][4];
#pragma unroll
  for (int a = 0; a < 2; ++a)
#pragma unroll
    for (int b = 0; b < 4; ++b) acc[a][b] = (f32x4){0.f, 0.f, 0.f, 0.f};
#pragma unroll
  for (int ni = 0; ni < 4; ++ni) {
    int col = (wn << 6) + (ni << 4) + lr;
    size_t ko = ((size_t)h * 2112 + nb * 64 + col) * 64 + kg;
#pragma unroll
    for (int ks = 0; ks < 2; ++ks) {
      bf16x8 bH = *reinterpret_cast<const bf16x8*>(rkh + ko + ks * 32);
      bf16x8 bL = *reinterpret_cast<const bf16x8*>(rkl + ko + ks * 32);
#pragma unroll
      for (int mi = 0; mi < 2; ++mi) {
        acc[mi][ni] = __builtin_amdgcn_mfma_f32_16x16x32_bf16(aH[mi][ks], bH, acc[mi][ni], 0, 0, 0);
        acc[mi][ni] = __builtin_amdgcn_mfma_f32_16x16x32_bf16(aL[mi][ks], bH, acc[mi][ni], 0, 0, 0);
        acc[mi][ni] = __builtin_amdgcn_mfma_f32_16x16x32_bf16(aH[mi][ks], bL, acc[mi][ni], 0, 0, 0);
      }
    }
  }
#pragma unroll
  for (int mi = 0; mi < 2; ++mi)
#pragma unroll
    for (int ni = 0; ni < 4; ++ni) {
      int col = (wn << 6) + (ni << 4) + lr;
#pragma unroll
      for (int r = 0; r < 4; ++r) {
        int qi2 = wm * 32 + mi * 16 + crow + r;
        bool ok = (col >= qi2 + 1) && (col <= qi2 + 64) && (nb > 0 || col >= 64);
        p[qi2][col] = ok ? acc[mi][ni][r] * 0.125f : NEGV;
      }
    }
  __syncthreads();

  // softmax: 4 threads per row
  const int qi = t >> 2, s = t & 3;
  float ev[32];
  float mx = -3.0e38f;
#pragma unroll
  for (int u = 0; u < 32; ++u) { ev[u] = p[qi][s + (u << 2)]; mx = fmaxf(mx, ev[u]); }
  mx = fmaxf(mx, __shfl_xor(mx, 1));
  mx = fmaxf(mx, __shfl_xor(mx, 2));
  float sum = 0.f;
#pragma unroll
  for (int u = 0; u < 32; ++u) { float e = __expf(ev[u] - mx); ev[u] = e; sum += e; }
  sum += __shfl_xor(sum, 1); sum += __shfl_xor(sum, 2);
  float invs = 1.f / sum;
#pragma unroll
  for (int u = 0; u < 32; ++u) p[qi][s + (u << 2)] = ev[u] * invs;
  __syncthreads();

  // PV: M=64 N=64 K=128
  f32x4 pacc[2][2];
#pragma unroll
  for (int a = 0; a < 2; ++a)
#pragma unroll
    for (int b = 0; b < 2; ++b) pacc[a][b] = (f32x4){0.f, 0.f, 0.f, 0.f};
#pragma unroll
  for (int ks = 0; ks < 4; ++ks) {
    int k0 = ks * 32 + kg;
    bf16x8 ph[2], pl[2];
#pragma unroll
    for (int mi = 0; mi < 2; ++mi) {
      int arow = wm * 32 + mi * 16 + lr;
      float4 x0 = *reinterpret_cast<const float4*>(&p[arow][k0]);
      float4 x1 = *reinterpret_cast<const float4*>(&p[arow][k0 + 4]);
      float xv[8] = {x0.x, x0.y, x0.z, x0.w, x1.x, x1.y, x1.z, x1.w};
#pragma unroll
      for (int e = 0; e < 8; ++e) {
        __bf16 hh = (__bf16)xv[e];
        ph[mi][e] = hh;
        pl[mi][e] = (__bf16)(xv[e] - (float)hh);
      }
    }
#pragma unroll
    for (int ni = 0; ni < 2; ++ni) {
      int d = (wn << 5) + (ni << 4) + lr;
      bf16x8 bv = *reinterpret_cast<const bf16x8*>(vtb + ((size_t)h * 64 + d) * 2112 + nb * 64 + k0);
#pragma unroll
      for (int mi = 0; mi < 2; ++mi) {
        pacc[mi][ni] = __builtin_amdgcn_mfma_f32_16x16x32_bf16(ph[mi], bv, pacc[mi][ni], 0, 0, 0);
        pacc[mi][ni] = __builtin_amdgcn_mfma_f32_16x16x32_bf16(pl[mi], bv, pacc[mi][ni], 0, 0, 0);
      }
    }
  }
#pragma unroll
  for (int mi = 0; mi < 2; ++mi)
#pragma unroll
    for (int ni = 0; ni < 2; ++ni) {
      int d = (wn << 5) + (ni << 4) + lr;
#pragma unroll
      for (int r = 0; r < 4; ++r) {
        int qi2 = wm * 32 + mi * 16 + crow + r;
        s_out[((size_t)h * NTOK + nb * 64 + qi2) * DHEAD + d] = pacc[mi][ni][r];
      }
    }
}

// ---------------- gate + combine -> bf16 ----------------
__global__ void k_combine(const float* __restrict__ strat, const float* __restrict__ c_out,
                          const float* __restrict__ f_out, const float* __restrict__ s_out,
                          bf16* __restrict__ comb) {
  int idx = blockIdx.x * 256 + threadIdx.x;
  int i = idx >> 9;
  int c = idx & 511;
  int h = c >> 6, d = c & 63;
  size_t a = ((size_t)h * NTOK + i) * DHEAD + d;
  const float* st = strat + (size_t)i * 24 + h * 3;
  comb[idx] = __float2bfloat16(st[0] * c_out[a] + st[1] * f_out[a] + st[2] * s_out[a]);
}

extern "C" void kernel_launch(void* const* d_in, const int* in_sizes, int n_in,
                              void* d_out, int out_size, void* d_ws, size_t ws_size,
                              hipStream_t stream) {
  const float* x      = (const float*)d_in[0];
  const float* g_norm = (const float*)d_in[1];
  const float* w_qkv  = (const float*)d_in[2];
  const float* k_pos  = (const float*)d_in[3];
  const float* v_pos  = (const float*)d_in[4];
  const float* mem_kv = (const float*)d_in[5];
  const float* k_w1   = (const float*)d_in[6];
  const float* k_b1   = (const float*)d_in[7];
  const float* k_w2   = (const float*)d_in[8];
  const float* k_b2   = (const float*)d_in[9];
  const float* v_w1   = (const float*)d_in[10];
  const float* v_b1   = (const float*)d_in[11];
  const float* v_w2   = (const float*)d_in[12];
  const float* v_b2   = (const float*)d_in[13];
  const float* w_comb = (const float*)d_in[14];
  const float* b_comb = (const float*)d_in[15];
  const float* w_out  = (const float*)d_in[16];
  float* out = (float*)d_out;
  char* wsb = (char*)d_ws;

  bf16* WQKV_H = (bf16*)(wsb + B_WQKV_H);
  bf16* WQKV_L = (bf16*)(wsb + B_WQKV_L);
  bf16* KW1_H  = (bf16*)(wsb + B_KW1_H);
  bf16* KW1_L  = (bf16*)(wsb + B_KW1_L);
  bf16* KW2_H  = (bf16*)(wsb + B_KW2_H);
  bf16* KW2_L  = (bf16*)(wsb + B_KW2_L);
  bf16* VW1_H  = (bf16*)(wsb + B_VW1_H);
  bf16* VW2_H  = (bf16*)(wsb + B_VW2_H);
  bf16* WOUT_H = (bf16*)(wsb + B_WOUT_H);
  bf16* HB_H   = (bf16*)(wsb + B_HB_H);
  bf16* HB_L   = (bf16*)(wsb + B_HB_L);
  bf16* QBH    = (bf16*)(wsb + B_QBH);
  bf16* QBM    = (bf16*)(wsb + B_QBM);
  bf16* QBL    = (bf16*)(wsb + B_QBL);
  float* KF    = (float*)(wsb + B_KF);
  bf16* VBH    = (bf16*)(wsb + B_VBH);
  bf16* RQH    = (bf16*)(wsb + B_RQH);
  bf16* RQL    = (bf16*)(wsb + B_RQL);
  bf16* RKH    = (bf16*)(wsb + B_RKH);
  bf16* RKL    = (bf16*)(wsb + B_RKL);
  float* RKF   = (float*)(wsb + B_RKF);
  bf16* VTB    = (bf16*)(wsb + B_VTB);
  bf16* CKT_H  = (bf16*)(wsb + B_CKT_H);
  bf16* CKT_M  = (bf16*)(wsb + B_CKT_M);
  bf16* CKT_L  = (bf16*)(wsb + B_CKT_L);
  bf16* CVT    = (bf16*)(wsb + B_CVT);
  float* STRAT = (float*)(wsb + B_STRAT);
  int*   SEL   = (int*)(wsb + B_SEL);
  float* COUT  = (float*)(wsb + B_COUT);
  float* FOUT  = (float*)(wsb + B_FOUT);
  float* SOUT  = (float*)(wsb + B_SOUT);
  bf16* KW_H   = (bf16*)(wsb + B_KW_H);
  bf16* KW_L   = (bf16*)(wsb + B_KW_L);
  bf16* VW_H   = (bf16*)(wsb + B_VW_H);
  bf16* HID_H  = (bf16*)(wsb + B_HID_H);
  bf16* HID_L  = (bf16*)(wsb + B_HID_L);
  bf16* COMBB  = (bf16*)(wsb + B_COMBB);

  // weight splits
  k_wt<<<dim3(16, 48), 256, 0, stream>>>(w_qkv, WQKV_H, WQKV_L, DMODEL, 1536);
  k_wt<<<dim3(32, 32), 256, 0, stream>>>(k_w1, KW1_H, KW1_L, CDIM, CDIM);
  k_wt<<<dim3(32, 2),  256, 0, stream>>>(k_w2, KW2_H, KW2_L, CDIM, DHEAD);
  k_wt<<<dim3(32, 32), 256, 0, stream>>>(v_w1, VW1_H, nullptr, CDIM, CDIM);
  k_wt<<<dim3(32, 2),  256, 0, stream>>>(v_w2, VW2_H, nullptr, CDIM, DHEAD);
  k_wt<<<dim3(16, 16), 256, 0, stream>>>(w_out, WOUT_H, nullptr, DMODEL, DMODEL);

  k_rmsnorm<<<NTOK, 256, 0, stream>>>(x, g_norm, HB_H, HB_L);
  k_zpad<<<128, 256, 0, stream>>>(RKH, RKL, VTB);
  // qkv (compensated) with fused split/scatter: q->QBH/QBM/QBL, k->KF, v->VBH
  k_cgemm<0, 3, 1><<<dim3(24, 32), 256, 0, stream>>>(
      HB_H, HB_L, WQKV_H, WQKV_L, nullptr, KF, QBH, QBM, VBH, QBL, NTOK, DMODEL, 1536);
  k_rope<<<2048, 256, 0, stream>>>(QBH, QBM, QBL, KF, RQH, RQL, RKH, RKL, RKF);
  k_vt<<<dim3(32, 8), 256, 0, stream>>>(VBH, VTB);
  k_windows<<<8128, 256, 0, stream>>>(KF, VBH, k_pos, v_pos, KW_H, KW_L, VW_H);
  // k-MLP (compensated, feeds selection) -> ckT hi/mid/lo
  k_cgemm<1, 2, 1><<<dim3(16, 32), 256, 0, stream>>>(
      KW_H, KW_L, KW1_H, KW1_L, k_b1, nullptr, HID_H, HID_L, nullptr, nullptr,
      NHEAD * NWIN, CDIM, CDIM);
  k_cgemm<0, 5, 1><<<dim3(1, 32), 256, 0, stream>>>(
      HID_H, HID_L, KW2_H, KW2_L, k_b2, nullptr, CKT_H, CKT_M, nullptr, CKT_L,
      NHEAD * NWIN, CDIM, DHEAD);
  // v-MLP (plain) -> cvT
  k_cgemm<1, 1, 0><<<dim3(16, 32), 256, 0, stream>>>(
      VW_H, nullptr, VW1_H, nullptr, v_b1, nullptr, HID_H, nullptr, nullptr, nullptr,
      NHEAD * NWIN, CDIM, CDIM);
  k_cgemm<0, 6, 0><<<dim3(1, 32), 256, 0, stream>>>(
      HID_H, nullptr, VW2_H, nullptr, v_b2, nullptr, CVT, nullptr, nullptr, nullptr,
      NHEAD * NWIN, CDIM, DHEAD);
  k_fillmem<<<1, 512, 0, stream>>>(mem_kv, CKT_H, CKT_M, CKT_L, CVT);
  // attention branches
  k_comp_attn<<<dim3(64, 8), 256, 0, stream>>>(QBH, QBM, QBL, CKT_H, CKT_M, CKT_L, CVT, COUT, SEL);
  k_fine_attn<<<dim3(512, 8), 256, 0, stream>>>(RQH, RQL, RKF, VBH, SEL, FOUT);
  k_slide_attn<<<dim3(32, 8), 256, 0, stream>>>(RQH, RQL, RKH, RKL, VTB, SOUT);
  // gates + combine + output projection
  k_strat<<<NTOK, 256, 0, stream>>>(HB_H, HB_L, w_comb, b_comb, STRAT);
  k_combine<<<4096, 256, 0, stream>>>(STRAT, COUT, FOUT, SOUT, COMBB);
  k_cgemm<0, 0, 0><<<dim3(8, 32), 256, 0, stream>>>(
      COMBB, nullptr, WOUT_H, nullptr, nullptr, out, nullptr, nullptr, nullptr, nullptr,
      NTOK, DMODEL, DMODEL);
}

// Round 8
// 310.016 us; speedup vs baseline: 4.2077x; 1.1924x over previous
//
#include <hip/hip_runtime.h>
#include <hip/hip_bf16.h>
#include <cstddef>

#define NTOK 2048
#define DMODEL 512
#define NHEAD 8
#define DHEAD 64
#define NWIN 254          // (2048-16)/8 + 1
#define CDIM 1024         // CB*DH
#define NEGV -1000000000.0f

typedef __attribute__((ext_vector_type(8))) __bf16 bf16x8;
typedef __attribute__((ext_vector_type(4))) float f32x4;
typedef __hip_bfloat16 bf16;

// ---------------- workspace layout (byte offsets) ----------------
static const size_t B_WQKV_H = 0;          // 1536*512*2
static const size_t B_WQKV_L = 1572864;
static const size_t B_KW1_H  = 3145728;    // 1024*1024*2
static const size_t B_KW1_L  = 5242880;
static const size_t B_KW2_H  = 7340032;    // 64*1024*2
static const size_t B_KW2_L  = 7471104;
static const size_t B_VW1_H  = 7602176;
static const size_t B_VW2_H  = 9699328;
static const size_t B_WOUT_H = 9830400;    // 512*512*2
static const size_t B_HB_H   = 10354688;   // 2048*512*2
static const size_t B_HB_L   = 12451840;
static const size_t B_QBH    = 14548992;   // 8*2048*64*2 (non-roped q, hi)
static const size_t B_QBL    = 16646144;   // (lo, 3rd term)
static const size_t B_KF     = 18743296;   // 8*2048*64*4 (k fp32, pre-rope; dead after k_post -> HIDV)
static const size_t B_VBH    = 22937600;   // 8*2048*64*2
static const size_t B_RQH    = 25034752;   // roped q hi/lo
static const size_t B_RQL    = 27131904;
static const size_t B_RKH    = 29229056;   // 8*2112*64*2 (roped k, 64 zero-pad rows front)
static const size_t B_RKL    = 31391744;
static const size_t B_VTB    = 33554432;   // 8*64*2112*2 (v^T, 64 zero-pad cols front)
static const size_t B_CKT_H  = 35717120;   // 8*256*64*2 (compressed k rows, j=0 mem)
static const size_t B_CKT_L  = 35979264;
static const size_t B_CVT    = 36241408;   // 8*64*256*2 (compressed v transposed)
static const size_t B_SEL    = 36700160;   // 8*2048*5*4
static const size_t B_COUT   = 37027840;   // 4194304 (overlays KW_H)
static const size_t B_FOUT   = 41222144;   // 4194304 (overlays KW_L)
static const size_t B_SOUT   = 45416448;   // 4194304 (overlays VW_H)
static const size_t B_KW_H   = B_COUT;     // 2032*1024*2 = 4161536
static const size_t B_KW_L   = B_FOUT;
static const size_t B_VW_H   = B_SOUT;
static const size_t B_HID_H  = 49610752;   // 4161536 (k hidden hi)
static const size_t B_HID_L  = 53772288;   // 4161536 (k hidden lo)
static const size_t B_QBM    = 57933824;   // 8*2048*64*2 (q mid term)
static const size_t B_CKT_M  = 60030976;   // 8*256*64*2
static const size_t B_RKF    = 60293120;   // 8*2048*64*4 (roped k fp32); end 64487424
static const size_t B_HIDV   = B_KF;       // v hidden hi (4161536 <= 4194304, KF dead)
static const size_t B_COMBB  = B_HID_H;    // 2097152 (after MLPs dead)

// ================= shared GEMM core (64x64 tile, 4 waves, K-step 32) =================
template <int COMP>
__device__ __forceinline__ void gemm_tile(
    const bf16* __restrict__ Ah, const bf16* __restrict__ Al,
    const bf16* __restrict__ Wh, const bf16* __restrict__ Wl,
    int M, int K, int row_base, int col_base, int lr, int kg,
    f32x4 accs[2][2]) {
  int ar0 = row_base + lr;       if (ar0 > M - 1) ar0 = M - 1;
  int ar1 = row_base + 16 + lr;  if (ar1 > M - 1) ar1 = M - 1;
  const size_t a0o = (size_t)ar0 * K + kg;
  const size_t a1o = (size_t)ar1 * K + kg;
  const size_t b0o = (size_t)(col_base + lr) * K + kg;
  const size_t b1o = (size_t)(col_base + 16 + lr) * K + kg;
  f32x4 acc00 = {}, acc01 = {}, acc10 = {}, acc11 = {};
  for (int k0 = 0; k0 < K; k0 += 32) {
    bf16x8 ah0 = *reinterpret_cast<const bf16x8*>(Ah + a0o + k0);
    bf16x8 ah1 = *reinterpret_cast<const bf16x8*>(Ah + a1o + k0);
    bf16x8 bh0 = *reinterpret_cast<const bf16x8*>(Wh + b0o + k0);
    bf16x8 bh1 = *reinterpret_cast<const bf16x8*>(Wh + b1o + k0);
    acc00 = __builtin_amdgcn_mfma_f32_16x16x32_bf16(ah0, bh0, acc00, 0, 0, 0);
    acc01 = __builtin_amdgcn_mfma_f32_16x16x32_bf16(ah0, bh1, acc01, 0, 0, 0);
    acc10 = __builtin_amdgcn_mfma_f32_16x16x32_bf16(ah1, bh0, acc10, 0, 0, 0);
    acc11 = __builtin_amdgcn_mfma_f32_16x16x32_bf16(ah1, bh1, acc11, 0, 0, 0);
    if constexpr (COMP) {
      bf16x8 al0 = *reinterpret_cast<const bf16x8*>(Al + a0o + k0);
      bf16x8 al1 = *reinterpret_cast<const bf16x8*>(Al + a1o + k0);
      bf16x8 bl0 = *reinterpret_cast<const bf16x8*>(Wl + b0o + k0);
      bf16x8 bl1 = *reinterpret_cast<const bf16x8*>(Wl + b1o + k0);
      acc00 = __builtin_amdgcn_mfma_f32_16x16x32_bf16(ah0, bl0, acc00, 0, 0, 0);
      acc01 = __builtin_amdgcn_mfma_f32_16x16x32_bf16(ah0, bl1, acc01, 0, 0, 0);
      acc10 = __builtin_amdgcn_mfma_f32_16x16x32_bf16(ah1, bl0, acc10, 0, 0, 0);
      acc11 = __builtin_amdgcn_mfma_f32_16x16x32_bf16(ah1, bl1, acc11, 0, 0, 0);
      acc00 = __builtin_amdgcn_mfma_f32_16x16x32_bf16(al0, bh0, acc00, 0, 0, 0);
      acc01 = __builtin_amdgcn_mfma_f32_16x16x32_bf16(al0, bh1, acc01, 0, 0, 0);
      acc10 = __builtin_amdgcn_mfma_f32_16x16x32_bf16(al1, bh0, acc10, 0, 0, 0);
      acc11 = __builtin_amdgcn_mfma_f32_16x16x32_bf16(al1, bh1, acc11, 0, 0, 0);
    }
  }
  accs[0][0] = acc00; accs[0][1] = acc01; accs[1][0] = acc10; accs[1][1] = acc11;
}

// ---------------- generic GEMM kernel (qkv scatter / fp32 out) ----------------
// OUT: 0 fp32 C; 3 qkv scatter (q hi/mid/lo, k fp32, v bf16)
template <int EPI, int OUT, int COMP>
__global__ __launch_bounds__(256) void k_cgemm(
    const bf16* __restrict__ Ah, const bf16* __restrict__ Al,
    const bf16* __restrict__ Wh, const bf16* __restrict__ Wl,
    const float* __restrict__ bias,
    float* __restrict__ Cf, bf16* __restrict__ P0,
    bf16* __restrict__ P1, bf16* __restrict__ P2, bf16* __restrict__ P3,
    int M, int K, int N) {
  const int lane = threadIdx.x & 63;
  const int w = threadIdx.x >> 6;
  const int wr = w >> 1, wc = w & 1;
  const int row_base = (blockIdx.y << 6) + (wr << 5);
  const int col_base = (blockIdx.x << 6) + (wc << 5);
  const int lr = lane & 15;
  const int kg = (lane >> 4) << 3;
  const int crow = (lane >> 4) << 2;

  f32x4 accs[2][2];
  gemm_tile<COMP>(Ah, Al, Wh, Wl, M, K, row_base, col_base, lr, kg, accs);

#pragma unroll
  for (int mi = 0; mi < 2; ++mi) {
#pragma unroll
    for (int ni = 0; ni < 2; ++ni) {
      int col = col_base + (ni << 4) + lr;
      float bv = bias ? bias[col] : 0.f;
#pragma unroll
      for (int r = 0; r < 4; ++r) {
        int row = row_base + (mi << 4) + crow + r;
        if (row < M) {
          float vv = accs[mi][ni][r] + bv;
          if (EPI == 1) vv = fmaxf(vv, 0.f);
          if constexpr (OUT == 0) {
            Cf[(size_t)row * N + col] = vv;
          } else {  // OUT == 3: qkv scatter
            int which = col >> 9, rem = col & 511;
            int hh = rem >> 6, dd = rem & 63;
            size_t o = ((size_t)hh * NTOK + row) * DHEAD + dd;
            if (which == 0) {
              bf16 h1 = __float2bfloat16(vv);
              float r1 = vv - __bfloat162float(h1);
              bf16 m1 = __float2bfloat16(r1);
              P0[o] = h1;
              P1[o] = m1;
              P3[o] = __float2bfloat16(r1 - __bfloat162float(m1));
            } else if (which == 1) {
              Cf[o] = vv;
            } else {
              P2[o] = __float2bfloat16(vv);
            }
          }
        }
      }
    }
  }
}

// ---------------- merged MLP1: z=0 k-path (compensated, hi/lo out), z=1 v-path ----------------
__global__ __launch_bounds__(256) void k_mlp1(
    const bf16* __restrict__ KWh, const bf16* __restrict__ KWl,
    const bf16* __restrict__ W1h, const bf16* __restrict__ W1l,
    const float* __restrict__ kb1,
    const bf16* __restrict__ VWh, const bf16* __restrict__ VW1h,
    const float* __restrict__ vb1,
    bf16* __restrict__ HKh, bf16* __restrict__ HKl, bf16* __restrict__ HVh) {
  const int lane = threadIdx.x & 63;
  const int w = threadIdx.x >> 6;
  const int wr = w >> 1, wc = w & 1;
  const int row_base = (blockIdx.y << 6) + (wr << 5);
  const int col_base = (blockIdx.x << 6) + (wc << 5);
  const int lr = lane & 15;
  const int kg = (lane >> 4) << 3;
  const int crow = (lane >> 4) << 2;
  const int M = NHEAD * NWIN;  // 2032

  f32x4 accs[2][2];
  if (blockIdx.z == 0)
    gemm_tile<1>(KWh, KWl, W1h, W1l, M, CDIM, row_base, col_base, lr, kg, accs);
  else
    gemm_tile<0>(VWh, nullptr, VW1h, nullptr, M, CDIM, row_base, col_base, lr, kg, accs);

  const float* bias = (blockIdx.z == 0) ? kb1 : vb1;
#pragma unroll
  for (int mi = 0; mi < 2; ++mi) {
#pragma unroll
    for (int ni = 0; ni < 2; ++ni) {
      int col = col_base + (ni << 4) + lr;
      float bv = bias[col];
#pragma unroll
      for (int r = 0; r < 4; ++r) {
        int row = row_base + (mi << 4) + crow + r;
        if (row < M) {
          float vv = fmaxf(accs[mi][ni][r] + bv, 0.f);
          size_t o = (size_t)row * CDIM + col;
          if (blockIdx.z == 0) {
            bf16 h1 = __float2bfloat16(vv);
            HKh[o] = h1;
            HKl[o] = __float2bfloat16(vv - __bfloat162float(h1));
          } else {
            HVh[o] = __float2bfloat16(vv);
          }
        }
      }
    }
  }
}

// ---------------- merged MLP2: z=0 k-path -> ckT hi/mid/lo, z=1 v-path -> cvT ----------------
__global__ __launch_bounds__(256) void k_mlp2(
    const bf16* __restrict__ HKh, const bf16* __restrict__ HKl,
    const bf16* __restrict__ W2h, const bf16* __restrict__ W2l,
    const float* __restrict__ kb2,
    const bf16* __restrict__ HVh, const bf16* __restrict__ VW2h,
    const float* __restrict__ vb2,
    bf16* __restrict__ ckh, bf16* __restrict__ ckm, bf16* __restrict__ ckl,
    bf16* __restrict__ cvtb) {
  const int lane = threadIdx.x & 63;
  const int w = threadIdx.x >> 6;
  const int wr = w >> 1, wc = w & 1;
  const int row_base = (blockIdx.y << 6) + (wr << 5);
  const int col_base = (wc << 5);
  const int lr = lane & 15;
  const int kg = (lane >> 4) << 3;
  const int crow = (lane >> 4) << 2;
  const int M = NHEAD * NWIN;

  f32x4 accs[2][2];
  if (blockIdx.z == 0)
    gemm_tile<1>(HKh, HKl, W2h, W2l, M, CDIM, row_base, col_base, lr, kg, accs);
  else
    gemm_tile<0>(HVh, nullptr, VW2h, nullptr, M, CDIM, row_base, col_base, lr, kg, accs);

  const float* bias = (blockIdx.z == 0) ? kb2 : vb2;
#pragma unroll
  for (int mi = 0; mi < 2; ++mi) {
#pragma unroll
    for (int ni = 0; ni < 2; ++ni) {
      int col = col_base + (ni << 4) + lr;
      float bv = bias[col];
#pragma unroll
      for (int r = 0; r < 4; ++r) {
        int row = row_base + (mi << 4) + crow + r;
        if (row < M) {
          float vv = accs[mi][ni][r] + bv;
          int hh = row / NWIN, jj = row - hh * NWIN;
          if (blockIdx.z == 0) {
            size_t o = ((size_t)hh * 256 + 1 + jj) * 64 + col;
            bf16 h1 = __float2bfloat16(vv);
            float r1 = vv - __bfloat162float(h1);
            bf16 m1 = __float2bfloat16(r1);
            ckh[o] = h1;
            ckm[o] = m1;
            ckl[o] = __float2bfloat16(r1 - __bfloat162float(m1));
          } else {
            cvtb[((size_t)hh * 64 + col) * 256 + 1 + jj] = __float2bfloat16(vv);
          }
        }
      }
    }
  }
}

// ================= k_setup: 6 weight transposes + zpad + fillmem + rmsnorm =================
__device__ __forceinline__ void wt_tile(const float* __restrict__ W,
                                        bf16* __restrict__ WTh, bf16* __restrict__ WTl,
                                        int K, int N, int bx, int by,
                                        float (*tsh)[33]) {
  const int k0 = bx << 5, n0 = by << 5;
  const int tx = threadIdx.x & 31, ty = threadIdx.x >> 5;
#pragma unroll
  for (int r = 0; r < 4; ++r)
    tsh[ty + (r << 3)][tx] = W[(size_t)(k0 + ty + (r << 3)) * N + n0 + tx];
  __syncthreads();
#pragma unroll
  for (int r = 0; r < 4; ++r) {
    float val = tsh[tx][ty + (r << 3)];
    size_t o = (size_t)(n0 + ty + (r << 3)) * K + k0 + tx;
    bf16 h1 = __float2bfloat16(val);
    WTh[o] = h1;
    if (WTl) WTl[o] = __float2bfloat16(val - __bfloat162float(h1));
  }
}

__global__ __launch_bounds__(256) void k_setup(
    const float* __restrict__ x, const float* __restrict__ g,
    const float* __restrict__ w_qkv, const float* __restrict__ k_w1,
    const float* __restrict__ k_w2, const float* __restrict__ v_w1,
    const float* __restrict__ v_w2, const float* __restrict__ w_out,
    const float* __restrict__ memkv,
    bf16* __restrict__ WQKV_H, bf16* __restrict__ WQKV_L,
    bf16* __restrict__ KW1_H, bf16* __restrict__ KW1_L,
    bf16* __restrict__ KW2_H, bf16* __restrict__ KW2_L,
    bf16* __restrict__ VW1_H, bf16* __restrict__ VW2_H, bf16* __restrict__ WOUT_H,
    bf16* __restrict__ hbh, bf16* __restrict__ hbl,
    bf16* __restrict__ rkh, bf16* __restrict__ rkl, bf16* __restrict__ vtb,
    bf16* __restrict__ ckh, bf16* __restrict__ ckm, bf16* __restrict__ ckl,
    bf16* __restrict__ cvtb) {
  __shared__ float tsh[32][33];
  __shared__ float wsum[4];
  __shared__ float scale_s;
  const int id = blockIdx.x;
  const int t = threadIdx.x;

  if (id < 768) {
    wt_tile(w_qkv, WQKV_H, WQKV_L, DMODEL, 1536, id % 16, id / 16, tsh);
  } else if (id < 1792) {
    int u = id - 768;  wt_tile(k_w1, KW1_H, KW1_L, CDIM, CDIM, u % 32, u / 32, tsh);
  } else if (id < 1856) {
    int u = id - 1792; wt_tile(k_w2, KW2_H, KW2_L, CDIM, DHEAD, u % 32, u / 32, tsh);
  } else if (id < 2880) {
    int u = id - 1856; wt_tile(v_w1, VW1_H, nullptr, CDIM, CDIM, u % 32, u / 32, tsh);
  } else if (id < 2944) {
    int u = id - 2880; wt_tile(v_w2, VW2_H, nullptr, CDIM, DHEAD, u % 32, u / 32, tsh);
  } else if (id < 3200) {
    int u = id - 2944; wt_tile(w_out, WOUT_H, nullptr, DMODEL, DMODEL, u % 16, u / 16, tsh);
  } else if (id < 3328) {
    // zpad: fronts of rkh/rkl rows and vtb cols
    int idx = (id - 3200) * 256 + t;   // [0, 32768)
    int h = idx >> 12, r = (idx >> 6) & 63, c = idx & 63;
    bf16 z = __float2bfloat16(0.f);
    rkh[((size_t)h * 2112 + r) * 64 + c] = z;
    rkl[((size_t)h * 2112 + r) * 64 + c] = z;
    vtb[((size_t)h * 64 + r) * 2112 + c] = z;
  } else if (id < 3330) {
    // fillmem: mem slot (j=0) + zero pad slot (j=255) of ckT/cvT
    int u = (id - 3328) * 256 + t;     // [0, 512)
    int h = u >> 6, e = u & 63;
    float kv = memkv[(size_t)h * DHEAD + e];
    bf16 h1 = __float2bfloat16(kv);
    float r1 = kv - __bfloat162float(h1);
    bf16 m1 = __float2bfloat16(r1);
    ckh[((size_t)h * 256) * 64 + e] = h1;
    ckm[((size_t)h * 256) * 64 + e] = m1;
    ckl[((size_t)h * 256) * 64 + e] = __float2bfloat16(r1 - __bfloat162float(m1));
    bf16 z = __float2bfloat16(0.f);
    ckh[((size_t)h * 256 + 255) * 64 + e] = z;
    ckm[((size_t)h * 256 + 255) * 64 + e] = z;
    ckl[((size_t)h * 256 + 255) * 64 + e] = z;
    float vv = memkv[(size_t)(NHEAD + h) * DHEAD + e];
    cvtb[((size_t)h * 64 + e) * 256 + 0] = __float2bfloat16(vv);
    cvtb[((size_t)h * 64 + e) * 256 + 255] = z;
  } else {
    // rmsnorm row
    const int row = id - 3330;
    const float* xr = x + (size_t)row * DMODEL;
    float s = 0.f;
    for (int c = t; c < DMODEL; c += 256) { float v = xr[c]; s += v * v; }
    for (int o = 32; o > 0; o >>= 1) s += __shfl_down(s, o);
    if ((t & 63) == 0) wsum[t >> 6] = s;
    __syncthreads();
    if (t == 0) {
      float tot = wsum[0] + wsum[1] + wsum[2] + wsum[3];
      scale_s = rsqrtf(tot * (1.f / DMODEL) + 1e-6f);
    }
    __syncthreads();
    float sc = scale_s;
    for (int c = t; c < DMODEL; c += 256) {
      float v = xr[c] * sc * g[c];
      bf16 h1 = __float2bfloat16(v);
      hbh[(size_t)row * DMODEL + c] = h1;
      hbl[(size_t)row * DMODEL + c] = __float2bfloat16(v - __bfloat162float(h1));
    }
  }
}

// ================= k_post: rope + v-transpose + compression windows =================
__global__ __launch_bounds__(256) void k_post(
    const bf16* __restrict__ qbh, const bf16* __restrict__ qbm,
    const bf16* __restrict__ qbl, const float* __restrict__ kf,
    const bf16* __restrict__ vbh,
    const float* __restrict__ kpos, const float* __restrict__ vpos,
    bf16* __restrict__ rqh, bf16* __restrict__ rql,
    bf16* __restrict__ rkh, bf16* __restrict__ rkl, float* __restrict__ rkf,
    bf16* __restrict__ vtb,
    bf16* __restrict__ kwh, bf16* __restrict__ kwl, bf16* __restrict__ vwh) {
  __shared__ bf16 tile[64][65];
  const int id = blockIdx.x;
  const int t = threadIdx.x;

  if (id < 2048) {
    // RoPE
    int idx = id * 256 + t;
    int i = idx & 31;
    int n = (idx >> 5) & (NTOK - 1);
    int h = idx >> 16;
    float ex = (float)(2 * i) * (1.f / 64.f);
    float inv = exp2f(-ex * 13.287712379549449f);
    float ang = (float)n * inv;
    float sn, cs;
    sincosf(ang, &sn, &cs);
    size_t base = ((size_t)h * NTOK + n) * DHEAD + 2 * i;
    float q1 = __bfloat162float(qbh[base]) + __bfloat162float(qbm[base]) + __bfloat162float(qbl[base]);
    float q2 = __bfloat162float(qbh[base + 1]) + __bfloat162float(qbm[base + 1]) + __bfloat162float(qbl[base + 1]);
    float r1 = q1 * cs - q2 * sn, r2 = q1 * sn + q2 * cs;
    bf16 h1 = __float2bfloat16(r1);
    rqh[base] = h1; rql[base] = __float2bfloat16(r1 - __bfloat162float(h1));
    h1 = __float2bfloat16(r2);
    rqh[base + 1] = h1; rql[base + 1] = __float2bfloat16(r2 - __bfloat162float(h1));
    float k1 = kf[base], k2 = kf[base + 1];
    float s1 = k1 * cs - k2 * sn, s2 = k1 * sn + k2 * cs;
    rkf[base] = s1;
    rkf[base + 1] = s2;
    size_t kb = ((size_t)h * 2112 + 64 + n) * DHEAD + 2 * i;
    h1 = __float2bfloat16(s1);
    rkh[kb] = h1; rkl[kb] = __float2bfloat16(s1 - __bfloat162float(h1));
    h1 = __float2bfloat16(s2);
    rkh[kb + 1] = h1; rkl[kb + 1] = __float2bfloat16(s2 - __bfloat162float(h1));
  } else if (id < 2304) {
    // v transpose (+64 col pad)
    int u = id - 2048;
    int h = u >> 5, n0 = (u & 31) << 6;
    int tx = t & 63, ty = t >> 6;
    for (int r = ty; r < 64; r += 4)
      tile[r][tx] = vbh[((size_t)h * NTOK + n0 + r) * DHEAD + tx];
    __syncthreads();
    for (int r = ty; r < 64; r += 4)
      vtb[((size_t)h * 64 + r) * 2112 + 64 + n0 + tx] = tile[tx][r];
  } else {
    // compression windows
    int idx = (id - 2304) * 256 + t;   // [0, 2080768)
    int d = idx & 63;
    int c = (idx >> 6) & 15;
    int j = (idx >> 10) % NWIN;
    int h = idx / (NWIN << 10);
    int srcpos = (j << 3) + c;
    size_t src = ((size_t)h * NTOK + srcpos) * DHEAD + d;
    size_t pp = ((size_t)h * 16 + c) * DHEAD + d;
    float kv = kf[src] + kpos[pp];
    bf16 h1 = __float2bfloat16(kv);
    kwh[idx] = h1;
    kwl[idx] = __float2bfloat16(kv - __bfloat162float(h1));
    vwh[idx] = __float2bfloat16(__bfloat162float(vbh[src]) + vpos[pp]);
  }
}

// ---------------- compression attention (MFMA, 32 queries/block) ----------------
__global__ __launch_bounds__(256) void k_comp_attn(
    const bf16* __restrict__ qbh, const bf16* __restrict__ qbm, const bf16* __restrict__ qbl,
    const bf16* __restrict__ ckh, const bf16* __restrict__ ckm, const bf16* __restrict__ ckl,
    const bf16* __restrict__ cvtb,
    float* __restrict__ c_out, int* __restrict__ sel) {
  const int h = blockIdx.y;
  const int i0 = blockIdx.x << 5;
  const int t = threadIdx.x;
  const int w = t >> 6, lane = t & 63;
  const int lr = lane & 15, kg = (lane >> 4) << 3;
  const int crow = (lane >> 4) << 2;

  __shared__ float p[32][260];

  // ---- QK^T, 6-term (hh, hm, mh, hl, lh, mm)
  bf16x8 aH[2][2], aM[2][2], aL[2][2];
#pragma unroll
  for (int mi = 0; mi < 2; ++mi) {
    size_t qo = ((size_t)h * NTOK + i0 + mi * 16 + lr) * DHEAD + kg;
#pragma unroll
    for (int ks = 0; ks < 2; ++ks) {
      aH[mi][ks] = *reinterpret_cast<const bf16x8*>(qbh + qo + ks * 32);
      aM[mi][ks] = *reinterpret_cast<const bf16x8*>(qbm + qo + ks * 32);
      aL[mi][ks] = *reinterpret_cast<const bf16x8*>(qbl + qo + ks * 32);
    }
  }
  f32x4 acc[2][4];
#pragma unroll
  for (int a = 0; a < 2; ++a)
#pragma unroll
    for (int b = 0; b < 4; ++b) acc[a][b] = (f32x4){0.f, 0.f, 0.f, 0.f};
#pragma unroll
  for (int ni = 0; ni < 4; ++ni) {
    int col = (w << 6) + (ni << 4) + lr;
    size_t ko = ((size_t)h * 256 + col) * 64 + kg;
#pragma unroll
    for (int ks = 0; ks < 2; ++ks) {
      bf16x8 bH = *reinterpret_cast<const bf16x8*>(ckh + ko + ks * 32);
      bf16x8 bM = *reinterpret_cast<const bf16x8*>(ckm + ko + ks * 32);
      bf16x8 bL = *reinterpret_cast<const bf16x8*>(ckl + ko + ks * 32);
#pragma unroll
      for (int mi = 0; mi < 2; ++mi) {
        acc[mi][ni] = __builtin_amdgcn_mfma_f32_16x16x32_bf16(aH[mi][ks], bH, acc[mi][ni], 0, 0, 0);
        acc[mi][ni] = __builtin_amdgcn_mfma_f32_16x16x32_bf16(aH[mi][ks], bM, acc[mi][ni], 0, 0, 0);
        acc[mi][ni] = __builtin_amdgcn_mfma_f32_16x16x32_bf16(aM[mi][ks], bH, acc[mi][ni], 0, 0, 0);
        acc[mi][ni] = __builtin_amdgcn_mfma_f32_16x16x32_bf16(aH[mi][ks], bL, acc[mi][ni], 0, 0, 0);
        acc[mi][ni] = __builtin_amdgcn_mfma_f32_16x16x32_bf16(aL[mi][ks], bH, acc[mi][ni], 0, 0, 0);
        acc[mi][ni] = __builtin_amdgcn_mfma_f32_16x16x32_bf16(aM[mi][ks], bM, acc[mi][ni], 0, 0, 0);
      }
    }
  }
#pragma unroll
  for (int mi = 0; mi < 2; ++mi)
#pragma unroll
    for (int ni = 0; ni < 4; ++ni) {
      int col = (w << 6) + (ni << 4) + lr;
      int wend = (col == 0) ? -1 : ((col - 1) << 3) + 15;
#pragma unroll
      for (int r = 0; r < 4; ++r) {
        int qi = mi * 16 + crow + r;
        bool ok = (col < 255) && (wend < i0 + qi);
        p[qi][col] = ok ? acc[mi][ni][r] * 0.125f : NEGV;
      }
    }
  __syncthreads();

  // ---- softmax: 8 threads per row
  const int qi = t >> 3, s = t & 7;
  float ev[32];
  float mx = -3.0e38f;
#pragma unroll
  for (int u = 0; u < 32; ++u) { ev[u] = p[qi][s + (u << 3)]; mx = fmaxf(mx, ev[u]); }
  mx = fmaxf(mx, __shfl_xor(mx, 1));
  mx = fmaxf(mx, __shfl_xor(mx, 2));
  mx = fmaxf(mx, __shfl_xor(mx, 4));
  float sum = 0.f;
#pragma unroll
  for (int u = 0; u < 32; ++u) { float e = __expf(ev[u] - mx); ev[u] = e; sum += e; }
  sum += __shfl_xor(sum, 1); sum += __shfl_xor(sum, 2); sum += __shfl_xor(sum, 4);
  float invs = 1.f / sum;
#pragma unroll
  for (int u = 0; u < 32; ++u) p[qi][s + (u << 3)] = ev[u] * invs;

  // ---- block importance in registers + wave-parallel top-4
  int qblk = (i0 + qi) >> 4;
  float vals[16];
#pragma unroll
  for (int u = 0; u < 16; ++u) {
    int f = (s << 4) + u;
    float v;
    if (f >= qblk || f == 127) v = NEGV;
    else v = (p[qi][2 * f + 1] + p[qi][2 * f + 2]) * 0.5f;
    vals[u] = v;
  }
  int base = ((h << 11) | (i0 + qi)) * 5;
  for (int kk = 0; kk < 4; ++kk) {
    float bv = -3.0e38f; int bi = 0;
#pragma unroll
    for (int u = 0; u < 16; ++u) {
      if (vals[u] > bv) { bv = vals[u]; bi = (s << 4) + u; }
    }
#pragma unroll
    for (int o = 1; o < 8; o <<= 1) {
      float ov = __shfl_xor(bv, o);
      int oi = __shfl_xor(bi, o);
      if (ov > bv || (ov == bv && oi < bi)) { bv = ov; bi = oi; }
    }
    if (s == 0) sel[base + kk] = (bv > -5.0e8f) ? bi : -1;
    if ((bi >> 4) == s) vals[bi & 15] = -3.0e38f;
  }
  if (s == 0) sel[base + 4] = (i0 + qi) >> 4;
  __syncthreads();

  // ---- PV: M=32 N=64 K=256, p split hi/lo (A), cvT bf16 (B)
  const int wm = w >> 1, wn = w & 1;
  const int arow = wm * 16 + lr;
  f32x4 pacc[2];
#pragma unroll
  for (int b = 0; b < 2; ++b) pacc[b] = (f32x4){0.f, 0.f, 0.f, 0.f};
#pragma unroll
  for (int ks = 0; ks < 8; ++ks) {
    int k0 = ks * 32 + kg;
    float4 x0 = *reinterpret_cast<const float4*>(&p[arow][k0]);
    float4 x1 = *reinterpret_cast<const float4*>(&p[arow][k0 + 4]);
    float xv[8] = {x0.x, x0.y, x0.z, x0.w, x1.x, x1.y, x1.z, x1.w};
    bf16x8 ph, pl;
#pragma unroll
    for (int e = 0; e < 8; ++e) {
      __bf16 hh = (__bf16)xv[e];
      ph[e] = hh;
      pl[e] = (__bf16)(xv[e] - (float)hh);
    }
#pragma unroll
    for (int ni = 0; ni < 2; ++ni) {
      int d = (wn << 5) + (ni << 4) + lr;
      bf16x8 bv = *reinterpret_cast<const bf16x8*>(cvtb + ((size_t)h * 64 + d) * 256 + k0);
      pacc[ni] = __builtin_amdgcn_mfma_f32_16x16x32_bf16(ph, bv, pacc[ni], 0, 0, 0);
      pacc[ni] = __builtin_amdgcn_mfma_f32_16x16x32_bf16(pl, bv, pacc[ni], 0, 0, 0);
    }
  }
#pragma unroll
  for (int ni = 0; ni < 2; ++ni) {
    int d = (wn << 5) + (ni << 4) + lr;
#pragma unroll
    for (int r = 0; r < 4; ++r) {
      int q2 = wm * 16 + crow + r;
      c_out[((size_t)h * NTOK + i0 + q2) * DHEAD + d] = pacc[ni][r];
    }
  }
}

// ---------------- fine attention: 1 wave per query, fp32 K via float4 ----------------
__global__ __launch_bounds__(256) void k_fine_attn(
    const bf16* __restrict__ rqh, const bf16* __restrict__ rql,
    const float* __restrict__ rkf, const bf16* __restrict__ vbh,
    const int* __restrict__ sel, float* __restrict__ f_out) {
  const int h = blockIdx.y;
  const int wid = threadIdx.x >> 6;
  const int lane = threadIdx.x & 63;
  const int i = (blockIdx.x << 2) | wid;

  __shared__ float qs[4][64];
  __shared__ float pb[4][80];
  __shared__ int selb[4][5];

  size_t qoff = ((size_t)h * NTOK + i) * DHEAD + lane;
  qs[wid][lane] = __bfloat162float(rqh[qoff]) + __bfloat162float(rql[qoff]);
  if (lane < 5) selb[wid][lane] = sel[((h << 11) | i) * 5 + lane];
  __syncthreads();

  float sim0 = NEGV, sim1 = NEGV;
  {
    int kb = selb[wid][lane >> 4];
    int pos = (kb << 4) + (lane & 15);
    if (kb >= 0 && pos <= i) {
      const float* kp = rkf + ((size_t)h * NTOK + pos) * DHEAD;
      float d = 0.f;
#pragma unroll
      for (int e4 = 0; e4 < 16; ++e4) {
        float4 kv = *reinterpret_cast<const float4*>(kp + e4 * 4);
        d = fmaf(qs[wid][e4 * 4 + 0], kv.x, d);
        d = fmaf(qs[wid][e4 * 4 + 1], kv.y, d);
        d = fmaf(qs[wid][e4 * 4 + 2], kv.z, d);
        d = fmaf(qs[wid][e4 * 4 + 3], kv.w, d);
      }
      sim0 = d * 0.125f;
    }
  }
  if (lane < 16) {
    int kb = selb[wid][4];
    int pos = (kb << 4) + lane;
    if (pos <= i) {
      const float* kp = rkf + ((size_t)h * NTOK + pos) * DHEAD;
      float d = 0.f;
#pragma unroll
      for (int e4 = 0; e4 < 16; ++e4) {
        float4 kv = *reinterpret_cast<const float4*>(kp + e4 * 4);
        d = fmaf(qs[wid][e4 * 4 + 0], kv.x, d);
        d = fmaf(qs[wid][e4 * 4 + 1], kv.y, d);
        d = fmaf(qs[wid][e4 * 4 + 2], kv.z, d);
        d = fmaf(qs[wid][e4 * 4 + 3], kv.w, d);
      }
      sim1 = d * 0.125f;
    }
  }

  float mx = fmaxf(sim0, sim1);
#pragma unroll
  for (int o = 32; o > 0; o >>= 1) mx = fmaxf(mx, __shfl_xor(mx, o));
  float e0 = __expf(sim0 - mx);
  float e1 = __expf(sim1 - mx);
  float sum = e0 + e1;
#pragma unroll
  for (int o = 32; o > 0; o >>= 1) sum += __shfl_xor(sum, o);
  float invs = 1.f / sum;
  pb[wid][lane] = e0 * invs;
  if (lane < 16) pb[wid][64 + lane] = e1 * invs;

  float acc = 0.f;
#pragma unroll
  for (int b = 0; b < 5; ++b) {
    int kb = selb[wid][b];
    if (kb < 0) continue;
    const bf16* vr = vbh + ((size_t)h * NTOK + ((size_t)kb << 4)) * DHEAD + lane;
#pragma unroll
    for (int u = 0; u < 16; ++u)
      acc = fmaf(pb[wid][b * 16 + u], __bfloat162float(vr[(size_t)u * DHEAD]), acc);
  }
  f_out[((size_t)h * NTOK + i) * DHEAD + lane] = acc;
}

// ---------------- sliding-window attention (MFMA, 64 queries/block) ----------------
__global__ __launch_bounds__(256) void k_slide_attn(
    const bf16* __restrict__ rqh, const bf16* __restrict__ rql,
    const bf16* __restrict__ rkh, const bf16* __restrict__ rkl,
    const bf16* __restrict__ vtb, float* __restrict__ s_out) {
  const int h = blockIdx.y, nb = blockIdx.x;
  const int t = threadIdx.x, w = t >> 6, lane = t & 63;
  const int lr = lane & 15, kg = (lane >> 4) << 3;
  const int crow = (lane >> 4) << 2;
  const int wm = w >> 1, wn = w & 1;
  __shared__ float p[64][132];

  bf16x8 aH[2][2], aL[2][2];
#pragma unroll
  for (int mi = 0; mi < 2; ++mi) {
    size_t qo = ((size_t)h * NTOK + nb * 64 + wm * 32 + mi * 16 + lr) * DHEAD + kg;
#pragma unroll
    for (int ks = 0; ks < 2; ++ks) {
      aH[mi][ks] = *reinterpret_cast<const bf16x8*>(rqh + qo + ks * 32);
      aL[mi][ks] = *reinterpret_cast<const bf16x8*>(rql + qo + ks * 32);
    }
  }
  f32x4 acc[2][4];
#pragma unroll
  for (int a = 0; a < 2; ++a)
#pragma unroll
    for (int b = 0; b < 4; ++b) acc[a][b] = (f32x4){0.f, 0.f, 0.f, 0.f};
#pragma unroll
  for (int ni = 0; ni < 4; ++ni) {
    int col = (wn << 6) + (ni << 4) + lr;
    size_t ko = ((size_t)h * 2112 + nb * 64 + col) * 64 + kg;
#pragma unroll
    for (int ks = 0; ks < 2; ++ks) {
      bf16x8 bH = *reinterpret_cast<const bf16x8*>(rkh + ko + ks * 32);
      bf16x8 bL = *reinterpret_cast<const bf16x8*>(rkl + ko + ks * 32);
#pragma unroll
      for (int mi = 0; mi < 2; ++mi) {
        acc[mi][ni] = __builtin_amdgcn_mfma_f32_16x16x32_bf16(aH[mi][ks], bH, acc[mi][ni], 0, 0, 0);
        acc[mi][ni] = __builtin_amdgcn_mfma_f32_16x16x32_bf16(aL[mi][ks], bH, acc[mi][ni], 0, 0, 0);
        acc[mi][ni] = __builtin_amdgcn_mfma_f32_16x16x32_bf16(aH[mi][ks], bL, acc[mi][ni], 0, 0, 0);
      }
    }
  }
#pragma unroll
  for (int mi = 0; mi < 2; ++mi)
#pragma unroll
    for (int ni = 0; ni < 4; ++ni) {
      int col = (wn << 6) + (ni << 4) + lr;
#pragma unroll
      for (int r = 0; r < 4; ++r) {
        int qi2 = wm * 32 + mi * 16 + crow + r;
        bool ok = (col >= qi2 + 1) && (col <= qi2 + 64) && (nb > 0 || col >= 64);
        p[qi2][col] = ok ? acc[mi][ni][r] * 0.125f : NEGV;
      }
    }
  __syncthreads();

  const int qi = t >> 2, s = t & 3;
  float ev[32];
  float mx = -3.0e38f;
#pragma unroll
  for (int u = 0; u < 32; ++u) { ev[u] = p[qi][s + (u << 2)]; mx = fmaxf(mx, ev[u]); }
  mx = fmaxf(mx, __shfl_xor(mx, 1));
  mx = fmaxf(mx, __shfl_xor(mx, 2));
  float sum = 0.f;
#pragma unroll
  for (int u = 0; u < 32; ++u) { float e = __expf(ev[u] - mx); ev[u] = e; sum += e; }
  sum += __shfl_xor(sum, 1); sum += __shfl_xor(sum, 2);
  float invs = 1.f / sum;
#pragma unroll
  for (int u = 0; u < 32; ++u) p[qi][s + (u << 2)] = ev[u] * invs;
  __syncthreads();

  f32x4 pacc[2][2];
#pragma unroll
  for (int a = 0; a < 2; ++a)
#pragma unroll
    for (int b = 0; b < 2; ++b) pacc[a][b] = (f32x4){0.f, 0.f, 0.f, 0.f};
#pragma unroll
  for (int ks = 0; ks < 4; ++ks) {
    int k0 = ks * 32 + kg;
    bf16x8 ph[2], pl[2];
#pragma unroll
    for (int mi = 0; mi < 2; ++mi) {
      int arow = wm * 32 + mi * 16 + lr;
      float4 x0 = *reinterpret_cast<const float4*>(&p[arow][k0]);
      float4 x1 = *reinterpret_cast<const float4*>(&p[arow][k0 + 4]);
      float xv[8] = {x0.x, x0.y, x0.z, x0.w, x1.x, x1.y, x1.z, x1.w};
#pragma unroll
      for (int e = 0; e < 8; ++e) {
        __bf16 hh = (__bf16)xv[e];
        ph[mi][e] = hh;
        pl[mi][e] = (__bf16)(xv[e] - (float)hh);
      }
    }
#pragma unroll
    for (int ni = 0; ni < 2; ++ni) {
      int d = (wn << 5) + (ni << 4) + lr;
      bf16x8 bv = *reinterpret_cast<const bf16x8*>(vtb + ((size_t)h * 64 + d) * 2112 + nb * 64 + k0);
#pragma unroll
      for (int mi = 0; mi < 2; ++mi) {
        pacc[mi][ni] = __builtin_amdgcn_mfma_f32_16x16x32_bf16(ph[mi], bv, pacc[mi][ni], 0, 0, 0);
        pacc[mi][ni] = __builtin_amdgcn_mfma_f32_16x16x32_bf16(pl[mi], bv, pacc[mi][ni], 0, 0, 0);
      }
    }
  }
#pragma unroll
  for (int mi = 0; mi < 2; ++mi)
#pragma unroll
    for (int ni = 0; ni < 2; ++ni) {
      int d = (wn << 5) + (ni << 4) + lr;
#pragma unroll
      for (int r = 0; r < 4; ++r) {
        int qi2 = wm * 32 + mi * 16 + crow + r;
        s_out[((size_t)h * NTOK + nb * 64 + qi2) * DHEAD + d] = pacc[mi][ni][r];
      }
    }
}

// ---------------- fused strat + combine: one block per token ----------------
__global__ __launch_bounds__(256) void k_combine2(
    const bf16* __restrict__ Ah, const bf16* __restrict__ Al,
    const float* __restrict__ W, const float* __restrict__ bias,
    const float* __restrict__ c_out, const float* __restrict__ f_out,
    const float* __restrict__ s_out, bf16* __restrict__ comb) {
  const int i = blockIdx.x;
  const int t = threadIdx.x;
  __shared__ float hs[DMODEL];
  __shared__ float st[24];
  size_t ro = (size_t)i * DMODEL;
#pragma unroll
  for (int u = 0; u < 2; ++u) {
    int c = t + u * 256;
    hs[c] = __bfloat162float(Ah[ro + c]) + __bfloat162float(Al[ro + c]);
  }
  __syncthreads();
  if (t < 192) {
    int c = t >> 3, s = t & 7;
    float acc = 0.f;
    for (int u = 0; u < 64; ++u) {
      int e = s * 64 + u;
      acc = fmaf(hs[e], W[(size_t)e * 24 + c], acc);
    }
    acc += __shfl_xor(acc, 1);
    acc += __shfl_xor(acc, 2);
    acc += __shfl_xor(acc, 4);
    if (s == 0) st[c] = 1.f / (1.f + expf(-(acc + bias[c])));
  }
  __syncthreads();
#pragma unroll
  for (int u = 0; u < 2; ++u) {
    int c = t + u * 256;
    int h = c >> 6, d = c & 63;
    size_t a = ((size_t)h * NTOK + i) * DHEAD + d;
    comb[ro + c] = __float2bfloat16(st[h * 3] * c_out[a] + st[h * 3 + 1] * f_out[a]
                                    + st[h * 3 + 2] * s_out[a]);
  }
}

extern "C" void kernel_launch(void* const* d_in, const int* in_sizes, int n_in,
                              void* d_out, int out_size, void* d_ws, size_t ws_size,
                              hipStream_t stream) {
  const float* x      = (const float*)d_in[0];
  const float* g_norm = (const float*)d_in[1];
  const float* w_qkv  = (const float*)d_in[2];
  const float* k_pos  = (const float*)d_in[3];
  const float* v_pos  = (const float*)d_in[4];
  const float* mem_kv = (const float*)d_in[5];
  const float* k_w1   = (const float*)d_in[6];
  const float* k_b1   = (const float*)d_in[7];
  const float* k_w2   = (const float*)d_in[8];
  const float* k_b2   = (const float*)d_in[9];
  const float* v_w1   = (const float*)d_in[10];
  const float* v_b1   = (const float*)d_in[11];
  const float* v_w2   = (const float*)d_in[12];
  const float* v_b2   = (const float*)d_in[13];
  const float* w_comb = (const float*)d_in[14];
  const float* b_comb = (const float*)d_in[15];
  const float* w_out  = (const float*)d_in[16];
  float* out = (float*)d_out;
  char* wsb = (char*)d_ws;

  bf16* WQKV_H = (bf16*)(wsb + B_WQKV_H);
  bf16* WQKV_L = (bf16*)(wsb + B_WQKV_L);
  bf16* KW1_H  = (bf16*)(wsb + B_KW1_H);
  bf16* KW1_L  = (bf16*)(wsb + B_KW1_L);
  bf16* KW2_H  = (bf16*)(wsb + B_KW2_H);
  bf16* KW2_L  = (bf16*)(wsb + B_KW2_L);
  bf16* VW1_H  = (bf16*)(wsb + B_VW1_H);
  bf16* VW2_H  = (bf16*)(wsb + B_VW2_H);
  bf16* WOUT_H = (bf16*)(wsb + B_WOUT_H);
  bf16* HB_H   = (bf16*)(wsb + B_HB_H);
  bf16* HB_L   = (bf16*)(wsb + B_HB_L);
  bf16* QBH    = (bf16*)(wsb + B_QBH);
  bf16* QBM    = (bf16*)(wsb + B_QBM);
  bf16* QBL    = (bf16*)(wsb + B_QBL);
  float* KF    = (float*)(wsb + B_KF);
  bf16* VBH    = (bf16*)(wsb + B_VBH);
  bf16* RQH    = (bf16*)(wsb + B_RQH);
  bf16* RQL    = (bf16*)(wsb + B_RQL);
  bf16* RKH    = (bf16*)(wsb + B_RKH);
  bf16* RKL    = (bf16*)(wsb + B_RKL);
  float* RKF   = (float*)(wsb + B_RKF);
  bf16* VTB    = (bf16*)(wsb + B_VTB);
  bf16* CKT_H  = (bf16*)(wsb + B_CKT_H);
  bf16* CKT_M  = (bf16*)(wsb + B_CKT_M);
  bf16* CKT_L  = (bf16*)(wsb + B_CKT_L);
  bf16* CVT    = (bf16*)(wsb + B_CVT);
  int*   SEL   = (int*)(wsb + B_SEL);
  float* COUT  = (float*)(wsb + B_COUT);
  float* FOUT  = (float*)(wsb + B_FOUT);
  float* SOUT  = (float*)(wsb + B_SOUT);
  bf16* KW_H   = (bf16*)(wsb + B_KW_H);
  bf16* KW_L   = (bf16*)(wsb + B_KW_L);
  bf16* VW_H   = (bf16*)(wsb + B_VW_H);
  bf16* HID_H  = (bf16*)(wsb + B_HID_H);
  bf16* HID_L  = (bf16*)(wsb + B_HID_L);
  bf16* HIDV   = (bf16*)(wsb + B_HIDV);
  bf16* COMBB  = (bf16*)(wsb + B_COMBB);

  // 1. setup: weight splits + pads + mem fill + rmsnorm
  k_setup<<<5378, 256, 0, stream>>>(x, g_norm, w_qkv, k_w1, k_w2, v_w1, v_w2, w_out, mem_kv,
                                    WQKV_H, WQKV_L, KW1_H, KW1_L, KW2_H, KW2_L,
                                    VW1_H, VW2_H, WOUT_H, HB_H, HB_L,
                                    RKH, RKL, VTB, CKT_H, CKT_M, CKT_L, CVT);
  // 2. qkv (compensated) with fused split/scatter
  k_cgemm<0, 3, 1><<<dim3(24, 32), 256, 0, stream>>>(
      HB_H, HB_L, WQKV_H, WQKV_L, nullptr, KF, QBH, QBM, VBH, QBL, NTOK, DMODEL, 1536);
  // 3. post: rope + v-transpose + windows
  k_post<<<10432, 256, 0, stream>>>(QBH, QBM, QBL, KF, VBH, k_pos, v_pos,
                                    RQH, RQL, RKH, RKL, RKF, VTB, KW_H, KW_L, VW_H);
  // 4. merged MLP1 (k compensated + v plain); HIDV overlays dead KF
  k_mlp1<<<dim3(16, 32, 2), 256, 0, stream>>>(KW_H, KW_L, KW1_H, KW1_L, k_b1,
                                              VW_H, VW1_H, v_b1, HID_H, HID_L, HIDV);
  // 5. merged MLP2 -> ckT hi/mid/lo + cvT
  k_mlp2<<<dim3(1, 32, 2), 256, 0, stream>>>(HID_H, HID_L, KW2_H, KW2_L, k_b2,
                                             HIDV, VW2_H, v_b2, CKT_H, CKT_M, CKT_L, CVT);
  // 6-8. attention branches
  k_comp_attn<<<dim3(64, 8), 256, 0, stream>>>(QBH, QBM, QBL, CKT_H, CKT_M, CKT_L, CVT, COUT, SEL);
  k_fine_attn<<<dim3(512, 8), 256, 0, stream>>>(RQH, RQL, RKF, VBH, SEL, FOUT);
  k_slide_attn<<<dim3(32, 8), 256, 0, stream>>>(RQH, RQL, RKH, RKL, VTB, SOUT);
  // 9. fused strat + combine
  k_combine2<<<NTOK, 256, 0, stream>>>(HB_H, HB_L, w_comb, b_comb, COUT, FOUT, SOUT, COMBB);
  // 10. output projection
  k_cgemm<0, 0, 0><<<dim3(8, 32), 256, 0, stream>>>(
      COMBB, nullptr, WOUT_H, nullptr, nullptr, out, nullptr, nullptr, nullptr, nullptr,
      NTOK, DMODEL, DMODEL);
}

// Round 9
// 291.415 us; speedup vs baseline: 4.4762x; 1.0638x over previous
//
#include <hip/hip_runtime.h>
#include <hip/hip_bf16.h>
#include <cstddef>

#define NTOK 2048
#define DMODEL 512
#define NHEAD 8
#define DHEAD 64
#define NWIN 254          // (2048-16)/8 + 1
#define CDIM 1024         // CB*DH
#define NEGV -1000000000.0f

typedef __attribute__((ext_vector_type(8))) __bf16 bf16x8;
typedef __attribute__((ext_vector_type(4))) float f32x4;
typedef __hip_bfloat16 bf16;

// ---------------- workspace layout (byte offsets) ----------------
static const size_t B_WQKV_H = 0;          // 1536*512*2
static const size_t B_WQKV_L = 1572864;
static const size_t B_KW1_H  = 3145728;    // 1024*1024*2
static const size_t B_KW1_L  = 5242880;
static const size_t B_KW2_H  = 7340032;    // 64*1024*2
static const size_t B_KW2_L  = 7471104;
static const size_t B_VW1_H  = 7602176;
static const size_t B_VW2_H  = 9699328;
static const size_t B_WOUT_H = 9830400;    // 512*512*2
static const size_t B_HB_H   = 10354688;   // 2048*512*2
static const size_t B_HB_L   = 12451840;
static const size_t B_QBH    = 14548992;   // 8*2048*64*2 (non-roped q, hi)
static const size_t B_QBL    = 16646144;   // (lo, 3rd term)
static const size_t B_KF     = 18743296;   // 8*2048*64*4 (k fp32, pre-rope; dead after k_post -> HIDV)
static const size_t B_VBH    = 22937600;   // 8*2048*64*2
static const size_t B_RQH    = 25034752;   // roped q hi/lo
static const size_t B_RQL    = 27131904;
static const size_t B_RKH    = 29229056;   // 8*2112*64*2 (roped k, 64 zero-pad rows front)
static const size_t B_RKL    = 31391744;
static const size_t B_VTB    = 33554432;   // 8*64*2112*2 (v^T, 64 zero-pad cols front)
static const size_t B_CKT_H  = 35717120;   // 8*256*64*2 (compressed k rows, j=0 mem)
static const size_t B_CKT_L  = 35979264;
static const size_t B_CVT    = 36241408;   // 8*64*256*2 (compressed v transposed)
static const size_t B_SEL    = 36700160;   // 8*2048*5*4
static const size_t B_COUT   = 37027840;   // 4194304 (overlays KW_H)
static const size_t B_FOUT   = 41222144;   // 4194304 (overlays KW_L)
static const size_t B_SOUT   = 45416448;   // 4194304 (overlays VW_H)
static const size_t B_KW_H   = B_COUT;     // 2032*1024*2 = 4161536
static const size_t B_KW_L   = B_FOUT;
static const size_t B_VW_H   = B_SOUT;
static const size_t B_HID_H  = 49610752;   // 4161536 (k hidden hi)
static const size_t B_HID_L  = 53772288;   // 4161536 (k hidden lo)
static const size_t B_QBM    = 57933824;   // 8*2048*64*2 (q mid term)
static const size_t B_CKT_M  = 60030976;   // 8*256*64*2
static const size_t B_RKF    = 60293120;   // 8*2048*64*4 (roped k fp32); end 64487424
static const size_t B_HIDV   = B_KF;       // v hidden hi (4161536 <= 4194304, KF dead)
static const size_t B_COMBB  = B_HID_H;    // 2097152 (after MLPs dead)

// ================= 32x32-per-wave GEMM core (64x64 block tile) =================
template <int COMP>
__device__ __forceinline__ void gemm_tile(
    const bf16* __restrict__ Ah, const bf16* __restrict__ Al,
    const bf16* __restrict__ Wh, const bf16* __restrict__ Wl,
    int M, int K, int row_base, int col_base, int lr, int kg,
    f32x4 accs[2][2]) {
  int ar0 = row_base + lr;       if (ar0 > M - 1) ar0 = M - 1;
  int ar1 = row_base + 16 + lr;  if (ar1 > M - 1) ar1 = M - 1;
  const size_t a0o = (size_t)ar0 * K + kg;
  const size_t a1o = (size_t)ar1 * K + kg;
  const size_t b0o = (size_t)(col_base + lr) * K + kg;
  const size_t b1o = (size_t)(col_base + 16 + lr) * K + kg;
  f32x4 acc00 = {}, acc01 = {}, acc10 = {}, acc11 = {};
  for (int k0 = 0; k0 < K; k0 += 32) {
    bf16x8 ah0 = *reinterpret_cast<const bf16x8*>(Ah + a0o + k0);
    bf16x8 ah1 = *reinterpret_cast<const bf16x8*>(Ah + a1o + k0);
    bf16x8 bh0 = *reinterpret_cast<const bf16x8*>(Wh + b0o + k0);
    bf16x8 bh1 = *reinterpret_cast<const bf16x8*>(Wh + b1o + k0);
    acc00 = __builtin_amdgcn_mfma_f32_16x16x32_bf16(ah0, bh0, acc00, 0, 0, 0);
    acc01 = __builtin_amdgcn_mfma_f32_16x16x32_bf16(ah0, bh1, acc01, 0, 0, 0);
    acc10 = __builtin_amdgcn_mfma_f32_16x16x32_bf16(ah1, bh0, acc10, 0, 0, 0);
    acc11 = __builtin_amdgcn_mfma_f32_16x16x32_bf16(ah1, bh1, acc11, 0, 0, 0);
    if constexpr (COMP) {
      bf16x8 al0 = *reinterpret_cast<const bf16x8*>(Al + a0o + k0);
      bf16x8 al1 = *reinterpret_cast<const bf16x8*>(Al + a1o + k0);
      bf16x8 bl0 = *reinterpret_cast<const bf16x8*>(Wl + b0o + k0);
      bf16x8 bl1 = *reinterpret_cast<const bf16x8*>(Wl + b1o + k0);
      acc00 = __builtin_amdgcn_mfma_f32_16x16x32_bf16(ah0, bl0, acc00, 0, 0, 0);
      acc01 = __builtin_amdgcn_mfma_f32_16x16x32_bf16(ah0, bl1, acc01, 0, 0, 0);
      acc10 = __builtin_amdgcn_mfma_f32_16x16x32_bf16(ah1, bl0, acc10, 0, 0, 0);
      acc11 = __builtin_amdgcn_mfma_f32_16x16x32_bf16(ah1, bl1, acc11, 0, 0, 0);
      acc00 = __builtin_amdgcn_mfma_f32_16x16x32_bf16(al0, bh0, acc00, 0, 0, 0);
      acc01 = __builtin_amdgcn_mfma_f32_16x16x32_bf16(al0, bh1, acc01, 0, 0, 0);
      acc10 = __builtin_amdgcn_mfma_f32_16x16x32_bf16(al1, bh0, acc10, 0, 0, 0);
      acc11 = __builtin_amdgcn_mfma_f32_16x16x32_bf16(al1, bh1, acc11, 0, 0, 0);
    }
  }
  accs[0][0] = acc00; accs[0][1] = acc01; accs[1][0] = acc10; accs[1][1] = acc11;
}

// ================= 64x64-per-wave GEMM core (128x128 block tile) =================
// Per K-step: 16 (COMP) / 8 loads vs 48 / 16 MFMAs -> 3x arithmetic intensity of the
// 32x32 core; MFMA stream covers next-iter load latency within a single wave.
template <int COMP>
__device__ __forceinline__ void gemm_tile64(
    const bf16* __restrict__ Ah, const bf16* __restrict__ Al,
    const bf16* __restrict__ Wh, const bf16* __restrict__ Wl,
    int M, int K, int row_base, int col_base, int lr, int kg,
    f32x4 (&acc)[4][4]) {
  size_t ao[4], bo[4];
#pragma unroll
  for (int mi = 0; mi < 4; ++mi) {
    int r = row_base + mi * 16 + lr; if (r > M - 1) r = M - 1;
    ao[mi] = (size_t)r * K + kg;
  }
#pragma unroll
  for (int ni = 0; ni < 4; ++ni)
    bo[ni] = (size_t)(col_base + ni * 16 + lr) * K + kg;

  for (int k0 = 0; k0 < K; k0 += 32) {
    bf16x8 ah[4], bh[4];
#pragma unroll
    for (int mi = 0; mi < 4; ++mi) ah[mi] = *reinterpret_cast<const bf16x8*>(Ah + ao[mi] + k0);
#pragma unroll
    for (int ni = 0; ni < 4; ++ni) bh[ni] = *reinterpret_cast<const bf16x8*>(Wh + bo[ni] + k0);
#pragma unroll
    for (int mi = 0; mi < 4; ++mi)
#pragma unroll
      for (int ni = 0; ni < 4; ++ni)
        acc[mi][ni] = __builtin_amdgcn_mfma_f32_16x16x32_bf16(ah[mi], bh[ni], acc[mi][ni], 0, 0, 0);
    if constexpr (COMP) {
      bf16x8 al[4], bl[4];
#pragma unroll
      for (int mi = 0; mi < 4; ++mi) al[mi] = *reinterpret_cast<const bf16x8*>(Al + ao[mi] + k0);
#pragma unroll
      for (int ni = 0; ni < 4; ++ni) bl[ni] = *reinterpret_cast<const bf16x8*>(Wl + bo[ni] + k0);
#pragma unroll
      for (int mi = 0; mi < 4; ++mi)
#pragma unroll
        for (int ni = 0; ni < 4; ++ni) {
          acc[mi][ni] = __builtin_amdgcn_mfma_f32_16x16x32_bf16(ah[mi], bl[ni], acc[mi][ni], 0, 0, 0);
          acc[mi][ni] = __builtin_amdgcn_mfma_f32_16x16x32_bf16(al[mi], bh[ni], acc[mi][ni], 0, 0, 0);
        }
    }
  }
}

// ---------------- generic GEMM kernel (fp32 out; used for out-proj) ----------------
template <int EPI, int COMP>
__global__ __launch_bounds__(256) void k_cgemm(
    const bf16* __restrict__ Ah, const bf16* __restrict__ Al,
    const bf16* __restrict__ Wh, const bf16* __restrict__ Wl,
    const float* __restrict__ bias, float* __restrict__ Cf,
    int M, int K, int N) {
  const int lane = threadIdx.x & 63;
  const int w = threadIdx.x >> 6;
  const int wr = w >> 1, wc = w & 1;
  const int row_base = (blockIdx.y << 6) + (wr << 5);
  const int col_base = (blockIdx.x << 6) + (wc << 5);
  const int lr = lane & 15;
  const int kg = (lane >> 4) << 3;
  const int crow = (lane >> 4) << 2;

  f32x4 accs[2][2];
  gemm_tile<COMP>(Ah, Al, Wh, Wl, M, K, row_base, col_base, lr, kg, accs);

#pragma unroll
  for (int mi = 0; mi < 2; ++mi) {
#pragma unroll
    for (int ni = 0; ni < 2; ++ni) {
      int col = col_base + (ni << 4) + lr;
      float bv = bias ? bias[col] : 0.f;
#pragma unroll
      for (int r = 0; r < 4; ++r) {
        int row = row_base + (mi << 4) + crow + r;
        if (row < M) {
          float vv = accs[mi][ni][r] + bv;
          if (EPI == 1) vv = fmaxf(vv, 0.f);
          Cf[(size_t)row * N + col] = vv;
        }
      }
    }
  }
}

// ---------------- qkv GEMM (64x64/wave, compensated, fused split/scatter) ----------------
__global__ __launch_bounds__(256) void k_qkv(
    const bf16* __restrict__ Ah, const bf16* __restrict__ Al,
    const bf16* __restrict__ Wh, const bf16* __restrict__ Wl,
    float* __restrict__ KFo, bf16* __restrict__ QH, bf16* __restrict__ QM,
    bf16* __restrict__ QL, bf16* __restrict__ VB) {
  const int lane = threadIdx.x & 63;
  const int w = threadIdx.x >> 6;
  const int wr = w >> 1, wc = w & 1;
  const int row_base = (blockIdx.y << 7) + (wr << 6);
  const int col_base = (blockIdx.x << 7) + (wc << 6);
  const int lr = lane & 15;
  const int kg = (lane >> 4) << 3;
  const int crow = (lane >> 4) << 2;

  f32x4 acc[4][4];
#pragma unroll
  for (int a = 0; a < 4; ++a)
#pragma unroll
    for (int b = 0; b < 4; ++b) acc[a][b] = (f32x4){0.f, 0.f, 0.f, 0.f};
  gemm_tile64<1>(Ah, Al, Wh, Wl, NTOK, DMODEL, row_base, col_base, lr, kg, acc);

#pragma unroll
  for (int mi = 0; mi < 4; ++mi) {
#pragma unroll
    for (int ni = 0; ni < 4; ++ni) {
      int col = col_base + (ni << 4) + lr;
      int which = col >> 9, rem = col & 511;
      int hh = rem >> 6, dd = rem & 63;
#pragma unroll
      for (int r = 0; r < 4; ++r) {
        int row = row_base + (mi << 4) + crow + r;   // M=2048 exact, no guard
        float vv = acc[mi][ni][r];
        size_t o = ((size_t)hh * NTOK + row) * DHEAD + dd;
        if (which == 0) {
          bf16 h1 = __float2bfloat16(vv);
          float r1 = vv - __bfloat162float(h1);
          bf16 m1 = __float2bfloat16(r1);
          QH[o] = h1;
          QM[o] = m1;
          QL[o] = __float2bfloat16(r1 - __bfloat162float(m1));
        } else if (which == 1) {
          KFo[o] = vv;
        } else {
          VB[o] = __float2bfloat16(vv);
        }
      }
    }
  }
}

// ---------------- merged MLP1 (64x64/wave): z=0 k-path (comp, hi/lo out), z=1 v-path ----------------
__global__ __launch_bounds__(256) void k_mlp1(
    const bf16* __restrict__ KWh, const bf16* __restrict__ KWl,
    const bf16* __restrict__ W1h, const bf16* __restrict__ W1l,
    const float* __restrict__ kb1,
    const bf16* __restrict__ VWh, const bf16* __restrict__ VW1h,
    const float* __restrict__ vb1,
    bf16* __restrict__ HKh, bf16* __restrict__ HKl, bf16* __restrict__ HVh) {
  const int lane = threadIdx.x & 63;
  const int w = threadIdx.x >> 6;
  const int wr = w >> 1, wc = w & 1;
  const int row_base = (blockIdx.y << 7) + (wr << 6);
  const int col_base = (blockIdx.x << 7) + (wc << 6);
  const int lr = lane & 15;
  const int kg = (lane >> 4) << 3;
  const int crow = (lane >> 4) << 2;
  const int M = NHEAD * NWIN;  // 2032

  f32x4 acc[4][4];
#pragma unroll
  for (int a = 0; a < 4; ++a)
#pragma unroll
    for (int b = 0; b < 4; ++b) acc[a][b] = (f32x4){0.f, 0.f, 0.f, 0.f};
  if (blockIdx.z == 0)
    gemm_tile64<1>(KWh, KWl, W1h, W1l, M, CDIM, row_base, col_base, lr, kg, acc);
  else
    gemm_tile64<0>(VWh, nullptr, VW1h, nullptr, M, CDIM, row_base, col_base, lr, kg, acc);

  const float* bias = (blockIdx.z == 0) ? kb1 : vb1;
#pragma unroll
  for (int mi = 0; mi < 4; ++mi) {
#pragma unroll
    for (int ni = 0; ni < 4; ++ni) {
      int col = col_base + (ni << 4) + lr;
      float bv = bias[col];
#pragma unroll
      for (int r = 0; r < 4; ++r) {
        int row = row_base + (mi << 4) + crow + r;
        if (row < M) {
          float vv = fmaxf(acc[mi][ni][r] + bv, 0.f);
          size_t o = (size_t)row * CDIM + col;
          if (blockIdx.z == 0) {
            bf16 h1 = __float2bfloat16(vv);
            HKh[o] = h1;
            HKl[o] = __float2bfloat16(vv - __bfloat162float(h1));
          } else {
            HVh[o] = __float2bfloat16(vv);
          }
        }
      }
    }
  }
}

// ---------------- merged MLP2: z=0 k-path -> ckT hi/mid/lo, z=1 v-path -> cvT ----------------
__global__ __launch_bounds__(256) void k_mlp2(
    const bf16* __restrict__ HKh, const bf16* __restrict__ HKl,
    const bf16* __restrict__ W2h, const bf16* __restrict__ W2l,
    const float* __restrict__ kb2,
    const bf16* __restrict__ HVh, const bf16* __restrict__ VW2h,
    const float* __restrict__ vb2,
    bf16* __restrict__ ckh, bf16* __restrict__ ckm, bf16* __restrict__ ckl,
    bf16* __restrict__ cvtb) {
  const int lane = threadIdx.x & 63;
  const int w = threadIdx.x >> 6;
  const int wr = w >> 1, wc = w & 1;
  const int row_base = (blockIdx.y << 6) + (wr << 5);
  const int col_base = (wc << 5);
  const int lr = lane & 15;
  const int kg = (lane >> 4) << 3;
  const int crow = (lane >> 4) << 2;
  const int M = NHEAD * NWIN;

  f32x4 accs[2][2];
  if (blockIdx.z == 0)
    gemm_tile<1>(HKh, HKl, W2h, W2l, M, CDIM, row_base, col_base, lr, kg, accs);
  else
    gemm_tile<0>(HVh, nullptr, VW2h, nullptr, M, CDIM, row_base, col_base, lr, kg, accs);

  const float* bias = (blockIdx.z == 0) ? kb2 : vb2;
#pragma unroll
  for (int mi = 0; mi < 2; ++mi) {
#pragma unroll
    for (int ni = 0; ni < 2; ++ni) {
      int col = col_base + (ni << 4) + lr;
      float bv = bias[col];
#pragma unroll
      for (int r = 0; r < 4; ++r) {
        int row = row_base + (mi << 4) + crow + r;
        if (row < M) {
          float vv = accs[mi][ni][r] + bv;
          int hh = row / NWIN, jj = row - hh * NWIN;
          if (blockIdx.z == 0) {
            size_t o = ((size_t)hh * 256 + 1 + jj) * 64 + col;
            bf16 h1 = __float2bfloat16(vv);
            float r1 = vv - __bfloat162float(h1);
            bf16 m1 = __float2bfloat16(r1);
            ckh[o] = h1;
            ckm[o] = m1;
            ckl[o] = __float2bfloat16(r1 - __bfloat162float(m1));
          } else {
            cvtb[((size_t)hh * 64 + col) * 256 + 1 + jj] = __float2bfloat16(vv);
          }
        }
      }
    }
  }
}

// ================= k_setup: 6 weight transposes + zpad + fillmem + rmsnorm =================
__device__ __forceinline__ void wt_tile(const float* __restrict__ W,
                                        bf16* __restrict__ WTh, bf16* __restrict__ WTl,
                                        int K, int N, int bx, int by,
                                        float (*tsh)[33]) {
  const int k0 = bx << 5, n0 = by << 5;
  const int tx = threadIdx.x & 31, ty = threadIdx.x >> 5;
#pragma unroll
  for (int r = 0; r < 4; ++r)
    tsh[ty + (r << 3)][tx] = W[(size_t)(k0 + ty + (r << 3)) * N + n0 + tx];
  __syncthreads();
#pragma unroll
  for (int r = 0; r < 4; ++r) {
    float val = tsh[tx][ty + (r << 3)];
    size_t o = (size_t)(n0 + ty + (r << 3)) * K + k0 + tx;
    bf16 h1 = __float2bfloat16(val);
    WTh[o] = h1;
    if (WTl) WTl[o] = __float2bfloat16(val - __bfloat162float(h1));
  }
}

__global__ __launch_bounds__(256) void k_setup(
    const float* __restrict__ x, const float* __restrict__ g,
    const float* __restrict__ w_qkv, const float* __restrict__ k_w1,
    const float* __restrict__ k_w2, const float* __restrict__ v_w1,
    const float* __restrict__ v_w2, const float* __restrict__ w_out,
    const float* __restrict__ memkv,
    bf16* __restrict__ WQKV_H, bf16* __restrict__ WQKV_L,
    bf16* __restrict__ KW1_H, bf16* __restrict__ KW1_L,
    bf16* __restrict__ KW2_H, bf16* __restrict__ KW2_L,
    bf16* __restrict__ VW1_H, bf16* __restrict__ VW2_H, bf16* __restrict__ WOUT_H,
    bf16* __restrict__ hbh, bf16* __restrict__ hbl,
    bf16* __restrict__ rkh, bf16* __restrict__ rkl, bf16* __restrict__ vtb,
    bf16* __restrict__ ckh, bf16* __restrict__ ckm, bf16* __restrict__ ckl,
    bf16* __restrict__ cvtb) {
  __shared__ float tsh[32][33];
  __shared__ float wsum[4];
  __shared__ float scale_s;
  const int id = blockIdx.x;
  const int t = threadIdx.x;

  if (id < 768) {
    wt_tile(w_qkv, WQKV_H, WQKV_L, DMODEL, 1536, id % 16, id / 16, tsh);
  } else if (id < 1792) {
    int u = id - 768;  wt_tile(k_w1, KW1_H, KW1_L, CDIM, CDIM, u % 32, u / 32, tsh);
  } else if (id < 1856) {
    int u = id - 1792; wt_tile(k_w2, KW2_H, KW2_L, CDIM, DHEAD, u % 32, u / 32, tsh);
  } else if (id < 2880) {
    int u = id - 1856; wt_tile(v_w1, VW1_H, nullptr, CDIM, CDIM, u % 32, u / 32, tsh);
  } else if (id < 2944) {
    int u = id - 2880; wt_tile(v_w2, VW2_H, nullptr, CDIM, DHEAD, u % 32, u / 32, tsh);
  } else if (id < 3200) {
    int u = id - 2944; wt_tile(w_out, WOUT_H, nullptr, DMODEL, DMODEL, u % 16, u / 16, tsh);
  } else if (id < 3328) {
    int idx = (id - 3200) * 256 + t;   // [0, 32768)
    int h = idx >> 12, r = (idx >> 6) & 63, c = idx & 63;
    bf16 z = __float2bfloat16(0.f);
    rkh[((size_t)h * 2112 + r) * 64 + c] = z;
    rkl[((size_t)h * 2112 + r) * 64 + c] = z;
    vtb[((size_t)h * 64 + r) * 2112 + c] = z;
  } else if (id < 3330) {
    int u = (id - 3328) * 256 + t;     // [0, 512)
    if (u < 512) {
      int h = u >> 6, e = u & 63;
      float kv = memkv[(size_t)h * DHEAD + e];
      bf16 h1 = __float2bfloat16(kv);
      float r1 = kv - __bfloat162float(h1);
      bf16 m1 = __float2bfloat16(r1);
      ckh[((size_t)h * 256) * 64 + e] = h1;
      ckm[((size_t)h * 256) * 64 + e] = m1;
      ckl[((size_t)h * 256) * 64 + e] = __float2bfloat16(r1 - __bfloat162float(m1));
      bf16 z = __float2bfloat16(0.f);
      ckh[((size_t)h * 256 + 255) * 64 + e] = z;
      ckm[((size_t)h * 256 + 255) * 64 + e] = z;
      ckl[((size_t)h * 256 + 255) * 64 + e] = z;
      float vv = memkv[(size_t)(NHEAD + h) * DHEAD + e];
      cvtb[((size_t)h * 64 + e) * 256 + 0] = __float2bfloat16(vv);
      cvtb[((size_t)h * 64 + e) * 256 + 255] = z;
    }
  } else {
    const int row = id - 3330;
    const float* xr = x + (size_t)row * DMODEL;
    float s = 0.f;
    for (int c = t; c < DMODEL; c += 256) { float v = xr[c]; s += v * v; }
    for (int o = 32; o > 0; o >>= 1) s += __shfl_down(s, o);
    if ((t & 63) == 0) wsum[t >> 6] = s;
    __syncthreads();
    if (t == 0) {
      float tot = wsum[0] + wsum[1] + wsum[2] + wsum[3];
      scale_s = rsqrtf(tot * (1.f / DMODEL) + 1e-6f);
    }
    __syncthreads();
    float sc = scale_s;
    for (int c = t; c < DMODEL; c += 256) {
      float v = xr[c] * sc * g[c];
      bf16 h1 = __float2bfloat16(v);
      hbh[(size_t)row * DMODEL + c] = h1;
      hbl[(size_t)row * DMODEL + c] = __float2bfloat16(v - __bfloat162float(h1));
    }
  }
}

// ================= k_post: rope + v-transpose + compression windows =================
__global__ __launch_bounds__(256) void k_post(
    const bf16* __restrict__ qbh, const bf16* __restrict__ qbm,
    const bf16* __restrict__ qbl, const float* __restrict__ kf,
    const bf16* __restrict__ vbh,
    const float* __restrict__ kpos, const float* __restrict__ vpos,
    bf16* __restrict__ rqh, bf16* __restrict__ rql,
    bf16* __restrict__ rkh, bf16* __restrict__ rkl, float* __restrict__ rkf,
    bf16* __restrict__ vtb,
    bf16* __restrict__ kwh, bf16* __restrict__ kwl, bf16* __restrict__ vwh) {
  __shared__ bf16 tile[64][65];
  const int id = blockIdx.x;
  const int t = threadIdx.x;

  if (id < 2048) {
    int idx = id * 256 + t;
    int i = idx & 31;
    int n = (idx >> 5) & (NTOK - 1);
    int h = idx >> 16;
    float ex = (float)(2 * i) * (1.f / 64.f);
    float inv = exp2f(-ex * 13.287712379549449f);
    float ang = (float)n * inv;
    float sn, cs;
    sincosf(ang, &sn, &cs);
    size_t base = ((size_t)h * NTOK + n) * DHEAD + 2 * i;
    float q1 = __bfloat162float(qbh[base]) + __bfloat162float(qbm[base]) + __bfloat162float(qbl[base]);
    float q2 = __bfloat162float(qbh[base + 1]) + __bfloat162float(qbm[base + 1]) + __bfloat162float(qbl[base + 1]);
    float r1 = q1 * cs - q2 * sn, r2 = q1 * sn + q2 * cs;
    bf16 h1 = __float2bfloat16(r1);
    rqh[base] = h1; rql[base] = __float2bfloat16(r1 - __bfloat162float(h1));
    h1 = __float2bfloat16(r2);
    rqh[base + 1] = h1; rql[base + 1] = __float2bfloat16(r2 - __bfloat162float(h1));
    float k1 = kf[base], k2 = kf[base + 1];
    float s1 = k1 * cs - k2 * sn, s2 = k1 * sn + k2 * cs;
    rkf[base] = s1;
    rkf[base + 1] = s2;
    size_t kb = ((size_t)h * 2112 + 64 + n) * DHEAD + 2 * i;
    h1 = __float2bfloat16(s1);
    rkh[kb] = h1; rkl[kb] = __float2bfloat16(s1 - __bfloat162float(h1));
    h1 = __float2bfloat16(s2);
    rkh[kb + 1] = h1; rkl[kb + 1] = __float2bfloat16(s2 - __bfloat162float(h1));
  } else if (id < 2304) {
    int u = id - 2048;
    int h = u >> 5, n0 = (u & 31) << 6;
    int tx = t & 63, ty = t >> 6;
    for (int r = ty; r < 64; r += 4)
      tile[r][tx] = vbh[((size_t)h * NTOK + n0 + r) * DHEAD + tx];
    __syncthreads();
    for (int r = ty; r < 64; r += 4)
      vtb[((size_t)h * 64 + r) * 2112 + 64 + n0 + tx] = tile[tx][r];
  } else {
    int idx = (id - 2304) * 256 + t;   // [0, 2080768)
    int d = idx & 63;
    int c = (idx >> 6) & 15;
    int j = (idx >> 10) % NWIN;
    int h = idx / (NWIN << 10);
    int srcpos = (j << 3) + c;
    size_t src = ((size_t)h * NTOK + srcpos) * DHEAD + d;
    size_t pp = ((size_t)h * 16 + c) * DHEAD + d;
    float kv = kf[src] + kpos[pp];
    bf16 h1 = __float2bfloat16(kv);
    kwh[idx] = h1;
    kwl[idx] = __float2bfloat16(kv - __bfloat162float(h1));
    vwh[idx] = __float2bfloat16(__bfloat162float(vbh[src]) + vpos[pp]);
  }
}

// ---------------- compression attention (MFMA, 32 queries/block) ----------------
__global__ __launch_bounds__(256) void k_comp_attn(
    const bf16* __restrict__ qbh, const bf16* __restrict__ qbm, const bf16* __restrict__ qbl,
    const bf16* __restrict__ ckh, const bf16* __restrict__ ckm, const bf16* __restrict__ ckl,
    const bf16* __restrict__ cvtb,
    float* __restrict__ c_out, int* __restrict__ sel) {
  const int h = blockIdx.y;
  const int i0 = blockIdx.x << 5;
  const int t = threadIdx.x;
  const int w = t >> 6, lane = t & 63;
  const int lr = lane & 15, kg = (lane >> 4) << 3;
  const int crow = (lane >> 4) << 2;

  __shared__ float p[32][260];

  bf16x8 aH[2][2], aM[2][2], aL[2][2];
#pragma unroll
  for (int mi = 0; mi < 2; ++mi) {
    size_t qo = ((size_t)h * NTOK + i0 + mi * 16 + lr) * DHEAD + kg;
#pragma unroll
    for (int ks = 0; ks < 2; ++ks) {
      aH[mi][ks] = *reinterpret_cast<const bf16x8*>(qbh + qo + ks * 32);
      aM[mi][ks] = *reinterpret_cast<const bf16x8*>(qbm + qo + ks * 32);
      aL[mi][ks] = *reinterpret_cast<const bf16x8*>(qbl + qo + ks * 32);
    }
  }
  f32x4 acc[2][4];
#pragma unroll
  for (int a = 0; a < 2; ++a)
#pragma unroll
    for (int b = 0; b < 4; ++b) acc[a][b] = (f32x4){0.f, 0.f, 0.f, 0.f};
#pragma unroll
  for (int ni = 0; ni < 4; ++ni) {
    int col = (w << 6) + (ni << 4) + lr;
    size_t ko = ((size_t)h * 256 + col) * 64 + kg;
#pragma unroll
    for (int ks = 0; ks < 2; ++ks) {
      bf16x8 bH = *reinterpret_cast<const bf16x8*>(ckh + ko + ks * 32);
      bf16x8 bM = *reinterpret_cast<const bf16x8*>(ckm + ko + ks * 32);
      bf16x8 bL = *reinterpret_cast<const bf16x8*>(ckl + ko + ks * 32);
#pragma unroll
      for (int mi = 0; mi < 2; ++mi) {
        acc[mi][ni] = __builtin_amdgcn_mfma_f32_16x16x32_bf16(aH[mi][ks], bH, acc[mi][ni], 0, 0, 0);
        acc[mi][ni] = __builtin_amdgcn_mfma_f32_16x16x32_bf16(aH[mi][ks], bM, acc[mi][ni], 0, 0, 0);
        acc[mi][ni] = __builtin_amdgcn_mfma_f32_16x16x32_bf16(aM[mi][ks], bH, acc[mi][ni], 0, 0, 0);
        acc[mi][ni] = __builtin_amdgcn_mfma_f32_16x16x32_bf16(aH[mi][ks], bL, acc[mi][ni], 0, 0, 0);
        acc[mi][ni] = __builtin_amdgcn_mfma_f32_16x16x32_bf16(aL[mi][ks], bH, acc[mi][ni], 0, 0, 0);
        acc[mi][ni] = __builtin_amdgcn_mfma_f32_16x16x32_bf16(aM[mi][ks], bM, acc[mi][ni], 0, 0, 0);
      }
    }
  }
#pragma unroll
  for (int mi = 0; mi < 2; ++mi)
#pragma unroll
    for (int ni = 0; ni < 4; ++ni) {
      int col = (w << 6) + (ni << 4) + lr;
      int wend = (col == 0) ? -1 : ((col - 1) << 3) + 15;
#pragma unroll
      for (int r = 0; r < 4; ++r) {
        int qi = mi * 16 + crow + r;
        bool ok = (col < 255) && (wend < i0 + qi);
        p[qi][col] = ok ? acc[mi][ni][r] * 0.125f : NEGV;
      }
    }
  __syncthreads();

  const int qi = t >> 3, s = t & 7;
  float ev[32];
  float mx = -3.0e38f;
#pragma unroll
  for (int u = 0; u < 32; ++u) { ev[u] = p[qi][s + (u << 3)]; mx = fmaxf(mx, ev[u]); }
  mx = fmaxf(mx, __shfl_xor(mx, 1));
  mx = fmaxf(mx, __shfl_xor(mx, 2));
  mx = fmaxf(mx, __shfl_xor(mx, 4));
  float sum = 0.f;
#pragma unroll
  for (int u = 0; u < 32; ++u) { float e = __expf(ev[u] - mx); ev[u] = e; sum += e; }
  sum += __shfl_xor(sum, 1); sum += __shfl_xor(sum, 2); sum += __shfl_xor(sum, 4);
  float invs = 1.f / sum;
#pragma unroll
  for (int u = 0; u < 32; ++u) p[qi][s + (u << 3)] = ev[u] * invs;

  int qblk = (i0 + qi) >> 4;
  float vals[16];
#pragma unroll
  for (int u = 0; u < 16; ++u) {
    int f = (s << 4) + u;
    float v;
    if (f >= qblk || f == 127) v = NEGV;
    else v = (p[qi][2 * f + 1] + p[qi][2 * f + 2]) * 0.5f;
    vals[u] = v;
  }
  int base = ((h << 11) | (i0 + qi)) * 5;
  for (int kk = 0; kk < 4; ++kk) {
    float bv = -3.0e38f; int bi = 0;
#pragma unroll
    for (int u = 0; u < 16; ++u) {
      if (vals[u] > bv) { bv = vals[u]; bi = (s << 4) + u; }
    }
#pragma unroll
    for (int o = 1; o < 8; o <<= 1) {
      float ov = __shfl_xor(bv, o);
      int oi = __shfl_xor(bi, o);
      if (ov > bv || (ov == bv && oi < bi)) { bv = ov; bi = oi; }
    }
    if (s == 0) sel[base + kk] = (bv > -5.0e8f) ? bi : -1;
    if ((bi >> 4) == s) vals[bi & 15] = -3.0e38f;
  }
  if (s == 0) sel[base + 4] = (i0 + qi) >> 4;
  __syncthreads();

  const int wm = w >> 1, wn = w & 1;
  const int arow = wm * 16 + lr;
  f32x4 pacc[2];
#pragma unroll
  for (int b = 0; b < 2; ++b) pacc[b] = (f32x4){0.f, 0.f, 0.f, 0.f};
#pragma unroll
  for (int ks = 0; ks < 8; ++ks) {
    int k0 = ks * 32 + kg;
    float4 x0 = *reinterpret_cast<const float4*>(&p[arow][k0]);
    float4 x1 = *reinterpret_cast<const float4*>(&p[arow][k0 + 4]);
    float xv[8] = {x0.x, x0.y, x0.z, x0.w, x1.x, x1.y, x1.z, x1.w};
    bf16x8 ph, pl;
#pragma unroll
    for (int e = 0; e < 8; ++e) {
      __bf16 hh = (__bf16)xv[e];
      ph[e] = hh;
      pl[e] = (__bf16)(xv[e] - (float)hh);
    }
#pragma unroll
    for (int ni = 0; ni < 2; ++ni) {
      int d = (wn << 5) + (ni << 4) + lr;
      bf16x8 bv = *reinterpret_cast<const bf16x8*>(cvtb + ((size_t)h * 64 + d) * 256 + k0);
      pacc[ni] = __builtin_amdgcn_mfma_f32_16x16x32_bf16(ph, bv, pacc[ni], 0, 0, 0);
      pacc[ni] = __builtin_amdgcn_mfma_f32_16x16x32_bf16(pl, bv, pacc[ni], 0, 0, 0);
    }
  }
#pragma unroll
  for (int ni = 0; ni < 2; ++ni) {
    int d = (wn << 5) + (ni << 4) + lr;
#pragma unroll
    for (int r = 0; r < 4; ++r) {
      int q2 = wm * 16 + crow + r;
      c_out[((size_t)h * NTOK + i0 + q2) * DHEAD + d] = pacc[ni][r];
    }
  }
}

// ---------------- fine attention: 1 wave per query, fp32 K via float4 ----------------
__global__ __launch_bounds__(256) void k_fine_attn(
    const bf16* __restrict__ rqh, const bf16* __restrict__ rql,
    const float* __restrict__ rkf, const bf16* __restrict__ vbh,
    const int* __restrict__ sel, float* __restrict__ f_out) {
  const int h = blockIdx.y;
  const int wid = threadIdx.x >> 6;
  const int lane = threadIdx.x & 63;
  const int i = (blockIdx.x << 2) | wid;

  __shared__ float qs[4][64];
  __shared__ float pb[4][80];
  __shared__ int selb[4][5];

  size_t qoff = ((size_t)h * NTOK + i) * DHEAD + lane;
  qs[wid][lane] = __bfloat162float(rqh[qoff]) + __bfloat162float(rql[qoff]);
  if (lane < 5) selb[wid][lane] = sel[((h << 11) | i) * 5 + lane];
  __syncthreads();

  float sim0 = NEGV, sim1 = NEGV;
  {
    int kb = selb[wid][lane >> 4];
    int pos = (kb << 4) + (lane & 15);
    if (kb >= 0 && pos <= i) {
      const float* kp = rkf + ((size_t)h * NTOK + pos) * DHEAD;
      float d = 0.f;
#pragma unroll
      for (int e4 = 0; e4 < 16; ++e4) {
        float4 kv = *reinterpret_cast<const float4*>(kp + e4 * 4);
        d = fmaf(qs[wid][e4 * 4 + 0], kv.x, d);
        d = fmaf(qs[wid][e4 * 4 + 1], kv.y, d);
        d = fmaf(qs[wid][e4 * 4 + 2], kv.z, d);
        d = fmaf(qs[wid][e4 * 4 + 3], kv.w, d);
      }
      sim0 = d * 0.125f;
    }
  }
  if (lane < 16) {
    int kb = selb[wid][4];
    int pos = (kb << 4) + lane;
    if (pos <= i) {
      const float* kp = rkf + ((size_t)h * NTOK + pos) * DHEAD;
      float d = 0.f;
#pragma unroll
      for (int e4 = 0; e4 < 16; ++e4) {
        float4 kv = *reinterpret_cast<const float4*>(kp + e4 * 4);
        d = fmaf(qs[wid][e4 * 4 + 0], kv.x, d);
        d = fmaf(qs[wid][e4 * 4 + 1], kv.y, d);
        d = fmaf(qs[wid][e4 * 4 + 2], kv.z, d);
        d = fmaf(qs[wid][e4 * 4 + 3], kv.w, d);
      }
      sim1 = d * 0.125f;
    }
  }

  float mx = fmaxf(sim0, sim1);
#pragma unroll
  for (int o = 32; o > 0; o >>= 1) mx = fmaxf(mx, __shfl_xor(mx, o));
  float e0 = __expf(sim0 - mx);
  float e1 = __expf(sim1 - mx);
  float sum = e0 + e1;
#pragma unroll
  for (int o = 32; o > 0; o >>= 1) sum += __shfl_xor(sum, o);
  float invs = 1.f / sum;
  pb[wid][lane] = e0 * invs;
  if (lane < 16) pb[wid][64 + lane] = e1 * invs;

  float acc = 0.f;
#pragma unroll
  for (int b = 0; b < 5; ++b) {
    int kb = selb[wid][b];
    if (kb < 0) continue;
    const bf16* vr = vbh + ((size_t)h * NTOK + ((size_t)kb << 4)) * DHEAD + lane;
#pragma unroll
    for (int u = 0; u < 16; ++u)
      acc = fmaf(pb[wid][b * 16 + u], __bfloat162float(vr[(size_t)u * DHEAD]), acc);
  }
  f_out[((size_t)h * NTOK + i) * DHEAD + lane] = acc;
}

// ---------------- sliding-window attention (MFMA, 64 queries/block) ----------------
__global__ __launch_bounds__(256) void k_slide_attn(
    const bf16* __restrict__ rqh, const bf16* __restrict__ rql,
    const bf16* __restrict__ rkh, const bf16* __restrict__ rkl,
    const bf16* __restrict__ vtb, float* __restrict__ s_out) {
  const int h = blockIdx.y, nb = blockIdx.x;
  const int t = threadIdx.x, w = t >> 6, lane = t & 63;
  const int lr = lane & 15, kg = (lane >> 4) << 3;
  const int crow = (lane >> 4) << 2;
  const int wm = w >> 1, wn = w & 1;
  __shared__ float p[64][132];

  bf16x8 aH[2][2], aL[2][2];
#pragma unroll
  for (int mi = 0; mi < 2; ++mi) {
    size_t qo = ((size_t)h * NTOK + nb * 64 + wm * 32 + mi * 16 + lr) * DHEAD + kg;
#pragma unroll
    for (int ks = 0; ks < 2; ++ks) {
      aH[mi][ks] = *reinterpret_cast<const bf16x8*>(rqh + qo + ks * 32);
      aL[mi][ks] = *reinterpret_cast<const bf16x8*>(rql + qo + ks * 32);
    }
  }
  f32x4 acc[2][4];
#pragma unroll
  for (int a = 0; a < 2; ++a)
#pragma unroll
    for (int b = 0; b < 4; ++b) acc[a][b] = (f32x4){0.f, 0.f, 0.f, 0.f};
#pragma unroll
  for (int ni = 0; ni < 4; ++ni) {
    int col = (wn << 6) + (ni << 4) + lr;
    size_t ko = ((size_t)h * 2112 + nb * 64 + col) * 64 + kg;
#pragma unroll
    for (int ks = 0; ks < 2; ++ks) {
      bf16x8 bH = *reinterpret_cast<const bf16x8*>(rkh + ko + ks * 32);
      bf16x8 bL = *reinterpret_cast<const bf16x8*>(rkl + ko + ks * 32);
#pragma unroll
      for (int mi = 0; mi < 2; ++mi) {
        acc[mi][ni] = __builtin_amdgcn_mfma_f32_16x16x32_bf16(aH[mi][ks], bH, acc[mi][ni], 0, 0, 0);
        acc[mi][ni] = __builtin_amdgcn_mfma_f32_16x16x32_bf16(aL[mi][ks], bH, acc[mi][ni], 0, 0, 0);
        acc[mi][ni] = __builtin_amdgcn_mfma_f32_16x16x32_bf16(aH[mi][ks], bL, acc[mi][ni], 0, 0, 0);
      }
    }
  }
#pragma unroll
  for (int mi = 0; mi < 2; ++mi)
#pragma unroll
    for (int ni = 0; ni < 4; ++ni) {
      int col = (wn << 6) + (ni << 4) + lr;
#pragma unroll
      for (int r = 0; r < 4; ++r) {
        int qi2 = wm * 32 + mi * 16 + crow + r;
        bool ok = (col >= qi2 + 1) && (col <= qi2 + 64) && (nb > 0 || col >= 64);
        p[qi2][col] = ok ? acc[mi][ni][r] * 0.125f : NEGV;
      }
    }
  __syncthreads();

  const int qi = t >> 2, s = t & 3;
  float ev[32];
  float mx = -3.0e38f;
#pragma unroll
  for (int u = 0; u < 32; ++u) { ev[u] = p[qi][s + (u << 2)]; mx = fmaxf(mx, ev[u]); }
  mx = fmaxf(mx, __shfl_xor(mx, 1));
  mx = fmaxf(mx, __shfl_xor(mx, 2));
  float sum = 0.f;
#pragma unroll
  for (int u = 0; u < 32; ++u) { float e = __expf(ev[u] - mx); ev[u] = e; sum += e; }
  sum += __shfl_xor(sum, 1); sum += __shfl_xor(sum, 2);
  float invs = 1.f / sum;
#pragma unroll
  for (int u = 0; u < 32; ++u) p[qi][s + (u << 2)] = ev[u] * invs;
  __syncthreads();

  f32x4 pacc[2][2];
#pragma unroll
  for (int a = 0; a < 2; ++a)
#pragma unroll
    for (int b = 0; b < 2; ++b) pacc[a][b] = (f32x4){0.f, 0.f, 0.f, 0.f};
#pragma unroll
  for (int ks = 0; ks < 4; ++ks) {
    int k0 = ks * 32 + kg;
    bf16x8 ph[2], pl[2];
#pragma unroll
    for (int mi = 0; mi < 2; ++mi) {
      int arow = wm * 32 + mi * 16 + lr;
      float4 x0 = *reinterpret_cast<const float4*>(&p[arow][k0]);
      float4 x1 = *reinterpret_cast<const float4*>(&p[arow][k0 + 4]);
      float xv[8] = {x0.x, x0.y, x0.z, x0.w, x1.x, x1.y, x1.z, x1.w};
#pragma unroll
      for (int e = 0; e < 8; ++e) {
        __bf16 hh = (__bf16)xv[e];
        ph[mi][e] = hh;
        pl[mi][e] = (__bf16)(xv[e] - (float)hh);
      }
    }
#pragma unroll
    for (int ni = 0; ni < 2; ++ni) {
      int d = (wn << 5) + (ni << 4) + lr;
      bf16x8 bv = *reinterpret_cast<const bf16x8*>(vtb + ((size_t)h * 64 + d) * 2112 + nb * 64 + k0);
#pragma unroll
      for (int mi = 0; mi < 2; ++mi) {
        pacc[mi][ni] = __builtin_amdgcn_mfma_f32_16x16x32_bf16(ph[mi], bv, pacc[mi][ni], 0, 0, 0);
        pacc[mi][ni] = __builtin_amdgcn_mfma_f32_16x16x32_bf16(pl[mi], bv, pacc[mi][ni], 0, 0, 0);
      }
    }
  }
#pragma unroll
  for (int mi = 0; mi < 2; ++mi)
#pragma unroll
    for (int ni = 0; ni < 2; ++ni) {
      int d = (wn << 5) + (ni << 4) + lr;
#pragma unroll
      for (int r = 0; r < 4; ++r) {
        int qi2 = wm * 32 + mi * 16 + crow + r;
        s_out[((size_t)h * NTOK + nb * 64 + qi2) * DHEAD + d] = pacc[mi][ni][r];
      }
    }
}

// ---------------- fused strat + combine: one block per token ----------------
__global__ __launch_bounds__(256) void k_combine2(
    const bf16* __restrict__ Ah, const bf16* __restrict__ Al,
    const float* __restrict__ W, const float* __restrict__ bias,
    const float* __restrict__ c_out, const float* __restrict__ f_out,
    const float* __restrict__ s_out, bf16* __restrict__ comb) {
  const int i = blockIdx.x;
  const int t = threadIdx.x;
  __shared__ float hs[DMODEL];
  __shared__ float st[24];
  size_t ro = (size_t)i * DMODEL;
#pragma unroll
  for (int u = 0; u < 2; ++u) {
    int c = t + u * 256;
    hs[c] = __bfloat162float(Ah[ro + c]) + __bfloat162float(Al[ro + c]);
  }
  __syncthreads();
  if (t < 192) {
    int c = t >> 3, s = t & 7;
    float acc = 0.f;
    for (int u = 0; u < 64; ++u) {
      int e = s * 64 + u;
      acc = fmaf(hs[e], W[(size_t)e * 24 + c], acc);
    }
    acc += __shfl_xor(acc, 1);
    acc += __shfl_xor(acc, 2);
    acc += __shfl_xor(acc, 4);
    if (s == 0) st[c] = 1.f / (1.f + expf(-(acc + bias[c])));
  }
  __syncthreads();
#pragma unroll
  for (int u = 0; u < 2; ++u) {
    int c = t + u * 256;
    int h = c >> 6, d = c & 63;
    size_t a = ((size_t)h * NTOK + i) * DHEAD + d;
    comb[ro + c] = __float2bfloat16(st[h * 3] * c_out[a] + st[h * 3 + 1] * f_out[a]
                                    + st[h * 3 + 2] * s_out[a]);
  }
}

extern "C" void kernel_launch(void* const* d_in, const int* in_sizes, int n_in,
                              void* d_out, int out_size, void* d_ws, size_t ws_size,
                              hipStream_t stream) {
  const float* x      = (const float*)d_in[0];
  const float* g_norm = (const float*)d_in[1];
  const float* w_qkv  = (const float*)d_in[2];
  const float* k_pos  = (const float*)d_in[3];
  const float* v_pos  = (const float*)d_in[4];
  const float* mem_kv = (const float*)d_in[5];
  const float* k_w1   = (const float*)d_in[6];
  const float* k_b1   = (const float*)d_in[7];
  const float* k_w2   = (const float*)d_in[8];
  const float* k_b2   = (const float*)d_in[9];
  const float* v_w1   = (const float*)d_in[10];
  const float* v_b1   = (const float*)d_in[11];
  const float* v_w2   = (const float*)d_in[12];
  const float* v_b2   = (const float*)d_in[13];
  const float* w_comb = (const float*)d_in[14];
  const float* b_comb = (const float*)d_in[15];
  const float* w_out  = (const float*)d_in[16];
  float* out = (float*)d_out;
  char* wsb = (char*)d_ws;

  bf16* WQKV_H = (bf16*)(wsb + B_WQKV_H);
  bf16* WQKV_L = (bf16*)(wsb + B_WQKV_L);
  bf16* KW1_H  = (bf16*)(wsb + B_KW1_H);
  bf16* KW1_L  = (bf16*)(wsb + B_KW1_L);
  bf16* KW2_H  = (bf16*)(wsb + B_KW2_H);
  bf16* KW2_L  = (bf16*)(wsb + B_KW2_L);
  bf16* VW1_H  = (bf16*)(wsb + B_VW1_H);
  bf16* VW2_H  = (bf16*)(wsb + B_VW2_H);
  bf16* WOUT_H = (bf16*)(wsb + B_WOUT_H);
  bf16* HB_H   = (bf16*)(wsb + B_HB_H);
  bf16* HB_L   = (bf16*)(wsb + B_HB_L);
  bf16* QBH    = (bf16*)(wsb + B_QBH);
  bf16* QBM    = (bf16*)(wsb + B_QBM);
  bf16* QBL    = (bf16*)(wsb + B_QBL);
  float* KF    = (float*)(wsb + B_KF);
  bf16* VBH    = (bf16*)(wsb + B_VBH);
  bf16* RQH    = (bf16*)(wsb + B_RQH);
  bf16* RQL    = (bf16*)(wsb + B_RQL);
  bf16* RKH    = (bf16*)(wsb + B_RKH);
  bf16* RKL    = (bf16*)(wsb + B_RKL);
  float* RKF   = (float*)(wsb + B_RKF);
  bf16* VTB    = (bf16*)(wsb + B_VTB);
  bf16* CKT_H  = (bf16*)(wsb + B_CKT_H);
  bf16* CKT_M  = (bf16*)(wsb + B_CKT_M);
  bf16* CKT_L  = (bf16*)(wsb + B_CKT_L);
  bf16* CVT    = (bf16*)(wsb + B_CVT);
  int*   SEL   = (int*)(wsb + B_SEL);
  float* COUT  = (float*)(wsb + B_COUT);
  float* FOUT  = (float*)(wsb + B_FOUT);
  float* SOUT  = (float*)(wsb + B_SOUT);
  bf16* KW_H   = (bf16*)(wsb + B_KW_H);
  bf16* KW_L   = (bf16*)(wsb + B_KW_L);
  bf16* VW_H   = (bf16*)(wsb + B_VW_H);
  bf16* HID_H  = (bf16*)(wsb + B_HID_H);
  bf16* HID_L  = (bf16*)(wsb + B_HID_L);
  bf16* HIDV   = (bf16*)(wsb + B_HIDV);
  bf16* COMBB  = (bf16*)(wsb + B_COMBB);

  // 1. setup: weight splits + pads + mem fill + rmsnorm
  k_setup<<<5378, 256, 0, stream>>>(x, g_norm, w_qkv, k_w1, k_w2, v_w1, v_w2, w_out, mem_kv,
                                    WQKV_H, WQKV_L, KW1_H, KW1_L, KW2_H, KW2_L,
                                    VW1_H, VW2_H, WOUT_H, HB_H, HB_L,
                                    RKH, RKL, VTB, CKT_H, CKT_M, CKT_L, CVT);
  // 2. qkv (compensated, 64x64/wave) with fused split/scatter
  k_qkv<<<dim3(12, 16), 256, 0, stream>>>(HB_H, HB_L, WQKV_H, WQKV_L, KF, QBH, QBM, QBL, VBH);
  // 3. post: rope + v-transpose + windows
  k_post<<<10432, 256, 0, stream>>>(QBH, QBM, QBL, KF, VBH, k_pos, v_pos,
                                    RQH, RQL, RKH, RKL, RKF, VTB, KW_H, KW_L, VW_H);
  // 4. merged MLP1 (64x64/wave; k compensated + v plain); HIDV overlays dead KF
  k_mlp1<<<dim3(8, 16, 2), 256, 0, stream>>>(KW_H, KW_L, KW1_H, KW1_L, k_b1,
                                             VW_H, VW1_H, v_b1, HID_H, HID_L, HIDV);
  // 5. merged MLP2 -> ckT hi/mid/lo + cvT
  k_mlp2<<<dim3(1, 32, 2), 256, 0, stream>>>(HID_H, HID_L, KW2_H, KW2_L, k_b2,
                                             HIDV, VW2_H, v_b2, CKT_H, CKT_M, CKT_L, CVT);
  // 6-8. attention branches
  k_comp_attn<<<dim3(64, 8), 256, 0, stream>>>(QBH, QBM, QBL, CKT_H, CKT_M, CKT_L, CVT, COUT, SEL);
  k_fine_attn<<<dim3(512, 8), 256, 0, stream>>>(RQH, RQL, RKF, VBH, SEL, FOUT);
  k_slide_attn<<<dim3(32, 8), 256, 0, stream>>>(RQH, RQL, RKH, RKL, VTB, SOUT);
  // 9. fused strat + combine
  k_combine2<<<NTOK, 256, 0, stream>>>(HB_H, HB_L, w_comb, b_comb, COUT, FOUT, SOUT, COMBB);
  // 10. output projection (32-tile core)
  k_cgemm<0, 0><<<dim3(8, 32), 256, 0, stream>>>(
      COMBB, nullptr, WOUT_H, nullptr, nullptr, out, NTOK, DMODEL, DMODEL);
}

// Round 10
// 277.879 us; speedup vs baseline: 4.6943x; 1.0487x over previous
//
#include <hip/hip_runtime.h>
#include <hip/hip_bf16.h>
#include <cstddef>

#define NTOK 2048
#define DMODEL 512
#define NHEAD 8
#define DHEAD 64
#define NWIN 254          // (2048-16)/8 + 1
#define CDIM 1024         // CB*DH
#define NEGV -1000000000.0f

typedef __attribute__((ext_vector_type(8))) __bf16 bf16x8;
typedef __attribute__((ext_vector_type(4))) float f32x4;
typedef __hip_bfloat16 bf16;

// ---------------- workspace layout (byte offsets) ----------------
static const size_t B_WQKV_H = 0;          // 1536*512*2
static const size_t B_WQKV_L = 1572864;
static const size_t B_KW1_H  = 3145728;    // 1024*1024*2
static const size_t B_KW1_L  = 5242880;
static const size_t B_KW2_H  = 7340032;    // 64*1024*2
static const size_t B_KW2_L  = 7471104;
static const size_t B_VW1_H  = 7602176;
static const size_t B_VW2_H  = 9699328;
static const size_t B_WOUT_H = 9830400;    // 512*512*2
static const size_t B_HB_H   = 10354688;   // 2048*512*2
static const size_t B_HB_L   = 12451840;
static const size_t B_QBH    = 14548992;   // 8*2048*64*2 (non-roped q, hi)
static const size_t B_QBL    = 16646144;   // (lo, 3rd term)
static const size_t B_KF     = 18743296;   // 8*2048*64*4 (k fp32, pre-rope; dead after k_post -> HIDV)
static const size_t B_VBH    = 22937600;   // 8*2048*64*2
static const size_t B_RQH    = 25034752;   // roped q hi/lo
static const size_t B_RQL    = 27131904;
static const size_t B_RKH    = 29229056;   // 8*2112*64*2 (roped k, 64 zero-pad rows front)
static const size_t B_RKL    = 31391744;
static const size_t B_VTB    = 33554432;   // 8*64*2112*2 (v^T, 64 zero-pad cols front)
static const size_t B_CKT_H  = 35717120;   // 8*256*64*2 (compressed k rows, j=0 mem)
static const size_t B_CKT_L  = 35979264;
static const size_t B_CVT    = 36241408;   // 8*64*256*2 (compressed v transposed)
static const size_t B_SEL    = 36700160;   // 8*2048*5*4
static const size_t B_COUT   = 37027840;   // 4194304 (overlays KW_H)
static const size_t B_FOUT   = 41222144;   // 4194304 (overlays KW_L)
static const size_t B_SOUT   = 45416448;   // 4194304 (overlays VW_H)
static const size_t B_KW_H   = B_COUT;     // 2032*1024*2 = 4161536
static const size_t B_KW_L   = B_FOUT;
static const size_t B_VW_H   = B_SOUT;
static const size_t B_HID_H  = 49610752;   // 4161536 (k hidden hi)
static const size_t B_HID_L  = 53772288;   // 4161536 (k hidden lo)
static const size_t B_QBM    = 57933824;   // 8*2048*64*2 (q mid term)
static const size_t B_CKT_M  = 60030976;   // 8*256*64*2
static const size_t B_RKF    = 60293120;   // 8*2048*64*4 (roped k fp32); end 64487424
static const size_t B_HIDV   = B_KF;       // v hidden hi (4161536 <= 4194304, KF dead)
static const size_t B_COMBB  = B_HID_H;    // 2097152 (after MLPs dead)

// ================= 32x32-per-wave GEMM core (64x64 block tile) =================
template <int COMP>
__device__ __forceinline__ void gemm_tile(
    const bf16* __restrict__ Ah, const bf16* __restrict__ Al,
    const bf16* __restrict__ Wh, const bf16* __restrict__ Wl,
    int M, int K, int row_base, int col_base, int lr, int kg,
    f32x4 accs[2][2]) {
  int ar0 = row_base + lr;       if (ar0 > M - 1) ar0 = M - 1;
  int ar1 = row_base + 16 + lr;  if (ar1 > M - 1) ar1 = M - 1;
  const size_t a0o = (size_t)ar0 * K + kg;
  const size_t a1o = (size_t)ar1 * K + kg;
  const size_t b0o = (size_t)(col_base + lr) * K + kg;
  const size_t b1o = (size_t)(col_base + 16 + lr) * K + kg;
  f32x4 acc00 = {}, acc01 = {}, acc10 = {}, acc11 = {};
  for (int k0 = 0; k0 < K; k0 += 32) {
    bf16x8 ah0 = *reinterpret_cast<const bf16x8*>(Ah + a0o + k0);
    bf16x8 ah1 = *reinterpret_cast<const bf16x8*>(Ah + a1o + k0);
    bf16x8 bh0 = *reinterpret_cast<const bf16x8*>(Wh + b0o + k0);
    bf16x8 bh1 = *reinterpret_cast<const bf16x8*>(Wh + b1o + k0);
    acc00 = __builtin_amdgcn_mfma_f32_16x16x32_bf16(ah0, bh0, acc00, 0, 0, 0);
    acc01 = __builtin_amdgcn_mfma_f32_16x16x32_bf16(ah0, bh1, acc01, 0, 0, 0);
    acc10 = __builtin_amdgcn_mfma_f32_16x16x32_bf16(ah1, bh0, acc10, 0, 0, 0);
    acc11 = __builtin_amdgcn_mfma_f32_16x16x32_bf16(ah1, bh1, acc11, 0, 0, 0);
    if constexpr (COMP) {
      bf16x8 al0 = *reinterpret_cast<const bf16x8*>(Al + a0o + k0);
      bf16x8 al1 = *reinterpret_cast<const bf16x8*>(Al + a1o + k0);
      bf16x8 bl0 = *reinterpret_cast<const bf16x8*>(Wl + b0o + k0);
      bf16x8 bl1 = *reinterpret_cast<const bf16x8*>(Wl + b1o + k0);
      acc00 = __builtin_amdgcn_mfma_f32_16x16x32_bf16(ah0, bl0, acc00, 0, 0, 0);
      acc01 = __builtin_amdgcn_mfma_f32_16x16x32_bf16(ah0, bl1, acc01, 0, 0, 0);
      acc10 = __builtin_amdgcn_mfma_f32_16x16x32_bf16(ah1, bl0, acc10, 0, 0, 0);
      acc11 = __builtin_amdgcn_mfma_f32_16x16x32_bf16(ah1, bl1, acc11, 0, 0, 0);
      acc00 = __builtin_amdgcn_mfma_f32_16x16x32_bf16(al0, bh0, acc00, 0, 0, 0);
      acc01 = __builtin_amdgcn_mfma_f32_16x16x32_bf16(al0, bh1, acc01, 0, 0, 0);
      acc10 = __builtin_amdgcn_mfma_f32_16x16x32_bf16(al1, bh0, acc10, 0, 0, 0);
      acc11 = __builtin_amdgcn_mfma_f32_16x16x32_bf16(al1, bh1, acc11, 0, 0, 0);
    }
  }
  accs[0][0] = acc00; accs[0][1] = acc01; accs[1][0] = acc10; accs[1][1] = acc11;
}

// ================= 64x64-per-wave GEMM core, register double-buffered =================
// Two named fragment sets; loads of step k+32 issue as a batch BEFORE the MFMAs of
// step k, into dedicated VGPRs (no recycling -> no per-load serialization).
// Requires K % 64 == 0 (K = 512 or 1024 here).
template <int COMP>
__device__ __forceinline__ void gemm_tile64(
    const bf16* __restrict__ Ah, const bf16* __restrict__ Al,
    const bf16* __restrict__ Wh, const bf16* __restrict__ Wl,
    int M, int K, int row_base, int col_base, int lr, int kg,
    f32x4 (&acc)[4][4]) {
  size_t ao[4], bo[4];
#pragma unroll
  for (int mi = 0; mi < 4; ++mi) {
    int r = row_base + mi * 16 + lr; if (r > M - 1) r = M - 1;
    ao[mi] = (size_t)r * K + kg;
  }
#pragma unroll
  for (int ni = 0; ni < 4; ++ni)
    bo[ni] = (size_t)(col_base + ni * 16 + lr) * K + kg;

  bf16x8 a0[4], b0[4], a1[4], b1[4];
  bf16x8 c0[4], d0[4], c1[4], d1[4];   // lo parts (COMP only)

  // prologue: set0 <- k=0
#pragma unroll
  for (int i = 0; i < 4; ++i) {
    a0[i] = *reinterpret_cast<const bf16x8*>(Ah + ao[i]);
    b0[i] = *reinterpret_cast<const bf16x8*>(Wh + bo[i]);
    if constexpr (COMP) {
      c0[i] = *reinterpret_cast<const bf16x8*>(Al + ao[i]);
      d0[i] = *reinterpret_cast<const bf16x8*>(Wl + bo[i]);
    }
  }

  for (int k0 = 0; k0 < K; k0 += 64) {
    // set1 <- k0+32 (always in range: K % 64 == 0)
#pragma unroll
    for (int i = 0; i < 4; ++i) {
      a1[i] = *reinterpret_cast<const bf16x8*>(Ah + ao[i] + k0 + 32);
      b1[i] = *reinterpret_cast<const bf16x8*>(Wh + bo[i] + k0 + 32);
      if constexpr (COMP) {
        c1[i] = *reinterpret_cast<const bf16x8*>(Al + ao[i] + k0 + 32);
        d1[i] = *reinterpret_cast<const bf16x8*>(Wl + bo[i] + k0 + 32);
      }
    }
    // MFMAs on set0
#pragma unroll
    for (int mi = 0; mi < 4; ++mi)
#pragma unroll
      for (int ni = 0; ni < 4; ++ni)
        acc[mi][ni] = __builtin_amdgcn_mfma_f32_16x16x32_bf16(a0[mi], b0[ni], acc[mi][ni], 0, 0, 0);
    if constexpr (COMP) {
#pragma unroll
      for (int mi = 0; mi < 4; ++mi)
#pragma unroll
        for (int ni = 0; ni < 4; ++ni) {
          acc[mi][ni] = __builtin_amdgcn_mfma_f32_16x16x32_bf16(a0[mi], d0[ni], acc[mi][ni], 0, 0, 0);
          acc[mi][ni] = __builtin_amdgcn_mfma_f32_16x16x32_bf16(c0[mi], b0[ni], acc[mi][ni], 0, 0, 0);
        }
    }
    // set0 <- k0+64 (next iteration's first half)
    if (k0 + 64 < K) {
#pragma unroll
      for (int i = 0; i < 4; ++i) {
        a0[i] = *reinterpret_cast<const bf16x8*>(Ah + ao[i] + k0 + 64);
        b0[i] = *reinterpret_cast<const bf16x8*>(Wh + bo[i] + k0 + 64);
        if constexpr (COMP) {
          c0[i] = *reinterpret_cast<const bf16x8*>(Al + ao[i] + k0 + 64);
          d0[i] = *reinterpret_cast<const bf16x8*>(Wl + bo[i] + k0 + 64);
        }
      }
    }
    // MFMAs on set1
#pragma unroll
    for (int mi = 0; mi < 4; ++mi)
#pragma unroll
      for (int ni = 0; ni < 4; ++ni)
        acc[mi][ni] = __builtin_amdgcn_mfma_f32_16x16x32_bf16(a1[mi], b1[ni], acc[mi][ni], 0, 0, 0);
    if constexpr (COMP) {
#pragma unroll
      for (int mi = 0; mi < 4; ++mi)
#pragma unroll
        for (int ni = 0; ni < 4; ++ni) {
          acc[mi][ni] = __builtin_amdgcn_mfma_f32_16x16x32_bf16(a1[mi], d1[ni], acc[mi][ni], 0, 0, 0);
          acc[mi][ni] = __builtin_amdgcn_mfma_f32_16x16x32_bf16(c1[mi], b1[ni], acc[mi][ni], 0, 0, 0);
        }
    }
  }
}

// ---------------- generic GEMM kernel (fp32 out; used for out-proj) ----------------
template <int EPI, int COMP>
__global__ __launch_bounds__(256) void k_cgemm(
    const bf16* __restrict__ Ah, const bf16* __restrict__ Al,
    const bf16* __restrict__ Wh, const bf16* __restrict__ Wl,
    const float* __restrict__ bias, float* __restrict__ Cf,
    int M, int K, int N) {
  const int lane = threadIdx.x & 63;
  const int w = threadIdx.x >> 6;
  const int wr = w >> 1, wc = w & 1;
  const int row_base = (blockIdx.y << 6) + (wr << 5);
  const int col_base = (blockIdx.x << 6) + (wc << 5);
  const int lr = lane & 15;
  const int kg = (lane >> 4) << 3;
  const int crow = (lane >> 4) << 2;

  f32x4 accs[2][2];
  gemm_tile<COMP>(Ah, Al, Wh, Wl, M, K, row_base, col_base, lr, kg, accs);

#pragma unroll
  for (int mi = 0; mi < 2; ++mi) {
#pragma unroll
    for (int ni = 0; ni < 2; ++ni) {
      int col = col_base + (ni << 4) + lr;
      float bv = bias ? bias[col] : 0.f;
#pragma unroll
      for (int r = 0; r < 4; ++r) {
        int row = row_base + (mi << 4) + crow + r;
        if (row < M) {
          float vv = accs[mi][ni][r] + bv;
          if (EPI == 1) vv = fmaxf(vv, 0.f);
          Cf[(size_t)row * N + col] = vv;
        }
      }
    }
  }
}

// ---------------- qkv GEMM (64x64/wave pipelined, compensated, fused split/scatter) ----------------
__global__ __launch_bounds__(256, 1) void k_qkv(
    const bf16* __restrict__ Ah, const bf16* __restrict__ Al,
    const bf16* __restrict__ Wh, const bf16* __restrict__ Wl,
    float* __restrict__ KFo, bf16* __restrict__ QH, bf16* __restrict__ QM,
    bf16* __restrict__ QL, bf16* __restrict__ VB) {
  const int lane = threadIdx.x & 63;
  const int w = threadIdx.x >> 6;
  const int wr = w >> 1, wc = w & 1;
  const int row_base = (blockIdx.y << 7) + (wr << 6);
  const int col_base = (blockIdx.x << 7) + (wc << 6);
  const int lr = lane & 15;
  const int kg = (lane >> 4) << 3;
  const int crow = (lane >> 4) << 2;

  f32x4 acc[4][4];
#pragma unroll
  for (int a = 0; a < 4; ++a)
#pragma unroll
    for (int b = 0; b < 4; ++b) acc[a][b] = (f32x4){0.f, 0.f, 0.f, 0.f};
  gemm_tile64<1>(Ah, Al, Wh, Wl, NTOK, DMODEL, row_base, col_base, lr, kg, acc);

#pragma unroll
  for (int mi = 0; mi < 4; ++mi) {
#pragma unroll
    for (int ni = 0; ni < 4; ++ni) {
      int col = col_base + (ni << 4) + lr;
      int which = col >> 9, rem = col & 511;
      int hh = rem >> 6, dd = rem & 63;
#pragma unroll
      for (int r = 0; r < 4; ++r) {
        int row = row_base + (mi << 4) + crow + r;   // M=2048 exact, no guard
        float vv = acc[mi][ni][r];
        size_t o = ((size_t)hh * NTOK + row) * DHEAD + dd;
        if (which == 0) {
          bf16 h1 = __float2bfloat16(vv);
          float r1 = vv - __bfloat162float(h1);
          bf16 m1 = __float2bfloat16(r1);
          QH[o] = h1;
          QM[o] = m1;
          QL[o] = __float2bfloat16(r1 - __bfloat162float(m1));
        } else if (which == 1) {
          KFo[o] = vv;
        } else {
          VB[o] = __float2bfloat16(vv);
        }
      }
    }
  }
}

// ---------------- merged MLP1 (64x64/wave pipelined): z=0 k-path (comp), z=1 v-path ----------------
__global__ __launch_bounds__(256, 1) void k_mlp1(
    const bf16* __restrict__ KWh, const bf16* __restrict__ KWl,
    const bf16* __restrict__ W1h, const bf16* __restrict__ W1l,
    const float* __restrict__ kb1,
    const bf16* __restrict__ VWh, const bf16* __restrict__ VW1h,
    const float* __restrict__ vb1,
    bf16* __restrict__ HKh, bf16* __restrict__ HKl, bf16* __restrict__ HVh) {
  const int lane = threadIdx.x & 63;
  const int w = threadIdx.x >> 6;
  const int wr = w >> 1, wc = w & 1;
  const int row_base = (blockIdx.y << 7) + (wr << 6);
  const int col_base = (blockIdx.x << 7) + (wc << 6);
  const int lr = lane & 15;
  const int kg = (lane >> 4) << 3;
  const int crow = (lane >> 4) << 2;
  const int M = NHEAD * NWIN;  // 2032

  f32x4 acc[4][4];
#pragma unroll
  for (int a = 0; a < 4; ++a)
#pragma unroll
    for (int b = 0; b < 4; ++b) acc[a][b] = (f32x4){0.f, 0.f, 0.f, 0.f};
  if (blockIdx.z == 0)
    gemm_tile64<1>(KWh, KWl, W1h, W1l, M, CDIM, row_base, col_base, lr, kg, acc);
  else
    gemm_tile64<0>(VWh, nullptr, VW1h, nullptr, M, CDIM, row_base, col_base, lr, kg, acc);

  const float* bias = (blockIdx.z == 0) ? kb1 : vb1;
#pragma unroll
  for (int mi = 0; mi < 4; ++mi) {
#pragma unroll
    for (int ni = 0; ni < 4; ++ni) {
      int col = col_base + (ni << 4) + lr;
      float bv = bias[col];
#pragma unroll
      for (int r = 0; r < 4; ++r) {
        int row = row_base + (mi << 4) + crow + r;
        if (row < M) {
          float vv = fmaxf(acc[mi][ni][r] + bv, 0.f);
          size_t o = (size_t)row * CDIM + col;
          if (blockIdx.z == 0) {
            bf16 h1 = __float2bfloat16(vv);
            HKh[o] = h1;
            HKl[o] = __float2bfloat16(vv - __bfloat162float(h1));
          } else {
            HVh[o] = __float2bfloat16(vv);
          }
        }
      }
    }
  }
}

// ---------------- merged MLP2: z=0 k-path -> ckT hi/mid/lo, z=1 v-path -> cvT ----------------
__global__ __launch_bounds__(256) void k_mlp2(
    const bf16* __restrict__ HKh, const bf16* __restrict__ HKl,
    const bf16* __restrict__ W2h, const bf16* __restrict__ W2l,
    const float* __restrict__ kb2,
    const bf16* __restrict__ HVh, const bf16* __restrict__ VW2h,
    const float* __restrict__ vb2,
    bf16* __restrict__ ckh, bf16* __restrict__ ckm, bf16* __restrict__ ckl,
    bf16* __restrict__ cvtb) {
  const int lane = threadIdx.x & 63;
  const int w = threadIdx.x >> 6;
  const int wr = w >> 1, wc = w & 1;
  const int row_base = (blockIdx.y << 6) + (wr << 5);
  const int col_base = (wc << 5);
  const int lr = lane & 15;
  const int kg = (lane >> 4) << 3;
  const int crow = (lane >> 4) << 2;
  const int M = NHEAD * NWIN;

  f32x4 accs[2][2];
  if (blockIdx.z == 0)
    gemm_tile<1>(HKh, HKl, W2h, W2l, M, CDIM, row_base, col_base, lr, kg, accs);
  else
    gemm_tile<0>(HVh, nullptr, VW2h, nullptr, M, CDIM, row_base, col_base, lr, kg, accs);

  const float* bias = (blockIdx.z == 0) ? kb2 : vb2;
#pragma unroll
  for (int mi = 0; mi < 2; ++mi) {
#pragma unroll
    for (int ni = 0; ni < 2; ++ni) {
      int col = col_base + (ni << 4) + lr;
      float bv = bias[col];
#pragma unroll
      for (int r = 0; r < 4; ++r) {
        int row = row_base + (mi << 4) + crow + r;
        if (row < M) {
          float vv = accs[mi][ni][r] + bv;
          int hh = row / NWIN, jj = row - hh * NWIN;
          if (blockIdx.z == 0) {
            size_t o = ((size_t)hh * 256 + 1 + jj) * 64 + col;
            bf16 h1 = __float2bfloat16(vv);
            float r1 = vv - __bfloat162float(h1);
            bf16 m1 = __float2bfloat16(r1);
            ckh[o] = h1;
            ckm[o] = m1;
            ckl[o] = __float2bfloat16(r1 - __bfloat162float(m1));
          } else {
            cvtb[((size_t)hh * 64 + col) * 256 + 1 + jj] = __float2bfloat16(vv);
          }
        }
      }
    }
  }
}

// ================= k_setup: 6 weight transposes + zpad + fillmem + rmsnorm =================
__device__ __forceinline__ void wt_tile(const float* __restrict__ W,
                                        bf16* __restrict__ WTh, bf16* __restrict__ WTl,
                                        int K, int N, int bx, int by,
                                        float (*tsh)[33]) {
  const int k0 = bx << 5, n0 = by << 5;
  const int tx = threadIdx.x & 31, ty = threadIdx.x >> 5;
#pragma unroll
  for (int r = 0; r < 4; ++r)
    tsh[ty + (r << 3)][tx] = W[(size_t)(k0 + ty + (r << 3)) * N + n0 + tx];
  __syncthreads();
#pragma unroll
  for (int r = 0; r < 4; ++r) {
    float val = tsh[tx][ty + (r << 3)];
    size_t o = (size_t)(n0 + ty + (r << 3)) * K + k0 + tx;
    bf16 h1 = __float2bfloat16(val);
    WTh[o] = h1;
    if (WTl) WTl[o] = __float2bfloat16(val - __bfloat162float(h1));
  }
}

__global__ __launch_bounds__(256) void k_setup(
    const float* __restrict__ x, const float* __restrict__ g,
    const float* __restrict__ w_qkv, const float* __restrict__ k_w1,
    const float* __restrict__ k_w2, const float* __restrict__ v_w1,
    const float* __restrict__ v_w2, const float* __restrict__ w_out,
    const float* __restrict__ memkv,
    bf16* __restrict__ WQKV_H, bf16* __restrict__ WQKV_L,
    bf16* __restrict__ KW1_H, bf16* __restrict__ KW1_L,
    bf16* __restrict__ KW2_H, bf16* __restrict__ KW2_L,
    bf16* __restrict__ VW1_H, bf16* __restrict__ VW2_H, bf16* __restrict__ WOUT_H,
    bf16* __restrict__ hbh, bf16* __restrict__ hbl,
    bf16* __restrict__ rkh, bf16* __restrict__ rkl, bf16* __restrict__ vtb,
    bf16* __restrict__ ckh, bf16* __restrict__ ckm, bf16* __restrict__ ckl,
    bf16* __restrict__ cvtb) {
  __shared__ float tsh[32][33];
  __shared__ float wsum[4];
  __shared__ float scale_s;
  const int id = blockIdx.x;
  const int t = threadIdx.x;

  if (id < 768) {
    wt_tile(w_qkv, WQKV_H, WQKV_L, DMODEL, 1536, id % 16, id / 16, tsh);
  } else if (id < 1792) {
    int u = id - 768;  wt_tile(k_w1, KW1_H, KW1_L, CDIM, CDIM, u % 32, u / 32, tsh);
  } else if (id < 1856) {
    int u = id - 1792; wt_tile(k_w2, KW2_H, KW2_L, CDIM, DHEAD, u % 32, u / 32, tsh);
  } else if (id < 2880) {
    int u = id - 1856; wt_tile(v_w1, VW1_H, nullptr, CDIM, CDIM, u % 32, u / 32, tsh);
  } else if (id < 2944) {
    int u = id - 2880; wt_tile(v_w2, VW2_H, nullptr, CDIM, DHEAD, u % 32, u / 32, tsh);
  } else if (id < 3200) {
    int u = id - 2944; wt_tile(w_out, WOUT_H, nullptr, DMODEL, DMODEL, u % 16, u / 16, tsh);
  } else if (id < 3328) {
    int idx = (id - 3200) * 256 + t;   // [0, 32768)
    int h = idx >> 12, r = (idx >> 6) & 63, c = idx & 63;
    bf16 z = __float2bfloat16(0.f);
    rkh[((size_t)h * 2112 + r) * 64 + c] = z;
    rkl[((size_t)h * 2112 + r) * 64 + c] = z;
    vtb[((size_t)h * 64 + r) * 2112 + c] = z;
  } else if (id < 3330) {
    int u = (id - 3328) * 256 + t;     // [0, 512)
    if (u < 512) {
      int h = u >> 6, e = u & 63;
      float kv = memkv[(size_t)h * DHEAD + e];
      bf16 h1 = __float2bfloat16(kv);
      float r1 = kv - __bfloat162float(h1);
      bf16 m1 = __float2bfloat16(r1);
      ckh[((size_t)h * 256) * 64 + e] = h1;
      ckm[((size_t)h * 256) * 64 + e] = m1;
      ckl[((size_t)h * 256) * 64 + e] = __float2bfloat16(r1 - __bfloat162float(m1));
      bf16 z = __float2bfloat16(0.f);
      ckh[((size_t)h * 256 + 255) * 64 + e] = z;
      ckm[((size_t)h * 256 + 255) * 64 + e] = z;
      ckl[((size_t)h * 256 + 255) * 64 + e] = z;
      float vv = memkv[(size_t)(NHEAD + h) * DHEAD + e];
      cvtb[((size_t)h * 64 + e) * 256 + 0] = __float2bfloat16(vv);
      cvtb[((size_t)h * 64 + e) * 256 + 255] = z;
    }
  } else {
    const int row = id - 3330;
    const float* xr = x + (size_t)row * DMODEL;
    float s = 0.f;
    for (int c = t; c < DMODEL; c += 256) { float v = xr[c]; s += v * v; }
    for (int o = 32; o > 0; o >>= 1) s += __shfl_down(s, o);
    if ((t & 63) == 0) wsum[t >> 6] = s;
    __syncthreads();
    if (t == 0) {
      float tot = wsum[0] + wsum[1] + wsum[2] + wsum[3];
      scale_s = rsqrtf(tot * (1.f / DMODEL) + 1e-6f);
    }
    __syncthreads();
    float sc = scale_s;
    for (int c = t; c < DMODEL; c += 256) {
      float v = xr[c] * sc * g[c];
      bf16 h1 = __float2bfloat16(v);
      hbh[(size_t)row * DMODEL + c] = h1;
      hbl[(size_t)row * DMODEL + c] = __float2bfloat16(v - __bfloat162float(h1));
    }
  }
}

// ================= k_post: rope + v-transpose + compression windows =================
__global__ __launch_bounds__(256) void k_post(
    const bf16* __restrict__ qbh, const bf16* __restrict__ qbm,
    const bf16* __restrict__ qbl, const float* __restrict__ kf,
    const bf16* __restrict__ vbh,
    const float* __restrict__ kpos, const float* __restrict__ vpos,
    bf16* __restrict__ rqh, bf16* __restrict__ rql,
    bf16* __restrict__ rkh, bf16* __restrict__ rkl, float* __restrict__ rkf,
    bf16* __restrict__ vtb,
    bf16* __restrict__ kwh, bf16* __restrict__ kwl, bf16* __restrict__ vwh) {
  __shared__ bf16 tile[64][65];
  const int id = blockIdx.x;
  const int t = threadIdx.x;

  if (id < 2048) {
    int idx = id * 256 + t;
    int i = idx & 31;
    int n = (idx >> 5) & (NTOK - 1);
    int h = idx >> 16;
    float ex = (float)(2 * i) * (1.f / 64.f);
    float inv = exp2f(-ex * 13.287712379549449f);
    float ang = (float)n * inv;
    float sn, cs;
    sincosf(ang, &sn, &cs);
    size_t base = ((size_t)h * NTOK + n) * DHEAD + 2 * i;
    float q1 = __bfloat162float(qbh[base]) + __bfloat162float(qbm[base]) + __bfloat162float(qbl[base]);
    float q2 = __bfloat162float(qbh[base + 1]) + __bfloat162float(qbm[base + 1]) + __bfloat162float(qbl[base + 1]);
    float r1 = q1 * cs - q2 * sn, r2 = q1 * sn + q2 * cs;
    bf16 h1 = __float2bfloat16(r1);
    rqh[base] = h1; rql[base] = __float2bfloat16(r1 - __bfloat162float(h1));
    h1 = __float2bfloat16(r2);
    rqh[base + 1] = h1; rql[base + 1] = __float2bfloat16(r2 - __bfloat162float(h1));
    float k1 = kf[base], k2 = kf[base + 1];
    float s1 = k1 * cs - k2 * sn, s2 = k1 * sn + k2 * cs;
    rkf[base] = s1;
    rkf[base + 1] = s2;
    size_t kb = ((size_t)h * 2112 + 64 + n) * DHEAD + 2 * i;
    h1 = __float2bfloat16(s1);
    rkh[kb] = h1; rkl[kb] = __float2bfloat16(s1 - __bfloat162float(h1));
    h1 = __float2bfloat16(s2);
    rkh[kb + 1] = h1; rkl[kb + 1] = __float2bfloat16(s2 - __bfloat162float(h1));
  } else if (id < 2304) {
    int u = id - 2048;
    int h = u >> 5, n0 = (u & 31) << 6;
    int tx = t & 63, ty = t >> 6;
    for (int r = ty; r < 64; r += 4)
      tile[r][tx] = vbh[((size_t)h * NTOK + n0 + r) * DHEAD + tx];
    __syncthreads();
    for (int r = ty; r < 64; r += 4)
      vtb[((size_t)h * 64 + r) * 2112 + 64 + n0 + tx] = tile[tx][r];
  } else {
    int idx = (id - 2304) * 256 + t;   // [0, 2080768)
    int d = idx & 63;
    int c = (idx >> 6) & 15;
    int j = (idx >> 10) % NWIN;
    int h = idx / (NWIN << 10);
    int srcpos = (j << 3) + c;
    size_t src = ((size_t)h * NTOK + srcpos) * DHEAD + d;
    size_t pp = ((size_t)h * 16 + c) * DHEAD + d;
    float kv = kf[src] + kpos[pp];
    bf16 h1 = __float2bfloat16(kv);
    kwh[idx] = h1;
    kwl[idx] = __float2bfloat16(kv - __bfloat162float(h1));
    vwh[idx] = __float2bfloat16(__bfloat162float(vbh[src]) + vpos[pp]);
  }
}

// ---------------- compression attention (MFMA, 32 queries/block) ----------------
__global__ __launch_bounds__(256) void k_comp_attn(
    const bf16* __restrict__ qbh, const bf16* __restrict__ qbm, const bf16* __restrict__ qbl,
    const bf16* __restrict__ ckh, const bf16* __restrict__ ckm, const bf16* __restrict__ ckl,
    const bf16* __restrict__ cvtb,
    float* __restrict__ c_out, int* __restrict__ sel) {
  const int h = blockIdx.y;
  const int i0 = blockIdx.x << 5;
  const int t = threadIdx.x;
  const int w = t >> 6, lane = t & 63;
  const int lr = lane & 15, kg = (lane >> 4) << 3;
  const int crow = (lane >> 4) << 2;

  __shared__ float p[32][260];

  bf16x8 aH[2][2], aM[2][2], aL[2][2];
#pragma unroll
  for (int mi = 0; mi < 2; ++mi) {
    size_t qo = ((size_t)h * NTOK + i0 + mi * 16 + lr) * DHEAD + kg;
#pragma unroll
    for (int ks = 0; ks < 2; ++ks) {
      aH[mi][ks] = *reinterpret_cast<const bf16x8*>(qbh + qo + ks * 32);
      aM[mi][ks] = *reinterpret_cast<const bf16x8*>(qbm + qo + ks * 32);
      aL[mi][ks] = *reinterpret_cast<const bf16x8*>(qbl + qo + ks * 32);
    }
  }
  f32x4 acc[2][4];
#pragma unroll
  for (int a = 0; a < 2; ++a)
#pragma unroll
    for (int b = 0; b < 4; ++b) acc[a][b] = (f32x4){0.f, 0.f, 0.f, 0.f};
#pragma unroll
  for (int ni = 0; ni < 4; ++ni) {
    int col = (w << 6) + (ni << 4) + lr;
    size_t ko = ((size_t)h * 256 + col) * 64 + kg;
#pragma unroll
    for (int ks = 0; ks < 2; ++ks) {
      bf16x8 bH = *reinterpret_cast<const bf16x8*>(ckh + ko + ks * 32);
      bf16x8 bM = *reinterpret_cast<const bf16x8*>(ckm + ko + ks * 32);
      bf16x8 bL = *reinterpret_cast<const bf16x8*>(ckl + ko + ks * 32);
#pragma unroll
      for (int mi = 0; mi < 2; ++mi) {
        acc[mi][ni] = __builtin_amdgcn_mfma_f32_16x16x32_bf16(aH[mi][ks], bH, acc[mi][ni], 0, 0, 0);
        acc[mi][ni] = __builtin_amdgcn_mfma_f32_16x16x32_bf16(aH[mi][ks], bM, acc[mi][ni], 0, 0, 0);
        acc[mi][ni] = __builtin_amdgcn_mfma_f32_16x16x32_bf16(aM[mi][ks], bH, acc[mi][ni], 0, 0, 0);
        acc[mi][ni] = __builtin_amdgcn_mfma_f32_16x16x32_bf16(aH[mi][ks], bL, acc[mi][ni], 0, 0, 0);
        acc[mi][ni] = __builtin_amdgcn_mfma_f32_16x16x32_bf16(aL[mi][ks], bH, acc[mi][ni], 0, 0, 0);
        acc[mi][ni] = __builtin_amdgcn_mfma_f32_16x16x32_bf16(aM[mi][ks], bM, acc[mi][ni], 0, 0, 0);
      }
    }
  }
#pragma unroll
  for (int mi = 0; mi < 2; ++mi)
#pragma unroll
    for (int ni = 0; ni < 4; ++ni) {
      int col = (w << 6) + (ni << 4) + lr;
      int wend = (col == 0) ? -1 : ((col - 1) << 3) + 15;
#pragma unroll
      for (int r = 0; r < 4; ++r) {
        int qi = mi * 16 + crow + r;
        bool ok = (col < 255) && (wend < i0 + qi);
        p[qi][col] = ok ? acc[mi][ni][r] * 0.125f : NEGV;
      }
    }
  __syncthreads();

  const int qi = t >> 3, s = t & 7;
  float ev[32];
  float mx = -3.0e38f;
#pragma unroll
  for (int u = 0; u < 32; ++u) { ev[u] = p[qi][s + (u << 3)]; mx = fmaxf(mx, ev[u]); }
  mx = fmaxf(mx, __shfl_xor(mx, 1));
  mx = fmaxf(mx, __shfl_xor(mx, 2));
  mx = fmaxf(mx, __shfl_xor(mx, 4));
  float sum = 0.f;
#pragma unroll
  for (int u = 0; u < 32; ++u) { float e = __expf(ev[u] - mx); ev[u] = e; sum += e; }
  sum += __shfl_xor(sum, 1); sum += __shfl_xor(sum, 2); sum += __shfl_xor(sum, 4);
  float invs = 1.f / sum;
#pragma unroll
  for (int u = 0; u < 32; ++u) p[qi][s + (u << 3)] = ev[u] * invs;

  int qblk = (i0 + qi) >> 4;
  float vals[16];
#pragma unroll
  for (int u = 0; u < 16; ++u) {
    int f = (s << 4) + u;
    float v;
    if (f >= qblk || f == 127) v = NEGV;
    else v = (p[qi][2 * f + 1] + p[qi][2 * f + 2]) * 0.5f;
    vals[u] = v;
  }
  int base = ((h << 11) | (i0 + qi)) * 5;
  for (int kk = 0; kk < 4; ++kk) {
    float bv = -3.0e38f; int bi = 0;
#pragma unroll
    for (int u = 0; u < 16; ++u) {
      if (vals[u] > bv) { bv = vals[u]; bi = (s << 4) + u; }
    }
#pragma unroll
    for (int o = 1; o < 8; o <<= 1) {
      float ov = __shfl_xor(bv, o);
      int oi = __shfl_xor(bi, o);
      if (ov > bv || (ov == bv && oi < bi)) { bv = ov; bi = oi; }
    }
    if (s == 0) sel[base + kk] = (bv > -5.0e8f) ? bi : -1;
    if ((bi >> 4) == s) vals[bi & 15] = -3.0e38f;
  }
  if (s == 0) sel[base + 4] = (i0 + qi) >> 4;
  __syncthreads();

  const int wm = w >> 1, wn = w & 1;
  const int arow = wm * 16 + lr;
  f32x4 pacc[2];
#pragma unroll
  for (int b = 0; b < 2; ++b) pacc[b] = (f32x4){0.f, 0.f, 0.f, 0.f};
#pragma unroll
  for (int ks = 0; ks < 8; ++ks) {
    int k0 = ks * 32 + kg;
    float4 x0 = *reinterpret_cast<const float4*>(&p[arow][k0]);
    float4 x1 = *reinterpret_cast<const float4*>(&p[arow][k0 + 4]);
    float xv[8] = {x0.x, x0.y, x0.z, x0.w, x1.x, x1.y, x1.z, x1.w};
    bf16x8 ph, pl;
#pragma unroll
    for (int e = 0; e < 8; ++e) {
      __bf16 hh = (__bf16)xv[e];
      ph[e] = hh;
      pl[e] = (__bf16)(xv[e] - (float)hh);
    }
#pragma unroll
    for (int ni = 0; ni < 2; ++ni) {
      int d = (wn << 5) + (ni << 4) + lr;
      bf16x8 bv = *reinterpret_cast<const bf16x8*>(cvtb + ((size_t)h * 64 + d) * 256 + k0);
      pacc[ni] = __builtin_amdgcn_mfma_f32_16x16x32_bf16(ph, bv, pacc[ni], 0, 0, 0);
      pacc[ni] = __builtin_amdgcn_mfma_f32_16x16x32_bf16(pl, bv, pacc[ni], 0, 0, 0);
    }
  }
#pragma unroll
  for (int ni = 0; ni < 2; ++ni) {
    int d = (wn << 5) + (ni << 4) + lr;
#pragma unroll
    for (int r = 0; r < 4; ++r) {
      int q2 = wm * 16 + crow + r;
      c_out[((size_t)h * NTOK + i0 + q2) * DHEAD + d] = pacc[ni][r];
    }
  }
}

// ---------------- fine attention: 1 wave per query, fp32 K via float4 ----------------
__global__ __launch_bounds__(256) void k_fine_attn(
    const bf16* __restrict__ rqh, const bf16* __restrict__ rql,
    const float* __restrict__ rkf, const bf16* __restrict__ vbh,
    const int* __restrict__ sel, float* __restrict__ f_out) {
  const int h = blockIdx.y;
  const int wid = threadIdx.x >> 6;
  const int lane = threadIdx.x & 63;
  const int i = (blockIdx.x << 2) | wid;

  __shared__ float qs[4][64];
  __shared__ float pb[4][80];
  __shared__ int selb[4][5];

  size_t qoff = ((size_t)h * NTOK + i) * DHEAD + lane;
  qs[wid][lane] = __bfloat162float(rqh[qoff]) + __bfloat162float(rql[qoff]);
  if (lane < 5) selb[wid][lane] = sel[((h << 11) | i) * 5 + lane];
  __syncthreads();

  float sim0 = NEGV, sim1 = NEGV;
  {
    int kb = selb[wid][lane >> 4];
    int pos = (kb << 4) + (lane & 15);
    if (kb >= 0 && pos <= i) {
      const float* kp = rkf + ((size_t)h * NTOK + pos) * DHEAD;
      float d = 0.f;
#pragma unroll
      for (int e4 = 0; e4 < 16; ++e4) {
        float4 kv = *reinterpret_cast<const float4*>(kp + e4 * 4);
        d = fmaf(qs[wid][e4 * 4 + 0], kv.x, d);
        d = fmaf(qs[wid][e4 * 4 + 1], kv.y, d);
        d = fmaf(qs[wid][e4 * 4 + 2], kv.z, d);
        d = fmaf(qs[wid][e4 * 4 + 3], kv.w, d);
      }
      sim0 = d * 0.125f;
    }
  }
  if (lane < 16) {
    int kb = selb[wid][4];
    int pos = (kb << 4) + lane;
    if (pos <= i) {
      const float* kp = rkf + ((size_t)h * NTOK + pos) * DHEAD;
      float d = 0.f;
#pragma unroll
      for (int e4 = 0; e4 < 16; ++e4) {
        float4 kv = *reinterpret_cast<const float4*>(kp + e4 * 4);
        d = fmaf(qs[wid][e4 * 4 + 0], kv.x, d);
        d = fmaf(qs[wid][e4 * 4 + 1], kv.y, d);
        d = fmaf(qs[wid][e4 * 4 + 2], kv.z, d);
        d = fmaf(qs[wid][e4 * 4 + 3], kv.w, d);
      }
      sim1 = d * 0.125f;
    }
  }

  float mx = fmaxf(sim0, sim1);
#pragma unroll
  for (int o = 32; o > 0; o >>= 1) mx = fmaxf(mx, __shfl_xor(mx, o));
  float e0 = __expf(sim0 - mx);
  float e1 = __expf(sim1 - mx);
  float sum = e0 + e1;
#pragma unroll
  for (int o = 32; o > 0; o >>= 1) sum += __shfl_xor(sum, o);
  float invs = 1.f / sum;
  pb[wid][lane] = e0 * invs;
  if (lane < 16) pb[wid][64 + lane] = e1 * invs;

  float acc = 0.f;
#pragma unroll
  for (int b = 0; b < 5; ++b) {
    int kb = selb[wid][b];
    if (kb < 0) continue;
    const bf16* vr = vbh + ((size_t)h * NTOK + ((size_t)kb << 4)) * DHEAD + lane;
#pragma unroll
    for (int u = 0; u < 16; ++u)
      acc = fmaf(pb[wid][b * 16 + u], __bfloat162float(vr[(size_t)u * DHEAD]), acc);
  }
  f_out[((size_t)h * NTOK + i) * DHEAD + lane] = acc;
}

// ---------------- sliding-window attention (MFMA, 64 queries/block) ----------------
__global__ __launch_bounds__(256) void k_slide_attn(
    const bf16* __restrict__ rqh, const bf16* __restrict__ rql,
    const bf16* __restrict__ rkh, const bf16* __restrict__ rkl,
    const bf16* __restrict__ vtb, float* __restrict__ s_out) {
  const int h = blockIdx.y, nb = blockIdx.x;
  const int t = threadIdx.x, w = t >> 6, lane = t & 63;
  const int lr = lane & 15, kg = (lane >> 4) << 3;
  const int crow = (lane >> 4) << 2;
  const int wm = w >> 1, wn = w & 1;
  __shared__ float p[64][132];

  bf16x8 aH[2][2], aL[2][2];
#pragma unroll
  for (int mi = 0; mi < 2; ++mi) {
    size_t qo = ((size_t)h * NTOK + nb * 64 + wm * 32 + mi * 16 + lr) * DHEAD + kg;
#pragma unroll
    for (int ks = 0; ks < 2; ++ks) {
      aH[mi][ks] = *reinterpret_cast<const bf16x8*>(rqh + qo + ks * 32);
      aL[mi][ks] = *reinterpret_cast<const bf16x8*>(rql + qo + ks * 32);
    }
  }
  f32x4 acc[2][4];
#pragma unroll
  for (int a = 0; a < 2; ++a)
#pragma unroll
    for (int b = 0; b < 4; ++b) acc[a][b] = (f32x4){0.f, 0.f, 0.f, 0.f};
#pragma unroll
  for (int ni = 0; ni < 4; ++ni) {
    int col = (wn << 6) + (ni << 4) + lr;
    size_t ko = ((size_t)h * 2112 + nb * 64 + col) * 64 + kg;
#pragma unroll
    for (int ks = 0; ks < 2; ++ks) {
      bf16x8 bH = *reinterpret_cast<const bf16x8*>(rkh + ko + ks * 32);
      bf16x8 bL = *reinterpret_cast<const bf16x8*>(rkl + ko + ks * 32);
#pragma unroll
      for (int mi = 0; mi < 2; ++mi) {
        acc[mi][ni] = __builtin_amdgcn_mfma_f32_16x16x32_bf16(aH[mi][ks], bH, acc[mi][ni], 0, 0, 0);
        acc[mi][ni] = __builtin_amdgcn_mfma_f32_16x16x32_bf16(aL[mi][ks], bH, acc[mi][ni], 0, 0, 0);
        acc[mi][ni] = __builtin_amdgcn_mfma_f32_16x16x32_bf16(aH[mi][ks], bL, acc[mi][ni], 0, 0, 0);
      }
    }
  }
#pragma unroll
  for (int mi = 0; mi < 2; ++mi)
#pragma unroll
    for (int ni = 0; ni < 4; ++ni) {
      int col = (wn << 6) + (ni << 4) + lr;
#pragma unroll
      for (int r = 0; r < 4; ++r) {
        int qi2 = wm * 32 + mi * 16 + crow + r;
        bool ok = (col >= qi2 + 1) && (col <= qi2 + 64) && (nb > 0 || col >= 64);
        p[qi2][col] = ok ? acc[mi][ni][r] * 0.125f : NEGV;
      }
    }
  __syncthreads();

  const int qi = t >> 2, s = t & 3;
  float ev[32];
  float mx = -3.0e38f;
#pragma unroll
  for (int u = 0; u < 32; ++u) { ev[u] = p[qi][s + (u << 2)]; mx = fmaxf(mx, ev[u]); }
  mx = fmaxf(mx, __shfl_xor(mx, 1));
  mx = fmaxf(mx, __shfl_xor(mx, 2));
  float sum = 0.f;
#pragma unroll
  for (int u = 0; u < 32; ++u) { float e = __expf(ev[u] - mx); ev[u] = e; sum += e; }
  sum += __shfl_xor(sum, 1); sum += __shfl_xor(sum, 2);
  float invs = 1.f / sum;
#pragma unroll
  for (int u = 0; u < 32; ++u) p[qi][s + (u << 2)] = ev[u] * invs;
  __syncthreads();

  f32x4 pacc[2][2];
#pragma unroll
  for (int a = 0; a < 2; ++a)
#pragma unroll
    for (int b = 0; b < 2; ++b) pacc[a][b] = (f32x4){0.f, 0.f, 0.f, 0.f};
#pragma unroll
  for (int ks = 0; ks < 4; ++ks) {
    int k0 = ks * 32 + kg;
    bf16x8 ph[2], pl[2];
#pragma unroll
    for (int mi = 0; mi < 2; ++mi) {
      int arow = wm * 32 + mi * 16 + lr;
      float4 x0 = *reinterpret_cast<const float4*>(&p[arow][k0]);
      float4 x1 = *reinterpret_cast<const float4*>(&p[arow][k0 + 4]);
      float xv[8] = {x0.x, x0.y, x0.z, x0.w, x1.x, x1.y, x1.z, x1.w};
#pragma unroll
      for (int e = 0; e < 8; ++e) {
        __bf16 hh = (__bf16)xv[e];
        ph[mi][e] = hh;
        pl[mi][e] = (__bf16)(xv[e] - (float)hh);
      }
    }
#pragma unroll
    for (int ni = 0; ni < 2; ++ni) {
      int d = (wn << 5) + (ni << 4) + lr;
      bf16x8 bv = *reinterpret_cast<const bf16x8*>(vtb + ((size_t)h * 64 + d) * 2112 + nb * 64 + k0);
#pragma unroll
      for (int mi = 0; mi < 2; ++mi) {
        pacc[mi][ni] = __builtin_amdgcn_mfma_f32_16x16x32_bf16(ph[mi], bv, pacc[mi][ni], 0, 0, 0);
        pacc[mi][ni] = __builtin_amdgcn_mfma_f32_16x16x32_bf16(pl[mi], bv, pacc[mi][ni], 0, 0, 0);
      }
    }
  }
#pragma unroll
  for (int mi = 0; mi < 2; ++mi)
#pragma unroll
    for (int ni = 0; ni < 2; ++ni) {
      int d = (wn << 5) + (ni << 4) + lr;
#pragma unroll
      for (int r = 0; r < 4; ++r) {
        int qi2 = wm * 32 + mi * 16 + crow + r;
        s_out[((size_t)h * NTOK + nb * 64 + qi2) * DHEAD + d] = pacc[mi][ni][r];
      }
    }
}

// ---------------- fused strat + combine: one block per token ----------------
__global__ __launch_bounds__(256) void k_combine2(
    const bf16* __restrict__ Ah, const bf16* __restrict__ Al,
    const float* __restrict__ W, const float* __restrict__ bias,
    const float* __restrict__ c_out, const float* __restrict__ f_out,
    const float* __restrict__ s_out, bf16* __restrict__ comb) {
  const int i = blockIdx.x;
  const int t = threadIdx.x;
  __shared__ float hs[DMODEL];
  __shared__ float st[24];
  size_t ro = (size_t)i * DMODEL;
#pragma unroll
  for (int u = 0; u < 2; ++u) {
    int c = t + u * 256;
    hs[c] = __bfloat162float(Ah[ro + c]) + __bfloat162float(Al[ro + c]);
  }
  __syncthreads();
  if (t < 192) {
    int c = t >> 3, s = t & 7;
    float acc = 0.f;
    for (int u = 0; u < 64; ++u) {
      int e = s * 64 + u;
      acc = fmaf(hs[e], W[(size_t)e * 24 + c], acc);
    }
    acc += __shfl_xor(acc, 1);
    acc += __shfl_xor(acc, 2);
    acc += __shfl_xor(acc, 4);
    if (s == 0) st[c] = 1.f / (1.f + expf(-(acc + bias[c])));
  }
  __syncthreads();
#pragma unroll
  for (int u = 0; u < 2; ++u) {
    int c = t + u * 256;
    int h = c >> 6, d = c & 63;
    size_t a = ((size_t)h * NTOK + i) * DHEAD + d;
    comb[ro + c] = __float2bfloat16(st[h * 3] * c_out[a] + st[h * 3 + 1] * f_out[a]
                                    + st[h * 3 + 2] * s_out[a]);
  }
}

extern "C" void kernel_launch(void* const* d_in, const int* in_sizes, int n_in,
                              void* d_out, int out_size, void* d_ws, size_t ws_size,
                              hipStream_t stream) {
  const float* x      = (const float*)d_in[0];
  const float* g_norm = (const float*)d_in[1];
  const float* w_qkv  = (const float*)d_in[2];
  const float* k_pos  = (const float*)d_in[3];
  const float* v_pos  = (const float*)d_in[4];
  const float* mem_kv = (const float*)d_in[5];
  const float* k_w1   = (const float*)d_in[6];
  const float* k_b1   = (const float*)d_in[7];
  const float* k_w2   = (const float*)d_in[8];
  const float* k_b2   = (const float*)d_in[9];
  const float* v_w1   = (const float*)d_in[10];
  const float* v_b1   = (const float*)d_in[11];
  const float* v_w2   = (const float*)d_in[12];
  const float* v_b2   = (const float*)d_in[13];
  const float* w_comb = (const float*)d_in[14];
  const float* b_comb = (const float*)d_in[15];
  const float* w_out  = (const float*)d_in[16];
  float* out = (float*)d_out;
  char* wsb = (char*)d_ws;

  bf16* WQKV_H = (bf16*)(wsb + B_WQKV_H);
  bf16* WQKV_L = (bf16*)(wsb + B_WQKV_L);
  bf16* KW1_H  = (bf16*)(wsb + B_KW1_H);
  bf16* KW1_L  = (bf16*)(wsb + B_KW1_L);
  bf16* KW2_H  = (bf16*)(wsb + B_KW2_H);
  bf16* KW2_L  = (bf16*)(wsb + B_KW2_L);
  bf16* VW1_H  = (bf16*)(wsb + B_VW1_H);
  bf16* VW2_H  = (bf16*)(wsb + B_VW2_H);
  bf16* WOUT_H = (bf16*)(wsb + B_WOUT_H);
  bf16* HB_H   = (bf16*)(wsb + B_HB_H);
  bf16* HB_L   = (bf16*)(wsb + B_HB_L);
  bf16* QBH    = (bf16*)(wsb + B_QBH);
  bf16* QBM    = (bf16*)(wsb + B_QBM);
  bf16* QBL    = (bf16*)(wsb + B_QBL);
  float* KF    = (float*)(wsb + B_KF);
  bf16* VBH    = (bf16*)(wsb + B_VBH);
  bf16* RQH    = (bf16*)(wsb + B_RQH);
  bf16* RQL    = (bf16*)(wsb + B_RQL);
  bf16* RKH    = (bf16*)(wsb + B_RKH);
  bf16* RKL    = (bf16*)(wsb + B_RKL);
  float* RKF   = (float*)(wsb + B_RKF);
  bf16* VTB    = (bf16*)(wsb + B_VTB);
  bf16* CKT_H  = (bf16*)(wsb + B_CKT_H);
  bf16* CKT_M  = (bf16*)(wsb + B_CKT_M);
  bf16* CKT_L  = (bf16*)(wsb + B_CKT_L);
  bf16* CVT    = (bf16*)(wsb + B_CVT);
  int*   SEL   = (int*)(wsb + B_SEL);
  float* COUT  = (float*)(wsb + B_COUT);
  float* FOUT  = (float*)(wsb + B_FOUT);
  float* SOUT  = (float*)(wsb + B_SOUT);
  bf16* KW_H   = (bf16*)(wsb + B_KW_H);
  bf16* KW_L   = (bf16*)(wsb + B_KW_L);
  bf16* VW_H   = (bf16*)(wsb + B_VW_H);
  bf16* HID_H  = (bf16*)(wsb + B_HID_H);
  bf16* HID_L  = (bf16*)(wsb + B_HID_L);
  bf16* HIDV   = (bf16*)(wsb + B_HIDV);
  bf16* COMBB  = (bf16*)(wsb + B_COMBB);

  // 1. setup: weight splits + pads + mem fill + rmsnorm
  k_setup<<<5378, 256, 0, stream>>>(x, g_norm, w_qkv, k_w1, k_w2, v_w1, v_w2, w_out, mem_kv,
                                    WQKV_H, WQKV_L, KW1_H, KW1_L, KW2_H, KW2_L,
                                    VW1_H, VW2_H, WOUT_H, HB_H, HB_L,
                                    RKH, RKL, VTB, CKT_H, CKT_M, CKT_L, CVT);
  // 2. qkv (compensated, pipelined 64x64/wave) with fused split/scatter
  k_qkv<<<dim3(12, 16), 256, 0, stream>>>(HB_H, HB_L, WQKV_H, WQKV_L, KF, QBH, QBM, QBL, VBH);
  // 3. post: rope + v-transpose + windows
  k_post<<<10432, 256, 0, stream>>>(QBH, QBM, QBL, KF, VBH, k_pos, v_pos,
                                    RQH, RQL, RKH, RKL, RKF, VTB, KW_H, KW_L, VW_H);
  // 4. merged MLP1 (pipelined 64x64/wave; k compensated + v plain); HIDV overlays dead KF
  k_mlp1<<<dim3(8, 16, 2), 256, 0, stream>>>(KW_H, KW_L, KW1_H, KW1_L, k_b1,
                                             VW_H, VW1_H, v_b1, HID_H, HID_L, HIDV);
  // 5. merged MLP2 -> ckT hi/mid/lo + cvT
  k_mlp2<<<dim3(1, 32, 2), 256, 0, stream>>>(HID_H, HID_L, KW2_H, KW2_L, k_b2,
                                             HIDV, VW2_H, v_b2, CKT_H, CKT_M, CKT_L, CVT);
  // 6-8. attention branches
  k_comp_attn<<<dim3(64, 8), 256, 0, stream>>>(QBH, QBM, QBL, CKT_H, CKT_M, CKT_L, CVT, COUT, SEL);
  k_fine_attn<<<dim3(512, 8), 256, 0, stream>>>(RQH, RQL, RKF, VBH, SEL, FOUT);
  k_slide_attn<<<dim3(32, 8), 256, 0, stream>>>(RQH, RQL, RKH, RKL, VTB, SOUT);
  // 9. fused strat + combine
  k_combine2<<<NTOK, 256, 0, stream>>>(HB_H, HB_L, w_comb, b_comb, COUT, FOUT, SOUT, COMBB);
  // 10. output projection (32-tile core)
  k_cgemm<0, 0><<<dim3(8, 32), 256, 0, stream>>>(
      COMBB, nullptr, WOUT_H, nullptr, nullptr, out, NTOK, DMODEL, DMODEL);
}